// Round 1
// baseline (2914.348 us; speedup 1.0000x reference)
//
#include <hip/hip_runtime.h>

#define NND 50000
#define NE  1600000

__device__ __forceinline__ float leaky02(float x){ return x > 0.f ? x : 0.2f*x; }

// ---------------------------------------------------------------- CSR build
__global__ __launch_bounds__(256) void hist_kernel(const int* __restrict__ ei,
                                                   int* __restrict__ cnt){
  int e = blockIdx.x*256 + threadIdx.x;
  if (e < NE) atomicAdd(&cnt[ei[NE + e]], 1);
}

__global__ __launch_bounds__(1024) void scan_kernel(const int* __restrict__ cnt,
                                                    int* __restrict__ offsets, int n){
  __shared__ int wsum[16];
  __shared__ int sbase;
  int t = threadIdx.x, lane = t & 63, w = t >> 6;
  if (t == 0) sbase = 0;
  __syncthreads();
  for (int start = 0; start < n; start += 1024){
    int i = start + t;
    int x = (i < n) ? cnt[i] : 0;
    #pragma unroll
    for (int off = 1; off < 64; off <<= 1){ int y = __shfl_up(x, off); if (lane >= off) x += y; }
    if (lane == 63) wsum[w] = x;
    __syncthreads();
    if (w == 0 && lane < 16){
      int sv = wsum[lane];
      #pragma unroll
      for (int off = 1; off < 16; off <<= 1){ int y = __shfl_up(sv, off); if (lane >= off) sv += y; }
      wsum[lane] = sv;
    }
    __syncthreads();
    int base = sbase + (w > 0 ? wsum[w-1] : 0);
    if (i < n) offsets[i+1] = base + x;
    __syncthreads();
    if (t == 0) sbase += wsum[15];
    __syncthreads();
  }
  if (t == 0) offsets[0] = 0;
}

__global__ __launch_bounds__(256) void scatter_kernel(const int* __restrict__ ei,
                                                      const float* __restrict__ ea,
                                                      const int* __restrict__ offsets,
                                                      int* __restrict__ cursor,
                                                      int4* __restrict__ srcattr){
  int e = blockIdx.x*256 + threadIdx.x;
  if (e < NE){
    int dstn = ei[NE + e];
    int pos  = atomicAdd(&cursor[dstn], 1);
    int idx  = offsets[dstn] + pos;
    srcattr[idx] = make_int4(ei[e], __float_as_int(ea[2*e]), __float_as_int(ea[2*e+1]), 0);
  }
}

// --------------------------------------------- UV encoder + sym encoder (per-node block)
__global__ __launch_bounds__(256) void uv_sym_kernel(
    const float* __restrict__ x_vis, const float* __restrict__ x_sym,
    const float* __restrict__ w1, const float* __restrict__ b1,
    const float* __restrict__ w2, const float* __restrict__ b2,
    const float* __restrict__ fcw, const float* __restrict__ fcb,
    const float* __restrict__ s1w, const float* __restrict__ s1b,
    const float* __restrict__ s2w, const float* __restrict__ s2b,
    float* __restrict__ x192)
{
  __shared__ float xp[600];     // [6][10][10] zero-padded input
  __shared__ float c1p[3840];   // [32][10][12] zero-padded conv1 out (row stride 12 -> 16B aligned)
  __shared__ float pooled[64];
  __shared__ float symh[64];
  const int nb = blockIdx.x;
  const int t  = threadIdx.x;

  for (int i = t; i < 600;  i += 256) xp[i]  = 0.f;
  for (int i = t; i < 3840; i += 256) c1p[i] = 0.f;
  __syncthreads();
  const float* xv = x_vis + (size_t)nb*384;
  for (int i = t; i < 384; i += 256){
    int c = i >> 6, rem = i & 63, y = rem >> 3, x = rem & 7;
    xp[c*100 + (y+1)*10 + (x+1)] = xv[i];
  }
  __syncthreads();

  // conv1: thread -> (oc = t>>3 in [0,32), row = t&7), computes one 8-wide output row
  {
    int oc = t >> 3, row = t & 7;
    float acc[8];
    #pragma unroll
    for (int x = 0; x < 8; x++) acc[x] = b1[oc];
    const float* woc = w1 + oc*54;
    for (int ic = 0; ic < 6; ic++){
      float r0[10], r1[10], r2[10];
      const float* base = xp + ic*100 + row*10;
      #pragma unroll
      for (int c = 0; c < 10; c++){ r0[c] = base[c]; r1[c] = base[10+c]; r2[c] = base[20+c]; }
      const float* wi = woc + ic*9;
      float w00=wi[0],w01=wi[1],w02=wi[2],w10=wi[3],w11=wi[4],w12=wi[5],w20=wi[6],w21=wi[7],w22=wi[8];
      #pragma unroll
      for (int x = 0; x < 8; x++){
        acc[x] += w00*r0[x] + w01*r0[x+1] + w02*r0[x+2]
                + w10*r1[x] + w11*r1[x+1] + w12*r1[x+2]
                + w20*r2[x] + w21*r2[x+1] + w22*r2[x+2];
      }
    }
    #pragma unroll
    for (int x = 0; x < 8; x++){
      float v = acc[x]; v = v > 0.f ? v : 0.f;
      c1p[oc*120 + (row+1)*12 + (x+1)] = v;
    }
  }
  __syncthreads();

  // conv2: thread -> (oc = t>>2 in [0,64), q = t&3 -> output rows 2q, 2q+1)
  {
    int oc = t >> 2, q = t & 3;
    int r0 = 2*q;
    float acc[16];
    #pragma unroll
    for (int i = 0; i < 16; i++) acc[i] = b2[oc];
    const float* woc = w2 + oc*288;
    for (int ic = 0; ic < 32; ic++){
      const float* wi = woc + ic*9;
      float wk[3][3];
      #pragma unroll
      for (int k = 0; k < 9; k++) wk[k/3][k%3] = wi[k];
      const float* base = c1p + ic*120 + r0*12;
      float rr[4][10];
      #pragma unroll
      for (int r = 0; r < 4; r++){
        const float* rp = base + r*12;
        float4 v0 = *(const float4*)(rp);
        float4 v1 = *(const float4*)(rp+4);
        float2 v2 = *(const float2*)(rp+8);
        rr[r][0]=v0.x; rr[r][1]=v0.y; rr[r][2]=v0.z; rr[r][3]=v0.w;
        rr[r][4]=v1.x; rr[r][5]=v1.y; rr[r][6]=v1.z; rr[r][7]=v1.w;
        rr[r][8]=v2.x; rr[r][9]=v2.y;
      }
      #pragma unroll
      for (int dy = 0; dy < 3; dy++){
        #pragma unroll
        for (int x = 0; x < 8; x++){
          acc[x]   += wk[dy][0]*rr[dy  ][x] + wk[dy][1]*rr[dy  ][x+1] + wk[dy][2]*rr[dy  ][x+2];
          acc[8+x] += wk[dy][0]*rr[dy+1][x] + wk[dy][1]*rr[dy+1][x+1] + wk[dy][2]*rr[dy+1][x+2];
        }
      }
    }
    float ps = 0.f;
    #pragma unroll
    for (int i = 0; i < 16; i++){ float v = acc[i] > 0.f ? acc[i] : 0.f; ps += v; }
    ps += __shfl_xor(ps, 1);
    ps += __shfl_xor(ps, 2);
    if (q == 0) pooled[oc] = ps * (1.f/64.f);
  }
  __syncthreads();

  // fc(64->128) on pooled (no activation), sym layer1 on other threads
  if (t < 128){
    float a = fcb[t];
    #pragma unroll 4
    for (int k = 0; k < 64; k++) a = fmaf(pooled[k], fcw[k*128 + t], a);
    x192[(size_t)nb*192 + t] = a;
  } else if (t < 192){
    int j = t - 128;
    const float* xs = x_sym + (size_t)nb*3;
    float a = s1b[j] + xs[0]*s1w[j] + xs[1]*s1w[64+j] + xs[2]*s1w[128+j];
    symh[j] = a > 0.f ? a : 0.f;
  }
  __syncthreads();
  if (t < 64){
    float a = s2b[t];
    #pragma unroll 4
    for (int k = 0; k < 64; k++) a = fmaf(symh[k], s2w[k*64 + t], a);
    x192[(size_t)nb*192 + 128 + t] = a > 0.f ? a : 0.f;
  }
}

// ------------------------------------- per-node transform: h = x@W+b, s=(h.a_src), d=(h.a_dst)
template<int K>
__global__ __launch_bounds__(256) void node_transform(
    const float* __restrict__ xin, const float* __restrict__ W, const float* __restrict__ b,
    const float* __restrict__ asrc, const float* __restrict__ adst,
    float* __restrict__ h_out, float* __restrict__ s_out, float* __restrict__ d_out)
{
  const int v  = blockIdx.x*4 + (threadIdx.x >> 6);
  const int l  = threadIdx.x & 63;
  const int vu = __builtin_amdgcn_readfirstlane(v);
  const float* xr = xin + (size_t)vu*K;
  const int c0 = 2*l;
  float2 acc = { b[c0], b[c0+1] };
  #pragma unroll 4
  for (int k = 0; k < K; k++){
    float xk = xr[k];
    float2 w = *(const float2*)(W + k*128 + c0);
    acc.x = fmaf(xk, w.x, acc.x);
    acc.y = fmaf(xk, w.y, acc.y);
  }
  *(float2*)(h_out + (size_t)v*128 + c0) = acc;
  const int hd = l >> 4;
  float as0 = asrc[hd*32 + (c0&31)], as1 = asrc[hd*32 + ((c0+1)&31)];
  float ad0 = adst[hd*32 + (c0&31)], ad1 = adst[hd*32 + ((c0+1)&31)];
  float sv = acc.x*as0 + acc.y*as1;
  float dv = acc.x*ad0 + acc.y*ad1;
  #pragma unroll
  for (int o = 1; o < 16; o <<= 1){ sv += __shfl_xor(sv, o); dv += __shfl_xor(dv, o); }
  if ((l & 15) == 0){ s_out[v*4 + hd] = sv; d_out[v*4 + hd] = dv; }
}

// -------------------------------------------- GAT aggregation, wave per dst node, no atomics
__global__ __launch_bounds__(256) void gat_aggregate(
    const float* __restrict__ sarr, const float* __restrict__ darr, const float* __restrict__ h,
    const int4* __restrict__ srcattr, const int* __restrict__ offsets,
    const float* __restrict__ We, const float* __restrict__ be,
    const float* __restrict__ aedge, const float* __restrict__ Wg, const float* __restrict__ bgp,
    float* __restrict__ xout)
{
  const int l  = threadIdx.x & 63;
  const int v  = blockIdx.x*4 + (threadIdx.x >> 6);
  const int hd = l >> 4;
  const int c0 = 2*l;

  // per-head edge-logit projections: el[h] = a0*P0[h] + a1*P1[h] + PC[h]
  float ae0 = aedge[hd*32 + (c0&31)];
  float ae1 = aedge[hd*32 + ((c0+1)&31)];
  float we00 = We[c0], we01 = We[c0+1], we10 = We[128+c0], we11 = We[128+c0+1];
  float beA = be[c0], beB = be[c0+1];
  float p0 = we00*ae0 + we01*ae1;
  float p1 = we10*ae0 + we11*ae1;
  float pc = beA*ae0 + beB*ae1;
  #pragma unroll
  for (int o = 1; o < 16; o <<= 1){ p0 += __shfl_xor(p0,o); p1 += __shfl_xor(p1,o); pc += __shfl_xor(pc,o); }
  float P00=__shfl(p0,0), P01=__shfl(p0,16), P02=__shfl(p0,32), P03=__shfl(p0,48);
  float P10=__shfl(p1,0), P11=__shfl(p1,16), P12=__shfl(p1,32), P13=__shfl(p1,48);
  float PC0=__shfl(pc,0), PC1=__shfl(pc,16), PC2=__shfl(pc,32), PC3=__shfl(pc,48);
  const float wg0 = Wg[0], wg1 = Wg[1], bgv = bgp[0];

  const int off = offsets[v];
  const int deg = offsets[v+1] - off;
  const float4 d4 = *(const float4*)(darr + (size_t)v*4);

  // phase 1: denominators (softmax without max-shift; logits are O(1e-2))
  float dn0=0.f, dn1=0.f, dn2=0.f, dn3=0.f;
  for (int base = 0; base < deg; base += 64){
    int ii = base + l;
    if (ii < deg){
      int4 sa = srcattr[off + ii];
      float a0 = __int_as_float(sa.y), a1 = __int_as_float(sa.z);
      const float4 sv = *(const float4*)(sarr + (size_t)sa.x*4);
      dn0 += __expf(leaky02(sv.x + d4.x + a0*P00 + a1*P10 + PC0));
      dn1 += __expf(leaky02(sv.y + d4.y + a0*P01 + a1*P11 + PC1));
      dn2 += __expf(leaky02(sv.z + d4.z + a0*P02 + a1*P12 + PC2));
      dn3 += __expf(leaky02(sv.w + d4.w + a0*P03 + a1*P13 + PC3));
    }
  }
  #pragma unroll
  for (int o = 1; o < 64; o <<= 1){
    dn0 += __shfl_xor(dn0,o); dn1 += __shfl_xor(dn1,o);
    dn2 += __shfl_xor(dn2,o); dn3 += __shfl_xor(dn3,o);
  }
  float den = (hd==0)?dn0:(hd==1)?dn1:(hd==2)?dn2:dn3;
  const float rden = 1.f/(den + 1e-16f);

  // phase 2: recompute per-edge terms lane-parallel, broadcast via shfl, accumulate messages
  float accx = 0.f, accy = 0.f;
  for (int base = 0; base < deg; base += 64){
    int ii = base + l;
    float e0=0.f,e1=0.f,e2=0.f,e3=0.f,a0=0.f,a1=0.f,gt=0.f; int sj=0;
    if (ii < deg){
      int4 sa = srcattr[off + ii];
      a0 = __int_as_float(sa.y); a1 = __int_as_float(sa.z); sj = sa.x;
      const float4 sv = *(const float4*)(sarr + (size_t)sa.x*4);
      e0 = __expf(leaky02(sv.x + d4.x + a0*P00 + a1*P10 + PC0));
      e1 = __expf(leaky02(sv.y + d4.y + a0*P01 + a1*P11 + PC1));
      e2 = __expf(leaky02(sv.z + d4.z + a0*P02 + a1*P12 + PC2));
      e3 = __expf(leaky02(sv.w + d4.w + a0*P03 + a1*P13 + PC3));
      gt = 1.f/(1.f + __expf(-(a0*wg0 + a1*wg1 + bgv)));
    }
    int lim = min(64, deg - base);
    for (int j = 0; j < lim; j++){
      float ee0=__shfl(e0,j), ee1=__shfl(e1,j), ee2=__shfl(e2,j), ee3=__shfl(e3,j);
      float aa0=__shfl(a0,j), aa1=__shfl(a1,j), gg=__shfl(gt,j);
      int   ss =__shfl(sj,j);
      float exh = (hd==0)?ee0:(hd==1)?ee1:(hd==2)?ee2:ee3;
      float m = gg * exh * rden;
      const float2 hv = *(const float2*)(h + (size_t)ss*128 + c0);
      float efA = beA + aa0*we00 + aa1*we10;
      float efB = beB + aa0*we01 + aa1*we11;
      accx = fmaf(hv.x + efA, m, accx);
      accy = fmaf(hv.y + efB, m, accy);
    }
  }
  float ox = accx > 0.f ? accx : (__expf(accx) - 1.f);
  float oy = accy > 0.f ? accy : (__expf(accy) - 1.f);
  *(float2*)(xout + (size_t)v*128 + c0) = make_float2(ox, oy);
}

// ---------------------------------------------------------------- classifier
__global__ __launch_bounds__(256) void classifier_kernel(
    const float* __restrict__ x, const float* __restrict__ w1c, const float* __restrict__ b1c,
    const float* __restrict__ w2c, const float* __restrict__ b2c, float* __restrict__ out)
{
  __shared__ float sh[4][64];
  const int wid = threadIdx.x >> 6, l = threadIdx.x & 63;
  const int v = blockIdx.x*4 + wid;
  const int vu = __builtin_amdgcn_readfirstlane(v);
  const float* xr = x + (size_t)vu*128;
  float a = b1c[l];
  #pragma unroll 4
  for (int k = 0; k < 128; k++) a = fmaf(xr[k], w1c[k*64 + l], a);
  a = a > 0.f ? a : 0.f;
  sh[wid][l] = a;
  __syncthreads();
  if (l < 25){
    float o = b2c[l];
    #pragma unroll 4
    for (int k = 0; k < 64; k++) o = fmaf(sh[wid][k], w2c[k*25 + l], o);
    out[(size_t)v*25 + l] = o;
  }
}

// ---------------------------------------------------------------- launch
extern "C" void kernel_launch(void* const* d_in, const int* in_sizes, int n_in,
                              void* d_out, int out_size, void* d_ws, size_t ws_size,
                              hipStream_t stream)
{
  (void)in_sizes; (void)n_in; (void)out_size; (void)ws_size;
  const float* x_vis   = (const float*)d_in[0];
  const float* x_sym   = (const float*)d_in[1];
  const int*   ei      = (const int*)  d_in[2];
  const float* ea      = (const float*)d_in[3];
  const float* c1w     = (const float*)d_in[4];
  const float* c1b     = (const float*)d_in[5];
  const float* c2w     = (const float*)d_in[6];
  const float* c2b     = (const float*)d_in[7];
  const float* fcw     = (const float*)d_in[8];
  const float* fcb     = (const float*)d_in[9];
  const float* s1w     = (const float*)d_in[10];
  const float* s1b     = (const float*)d_in[11];
  const float* s2w     = (const float*)d_in[12];
  const float* s2b     = (const float*)d_in[13];
  const float* g1W     = (const float*)d_in[14];
  const float* g1b     = (const float*)d_in[15];
  const float* g1We    = (const float*)d_in[16];
  const float* g1be    = (const float*)d_in[17];
  const float* g1asrc  = (const float*)d_in[18];
  const float* g1adst  = (const float*)d_in[19];
  const float* g1aedge = (const float*)d_in[20];
  const float* g1Wg    = (const float*)d_in[21];
  const float* g1bg    = (const float*)d_in[22];
  const float* g2W     = (const float*)d_in[23];
  const float* g2b     = (const float*)d_in[24];
  const float* g2We    = (const float*)d_in[25];
  const float* g2be    = (const float*)d_in[26];
  const float* g2asrc  = (const float*)d_in[27];
  const float* g2adst  = (const float*)d_in[28];
  const float* g2aedge = (const float*)d_in[29];
  const float* g2Wg    = (const float*)d_in[30];
  const float* g2bg    = (const float*)d_in[31];
  const float* cw1     = (const float*)d_in[32];
  const float* cb1     = (const float*)d_in[33];
  const float* cw2     = (const float*)d_in[34];
  const float* cb2     = (const float*)d_in[35];

  size_t off = 0;
  auto take = [&](size_t bytes) -> void* {
    off = (off + 255) & ~(size_t)255;
    void* p = (char*)d_ws + off;
    off += bytes;
    return p;
  };
  int*   cnt     = (int*)  take((size_t)NND*4);
  int*   offs    = (int*)  take((size_t)(NND+1)*4);
  int4*  srcattr = (int4*) take((size_t)NE*16);
  float* x192    = (float*)take((size_t)NND*192*4);
  float* hbuf    = (float*)take((size_t)NND*128*4);
  float* sbuf    = (float*)take((size_t)NND*4*4);
  float* dbuf    = (float*)take((size_t)NND*4*4);
  float* x2      = (float*)take((size_t)NND*128*4);
  float* x3      = x192;   // x192 is dead after node_transform<192>; reuse as layer-2 output

  // CSR build (graph identical for both GAT layers -> build once per call)
  hipMemsetAsync(cnt, 0, (size_t)NND*4, stream);
  hist_kernel<<<(NE+255)/256, 256, 0, stream>>>(ei, cnt);
  scan_kernel<<<1, 1024, 0, stream>>>(cnt, offs, NND);
  hipMemsetAsync(cnt, 0, (size_t)NND*4, stream);
  scatter_kernel<<<(NE+255)/256, 256, 0, stream>>>(ei, ea, offs, cnt, srcattr);

  // encoders
  uv_sym_kernel<<<NND, 256, 0, stream>>>(x_vis, x_sym, c1w, c1b, c2w, c2b,
                                         fcw, fcb, s1w, s1b, s2w, s2b, x192);
  // GAT layer 1
  node_transform<192><<<NND/4, 256, 0, stream>>>(x192, g1W, g1b, g1asrc, g1adst, hbuf, sbuf, dbuf);
  gat_aggregate<<<NND/4, 256, 0, stream>>>(sbuf, dbuf, hbuf, srcattr, offs,
                                           g1We, g1be, g1aedge, g1Wg, g1bg, x2);
  // GAT layer 2
  node_transform<128><<<NND/4, 256, 0, stream>>>(x2, g2W, g2b, g2asrc, g2adst, hbuf, sbuf, dbuf);
  gat_aggregate<<<NND/4, 256, 0, stream>>>(sbuf, dbuf, hbuf, srcattr, offs,
                                           g2We, g2be, g2aedge, g2Wg, g2bg, x3);
  // classifier
  classifier_kernel<<<NND/4, 256, 0, stream>>>(x3, cw1, cb1, cw2, cb2, (float*)d_out);
}

// Round 2
// 1303.346 us; speedup vs baseline: 2.2361x; 2.2361x over previous
//
#include <hip/hip_runtime.h>

#define NND 50000
#define NE  1600000

typedef __attribute__((ext_vector_type(8))) short bf16x8;
typedef __attribute__((ext_vector_type(4))) float f32x4;

__device__ __forceinline__ float leaky02(float x){ return x > 0.f ? x : 0.2f*x; }
__device__ __forceinline__ unsigned short f2bf(float f){
  unsigned u = __float_as_uint(f);
  u = (u + 0x7fffu + ((u >> 16) & 1u)) >> 16;
  return (unsigned short)u;
}
__device__ __forceinline__ bf16x8 ld_frag(const unsigned short* p){
  return __builtin_bit_cast(bf16x8, *(const uint4*)p);
}

// ---------------------------------------------------------------- CSR build
__global__ __launch_bounds__(256) void hist_kernel(const int* __restrict__ ei,
                                                   int* __restrict__ cnt){
  int e = blockIdx.x*256 + threadIdx.x;
  if (e < NE) atomicAdd(&cnt[ei[NE + e]], 1);
}

__global__ __launch_bounds__(1024) void scan_kernel(const int* __restrict__ cnt,
                                                    int* __restrict__ offsets, int n){
  __shared__ int wsum[16];
  __shared__ int sbase;
  int t = threadIdx.x, lane = t & 63, w = t >> 6;
  if (t == 0) sbase = 0;
  __syncthreads();
  for (int start = 0; start < n; start += 1024){
    int i = start + t;
    int x = (i < n) ? cnt[i] : 0;
    #pragma unroll
    for (int off = 1; off < 64; off <<= 1){ int y = __shfl_up(x, off); if (lane >= off) x += y; }
    if (lane == 63) wsum[w] = x;
    __syncthreads();
    if (w == 0 && lane < 16){
      int sv = wsum[lane];
      #pragma unroll
      for (int off = 1; off < 16; off <<= 1){ int y = __shfl_up(sv, off); if (lane >= off) sv += y; }
      wsum[lane] = sv;
    }
    __syncthreads();
    int base = sbase + (w > 0 ? wsum[w-1] : 0);
    if (i < n) offsets[i+1] = base + x;
    __syncthreads();
    if (t == 0) sbase += wsum[15];
    __syncthreads();
  }
  if (t == 0) offsets[0] = 0;
}

__global__ __launch_bounds__(256) void scatter_kernel(const int* __restrict__ ei,
                                                      const float* __restrict__ ea,
                                                      const int* __restrict__ offsets,
                                                      int* __restrict__ cursor,
                                                      int4* __restrict__ srcattr){
  int e = blockIdx.x*256 + threadIdx.x;
  if (e < NE){
    int dstn = ei[NE + e];
    int pos  = atomicAdd(&cursor[dstn], 1);
    int idx  = offsets[dstn] + pos;
    srcattr[idx] = make_int4(ei[e], __float_as_int(ea[2*e]), __float_as_int(ea[2*e+1]), 0);
  }
}

// -------------------------------------------------- weight pre-transform (bf16)
// W1t: [3 mfma][4 g][32 oc][8 j]  (tap = m*4+g, ic = j; zero-pad tap>8 / ic>5)
// W2t: [9 tap][4 g][64 oc][8 j]   (ic = g*8+j)
__global__ __launch_bounds__(256) void prep_weights(
    const float* __restrict__ w1, const float* __restrict__ w2,
    unsigned short* __restrict__ W1t, unsigned short* __restrict__ W2t)
{
  int t = threadIdx.x;
  if (blockIdx.x == 0){
    for (int i = t; i < 3072; i += 256){
      int j = i & 7, oc = (i >> 3) & 31, g = (i >> 8) & 3, m = i >> 10;
      int tap = m*4 + g;
      float v = (tap < 9 && j < 6) ? w1[oc*54 + j*9 + tap] : 0.f;
      W1t[i] = f2bf(v);
    }
  } else {
    for (int i = t; i < 18432; i += 256){
      int j = i & 7, oc = (i >> 3) & 63, g = (i >> 9) & 3, tap = i >> 11;
      int ic = g*8 + j;
      W2t[i] = f2bf(w2[oc*288 + ic*9 + tap]);
    }
  }
}

// -------------------------------------------- UV + sym encoder, MFMA implicit GEMM
// 4 nodes per block, 1 node per wave. M = 64 px rows/node.
__global__ __launch_bounds__(256, 3) void uv_mfma_kernel(
    const float* __restrict__ x_vis, const float* __restrict__ x_sym,
    const unsigned short* __restrict__ W1t, const unsigned short* __restrict__ W2t,
    const float* __restrict__ b1, const float* __restrict__ b2,
    const float* __restrict__ fcw, const float* __restrict__ fcb,
    const float* __restrict__ s1w, const float* __restrict__ s1b,
    const float* __restrict__ s2w, const float* __restrict__ s2b,
    float* __restrict__ x192)
{
  __shared__ __align__(16) unsigned short xic[4*800];    // [node][10][10][8ic] bf16, zero-padded border
  __shared__ __align__(16) unsigned short c1p[4*4000];   // [node][10][10][40]  bf16 (32 ic + 8 pad), padded border
  __shared__ float pooled[4][64];
  __shared__ float symh[4][64];

  const int t = threadIdx.x;
  const int w = t >> 6, l = t & 63;
  const int g = l >> 4, r16 = l & 15;
  const int xb = r16 & 7, yb = r16 >> 3;
  const int n = blockIdx.x*4 + w;

  // prefetch conv1 B fragments (global, L2-broadcast)
  uint4 B1[3][2];
  #pragma unroll
  for (int m = 0; m < 3; m++)
    #pragma unroll
    for (int nt = 0; nt < 2; nt++)
      B1[m][nt] = *(const uint4*)(W1t + m*1024 + g*256 + (nt*16 + r16)*8);

  // zero LDS (borders must be 0)
  uint4 z4 = {0,0,0,0};
  for (int i = t; i < 400;  i += 256) ((uint4*)xic)[i] = z4;
  for (int i = t; i < 2000; i += 256) ((uint4*)c1p)[i] = z4;
  __syncthreads();

  // stage x_vis -> xic interior (bf16)
  {
    const float* xv = x_vis + (size_t)blockIdx.x * 4 * 384;
    for (int i = t; i < 1536; i += 256){
      int nl = i / 384, rem = i - nl*384;
      int ic = rem >> 6, yx = rem & 63, y = yx >> 3, x = yx & 7;
      xic[nl*800 + ((y+1)*10 + (x+1))*8 + ic] = f2bf(xv[i]);
    }
  }
  __syncthreads();

  // ---- conv1: 3 MFMAs, 4 taps packed per MFMA into K=32 (slots 9..11 zero in B)
  const int t0 = g;     const int dy0 = t0/3, dx0 = t0%3;
  const int t1 = 4 + g; const int dy1 = t1/3, dx1 = t1%3;
  const int dy2 = 2, dx2 = 2;   // tap 8 for all g; g>0 slots have zero weights

  const float b1a = b1[r16], b1c = b1[16 + r16];
  f32x4 acc1[4][2];
  #pragma unroll
  for (int mt = 0; mt < 4; mt++){
    acc1[mt][0] = (f32x4){b1a, b1a, b1a, b1a};
    acc1[mt][1] = (f32x4){b1c, b1c, b1c, b1c};
  }
  const unsigned short* xn = xic + w*800;
  #pragma unroll
  for (int mt = 0; mt < 4; mt++){
    const int Y = mt*2 + yb;
    bf16x8 A0 = ld_frag(xn + (Y+dy0)*80 + (xb+dx0)*8);
    bf16x8 A1 = ld_frag(xn + (Y+dy1)*80 + (xb+dx1)*8);
    bf16x8 A2 = ld_frag(xn + (Y+dy2)*80 + (xb+dx2)*8);
    #pragma unroll
    for (int nt = 0; nt < 2; nt++){
      acc1[mt][nt] = __builtin_amdgcn_mfma_f32_16x16x32_bf16(A0, __builtin_bit_cast(bf16x8, B1[0][nt]), acc1[mt][nt], 0,0,0);
      acc1[mt][nt] = __builtin_amdgcn_mfma_f32_16x16x32_bf16(A1, __builtin_bit_cast(bf16x8, B1[1][nt]), acc1[mt][nt], 0,0,0);
      acc1[mt][nt] = __builtin_amdgcn_mfma_f32_16x16x32_bf16(A2, __builtin_bit_cast(bf16x8, B1[2][nt]), acc1[mt][nt], 0,0,0);
    }
  }
  // write conv1 out (relu, bf16) to c1p interior; D map: row=(l>>4)*4+j, col=l&15
  unsigned short* cn = c1p + w*4000;
  #pragma unroll
  for (int mt = 0; mt < 4; mt++)
    #pragma unroll
    for (int nt = 0; nt < 2; nt++)
      #pragma unroll
      for (int j = 0; j < 4; j++){
        int rowl = g*4 + j;
        int y = mt*2 + (rowl >> 3), x = rowl & 7;
        float v = acc1[mt][nt][j]; v = v > 0.f ? v : 0.f;
        cn[((y+1)*10 + (x+1))*40 + nt*16 + r16] = f2bf(v);
      }
  __syncthreads();

  // ---- conv2: tap-loop implicit GEMM, 9 taps x K=32, tiles 4M x 4N
  float b2v[4];
  #pragma unroll
  for (int nt = 0; nt < 4; nt++) b2v[nt] = b2[nt*16 + r16];
  f32x4 acc2[4][4];
  #pragma unroll
  for (int mt = 0; mt < 4; mt++)
    #pragma unroll
    for (int nt = 0; nt < 4; nt++)
      acc2[mt][nt] = (f32x4){b2v[nt], b2v[nt], b2v[nt], b2v[nt]};

  #pragma unroll
  for (int tap = 0; tap < 9; tap++){
    const int dy = tap/3, dx = tap%3;
    uint4 Bv[4];
    #pragma unroll
    for (int nt = 0; nt < 4; nt++)
      Bv[nt] = *(const uint4*)(W2t + tap*2048 + g*512 + (nt*16 + r16)*8);
    uint4 Av[4];
    #pragma unroll
    for (int mt = 0; mt < 4; mt++){
      int Y = mt*2 + yb + dy, X = xb + dx;
      Av[mt] = *(const uint4*)(cn + (Y*10 + X)*40 + g*8);
    }
    #pragma unroll
    for (int mt = 0; mt < 4; mt++)
      #pragma unroll
      for (int nt = 0; nt < 4; nt++)
        acc2[mt][nt] = __builtin_amdgcn_mfma_f32_16x16x32_bf16(
            __builtin_bit_cast(bf16x8, Av[mt]), __builtin_bit_cast(bf16x8, Bv[nt]), acc2[mt][nt], 0,0,0);
  }

  // relu + mean pool over 64 px
  #pragma unroll
  for (int nt = 0; nt < 4; nt++){
    float s = 0.f;
    #pragma unroll
    for (int mt = 0; mt < 4; mt++)
      #pragma unroll
      for (int j = 0; j < 4; j++){
        float v = acc2[mt][nt][j]; s += (v > 0.f ? v : 0.f);
      }
    s += __shfl_xor(s, 16);
    s += __shfl_xor(s, 32);
    if (l < 16) pooled[w][nt*16 + l] = s * (1.f/64.f);
  }
  // sym layer 1
  {
    const float* xs = x_sym + (size_t)n*3;
    float a = s1b[l] + xs[0]*s1w[l] + xs[1]*s1w[64+l] + xs[2]*s1w[128+l];
    symh[w][l] = a > 0.f ? a : 0.f;
  }
  __syncthreads();

  // fc(64->128) no act + sym2(64->64) relu
  {
    const int c0 = 2*l;
    float a0 = fcb[c0], a1 = fcb[c0+1];
    #pragma unroll 8
    for (int k = 0; k < 64; k++){
      float p = pooled[w][k];
      float2 wv = *(const float2*)(fcw + k*128 + c0);
      a0 = fmaf(p, wv.x, a0);
      a1 = fmaf(p, wv.y, a1);
    }
    float* xo = x192 + (size_t)n*192;
    *(float2*)(xo + c0) = make_float2(a0, a1);
    float a = s2b[l];
    #pragma unroll 8
    for (int k = 0; k < 64; k++) a = fmaf(symh[w][k], s2w[k*64 + l], a);
    xo[128 + l] = a > 0.f ? a : 0.f;
  }
}

// ------------------------------------- per-node transform: h = x@W+b, s=(h.a_src), d=(h.a_dst)
template<int K>
__global__ __launch_bounds__(256) void node_transform(
    const float* __restrict__ xin, const float* __restrict__ W, const float* __restrict__ b,
    const float* __restrict__ asrc, const float* __restrict__ adst,
    float* __restrict__ h_out, float* __restrict__ s_out, float* __restrict__ d_out)
{
  const int v  = blockIdx.x*4 + (threadIdx.x >> 6);
  const int l  = threadIdx.x & 63;
  const int vu = __builtin_amdgcn_readfirstlane(v);
  const float* xr = xin + (size_t)vu*K;
  const int c0 = 2*l;
  float2 acc = { b[c0], b[c0+1] };
  #pragma unroll 4
  for (int k = 0; k < K; k++){
    float xk = xr[k];
    float2 w = *(const float2*)(W + k*128 + c0);
    acc.x = fmaf(xk, w.x, acc.x);
    acc.y = fmaf(xk, w.y, acc.y);
  }
  *(float2*)(h_out + (size_t)v*128 + c0) = acc;
  const int hd = l >> 4;
  float as0 = asrc[hd*32 + (c0&31)], as1 = asrc[hd*32 + ((c0+1)&31)];
  float ad0 = adst[hd*32 + (c0&31)], ad1 = adst[hd*32 + ((c0+1)&31)];
  float sv = acc.x*as0 + acc.y*as1;
  float dv = acc.x*ad0 + acc.y*ad1;
  #pragma unroll
  for (int o = 1; o < 16; o <<= 1){ sv += __shfl_xor(sv, o); dv += __shfl_xor(dv, o); }
  if ((l & 15) == 0){ s_out[v*4 + hd] = sv; d_out[v*4 + hd] = dv; }
}

// -------------------------------------------- GAT aggregation, wave per dst node, no atomics
__global__ __launch_bounds__(256) void gat_aggregate(
    const float* __restrict__ sarr, const float* __restrict__ darr, const float* __restrict__ h,
    const int4* __restrict__ srcattr, const int* __restrict__ offsets,
    const float* __restrict__ We, const float* __restrict__ be,
    const float* __restrict__ aedge, const float* __restrict__ Wg, const float* __restrict__ bgp,
    float* __restrict__ xout)
{
  const int l  = threadIdx.x & 63;
  const int v  = blockIdx.x*4 + (threadIdx.x >> 6);
  const int hd = l >> 4;
  const int c0 = 2*l;

  float ae0 = aedge[hd*32 + (c0&31)];
  float ae1 = aedge[hd*32 + ((c0+1)&31)];
  float we00 = We[c0], we01 = We[c0+1], we10 = We[128+c0], we11 = We[128+c0+1];
  float beA = be[c0], beB = be[c0+1];
  float p0 = we00*ae0 + we01*ae1;
  float p1 = we10*ae0 + we11*ae1;
  float pc = beA*ae0 + beB*ae1;
  #pragma unroll
  for (int o = 1; o < 16; o <<= 1){ p0 += __shfl_xor(p0,o); p1 += __shfl_xor(p1,o); pc += __shfl_xor(pc,o); }
  float P00=__shfl(p0,0), P01=__shfl(p0,16), P02=__shfl(p0,32), P03=__shfl(p0,48);
  float P10=__shfl(p1,0), P11=__shfl(p1,16), P12=__shfl(p1,32), P13=__shfl(p1,48);
  float PC0=__shfl(pc,0), PC1=__shfl(pc,16), PC2=__shfl(pc,32), PC3=__shfl(pc,48);
  const float wg0 = Wg[0], wg1 = Wg[1], bgv = bgp[0];

  const int off = offsets[v];
  const int deg = offsets[v+1] - off;
  const float4 d4 = *(const float4*)(darr + (size_t)v*4);

  float dn0=0.f, dn1=0.f, dn2=0.f, dn3=0.f;
  for (int base = 0; base < deg; base += 64){
    int ii = base + l;
    if (ii < deg){
      int4 sa = srcattr[off + ii];
      float a0 = __int_as_float(sa.y), a1 = __int_as_float(sa.z);
      const float4 sv = *(const float4*)(sarr + (size_t)sa.x*4);
      dn0 += __expf(leaky02(sv.x + d4.x + a0*P00 + a1*P10 + PC0));
      dn1 += __expf(leaky02(sv.y + d4.y + a0*P01 + a1*P11 + PC1));
      dn2 += __expf(leaky02(sv.z + d4.z + a0*P02 + a1*P12 + PC2));
      dn3 += __expf(leaky02(sv.w + d4.w + a0*P03 + a1*P13 + PC3));
    }
  }
  #pragma unroll
  for (int o = 1; o < 64; o <<= 1){
    dn0 += __shfl_xor(dn0,o); dn1 += __shfl_xor(dn1,o);
    dn2 += __shfl_xor(dn2,o); dn3 += __shfl_xor(dn3,o);
  }
  float den = (hd==0)?dn0:(hd==1)?dn1:(hd==2)?dn2:dn3;
  const float rden = 1.f/(den + 1e-16f);

  float accx = 0.f, accy = 0.f;
  for (int base = 0; base < deg; base += 64){
    int ii = base + l;
    float e0=0.f,e1=0.f,e2=0.f,e3=0.f,a0=0.f,a1=0.f,gt=0.f; int sj=0;
    if (ii < deg){
      int4 sa = srcattr[off + ii];
      a0 = __int_as_float(sa.y); a1 = __int_as_float(sa.z); sj = sa.x;
      const float4 sv = *(const float4*)(sarr + (size_t)sa.x*4);
      e0 = __expf(leaky02(sv.x + d4.x + a0*P00 + a1*P10 + PC0));
      e1 = __expf(leaky02(sv.y + d4.y + a0*P01 + a1*P11 + PC1));
      e2 = __expf(leaky02(sv.z + d4.z + a0*P02 + a1*P12 + PC2));
      e3 = __expf(leaky02(sv.w + d4.w + a0*P03 + a1*P13 + PC3));
      gt = 1.f/(1.f + __expf(-(a0*wg0 + a1*wg1 + bgv)));
    }
    int lim = min(64, deg - base);
    for (int j = 0; j < lim; j++){
      float ee0=__shfl(e0,j), ee1=__shfl(e1,j), ee2=__shfl(e2,j), ee3=__shfl(e3,j);
      float aa0=__shfl(a0,j), aa1=__shfl(a1,j), gg=__shfl(gt,j);
      int   ss =__shfl(sj,j);
      float exh = (hd==0)?ee0:(hd==1)?ee1:(hd==2)?ee2:ee3;
      float m = gg * exh * rden;
      const float2 hv = *(const float2*)(h + (size_t)ss*128 + c0);
      float efA = beA + aa0*we00 + aa1*we10;
      float efB = beB + aa0*we01 + aa1*we11;
      accx = fmaf(hv.x + efA, m, accx);
      accy = fmaf(hv.y + efB, m, accy);
    }
  }
  float ox = accx > 0.f ? accx : (__expf(accx) - 1.f);
  float oy = accy > 0.f ? accy : (__expf(accy) - 1.f);
  *(float2*)(xout + (size_t)v*128 + c0) = make_float2(ox, oy);
}

// ---------------------------------------------------------------- classifier
__global__ __launch_bounds__(256) void classifier_kernel(
    const float* __restrict__ x, const float* __restrict__ w1c, const float* __restrict__ b1c,
    const float* __restrict__ w2c, const float* __restrict__ b2c, float* __restrict__ out)
{
  __shared__ float sh[4][64];
  const int wid = threadIdx.x >> 6, l = threadIdx.x & 63;
  const int v = blockIdx.x*4 + wid;
  const int vu = __builtin_amdgcn_readfirstlane(v);
  const float* xr = x + (size_t)vu*128;
  float a = b1c[l];
  #pragma unroll 4
  for (int k = 0; k < 128; k++) a = fmaf(xr[k], w1c[k*64 + l], a);
  a = a > 0.f ? a : 0.f;
  sh[wid][l] = a;
  __syncthreads();
  if (l < 25){
    float o = b2c[l];
    #pragma unroll 4
    for (int k = 0; k < 64; k++) o = fmaf(sh[wid][k], w2c[k*25 + l], o);
    out[(size_t)v*25 + l] = o;
  }
}

// ---------------------------------------------------------------- launch
extern "C" void kernel_launch(void* const* d_in, const int* in_sizes, int n_in,
                              void* d_out, int out_size, void* d_ws, size_t ws_size,
                              hipStream_t stream)
{
  (void)in_sizes; (void)n_in; (void)out_size; (void)ws_size;
  const float* x_vis   = (const float*)d_in[0];
  const float* x_sym   = (const float*)d_in[1];
  const int*   ei      = (const int*)  d_in[2];
  const float* ea      = (const float*)d_in[3];
  const float* c1w     = (const float*)d_in[4];
  const float* c1b     = (const float*)d_in[5];
  const float* c2w     = (const float*)d_in[6];
  const float* c2b     = (const float*)d_in[7];
  const float* fcw     = (const float*)d_in[8];
  const float* fcb     = (const float*)d_in[9];
  const float* s1w     = (const float*)d_in[10];
  const float* s1b     = (const float*)d_in[11];
  const float* s2w     = (const float*)d_in[12];
  const float* s2b     = (const float*)d_in[13];
  const float* g1W     = (const float*)d_in[14];
  const float* g1b     = (const float*)d_in[15];
  const float* g1We    = (const float*)d_in[16];
  const float* g1be    = (const float*)d_in[17];
  const float* g1asrc  = (const float*)d_in[18];
  const float* g1adst  = (const float*)d_in[19];
  const float* g1aedge = (const float*)d_in[20];
  const float* g1Wg    = (const float*)d_in[21];
  const float* g1bg    = (const float*)d_in[22];
  const float* g2W     = (const float*)d_in[23];
  const float* g2b     = (const float*)d_in[24];
  const float* g2We    = (const float*)d_in[25];
  const float* g2be    = (const float*)d_in[26];
  const float* g2asrc  = (const float*)d_in[27];
  const float* g2adst  = (const float*)d_in[28];
  const float* g2aedge = (const float*)d_in[29];
  const float* g2Wg    = (const float*)d_in[30];
  const float* g2bg    = (const float*)d_in[31];
  const float* cw1     = (const float*)d_in[32];
  const float* cb1     = (const float*)d_in[33];
  const float* cw2     = (const float*)d_in[34];
  const float* cb2     = (const float*)d_in[35];

  size_t off = 0;
  auto take = [&](size_t bytes) -> void* {
    off = (off + 255) & ~(size_t)255;
    void* p = (char*)d_ws + off;
    off += bytes;
    return p;
  };
  int*   cnt     = (int*)  take((size_t)NND*4);
  int*   offs    = (int*)  take((size_t)(NND+1)*4);
  int4*  srcattr = (int4*) take((size_t)NE*16);
  float* x192    = (float*)take((size_t)NND*192*4);
  float* hbuf    = (float*)take((size_t)NND*128*4);
  float* sbuf    = (float*)take((size_t)NND*4*4);
  float* dbuf    = (float*)take((size_t)NND*4*4);
  float* x2      = (float*)take((size_t)NND*128*4);
  unsigned short* W1t = (unsigned short*)take(3072*2);
  unsigned short* W2t = (unsigned short*)take(18432*2);
  float* x3      = x192;   // x192 dead after node_transform<192>; reuse as layer-2 output

  // weight pre-transform for MFMA conv
  prep_weights<<<2, 256, 0, stream>>>(c1w, c2w, W1t, W2t);

  // CSR build (graph identical for both GAT layers)
  hipMemsetAsync(cnt, 0, (size_t)NND*4, stream);
  hist_kernel<<<(NE+255)/256, 256, 0, stream>>>(ei, cnt);
  scan_kernel<<<1, 1024, 0, stream>>>(cnt, offs, NND);
  hipMemsetAsync(cnt, 0, (size_t)NND*4, stream);
  scatter_kernel<<<(NE+255)/256, 256, 0, stream>>>(ei, ea, offs, cnt, srcattr);

  // encoders (MFMA)
  uv_mfma_kernel<<<NND/4, 256, 0, stream>>>(x_vis, x_sym, W1t, W2t, c1b, c2b,
                                            fcw, fcb, s1w, s1b, s2w, s2b, x192);
  // GAT layer 1
  node_transform<192><<<NND/4, 256, 0, stream>>>(x192, g1W, g1b, g1asrc, g1adst, hbuf, sbuf, dbuf);
  gat_aggregate<<<NND/4, 256, 0, stream>>>(sbuf, dbuf, hbuf, srcattr, offs,
                                           g1We, g1be, g1aedge, g1Wg, g1bg, x2);
  // GAT layer 2
  node_transform<128><<<NND/4, 256, 0, stream>>>(x2, g2W, g2b, g2asrc, g2adst, hbuf, sbuf, dbuf);
  gat_aggregate<<<NND/4, 256, 0, stream>>>(sbuf, dbuf, hbuf, srcattr, offs,
                                           g2We, g2be, g2aedge, g2Wg, g2bg, x3);
  // classifier
  classifier_kernel<<<NND/4, 256, 0, stream>>>(x3, cw1, cb1, cw2, cb2, (float*)d_out);
}

// Round 3
// 843.866 us; speedup vs baseline: 3.4536x; 1.5445x over previous
//
#include <hip/hip_runtime.h>

#define NND 50000
#define NE  1600000

typedef __attribute__((ext_vector_type(8))) short bf16x8;
typedef __attribute__((ext_vector_type(4))) float f32x4;

__device__ __forceinline__ float leaky02(float x){ return x > 0.f ? x : 0.2f*x; }
__device__ __forceinline__ unsigned short f2bf(float f){
  unsigned u = __float_as_uint(f);
  u = (u + 0x7fffu + ((u >> 16) & 1u)) >> 16;
  return (unsigned short)u;
}
__device__ __forceinline__ float bf2f(unsigned short h){
  return __uint_as_float(((unsigned)h) << 16);
}
__device__ __forceinline__ bf16x8 ld_frag(const unsigned short* p){
  return __builtin_bit_cast(bf16x8, *(const uint4*)p);
}

// ---------------------------------------------------------------- CSR build
__global__ __launch_bounds__(256) void hist_kernel(const int* __restrict__ ei,
                                                   int* __restrict__ cnt){
  int e = blockIdx.x*256 + threadIdx.x;
  if (e < NE) atomicAdd(&cnt[ei[NE + e]], 1);
}

__global__ __launch_bounds__(1024) void scan_kernel(const int* __restrict__ cnt,
                                                    int* __restrict__ offsets, int n){
  __shared__ int wsum[16];
  __shared__ int sbase;
  int t = threadIdx.x, lane = t & 63, w = t >> 6;
  if (t == 0) sbase = 0;
  __syncthreads();
  for (int start = 0; start < n; start += 1024){
    int i = start + t;
    int x = (i < n) ? cnt[i] : 0;
    #pragma unroll
    for (int off = 1; off < 64; off <<= 1){ int y = __shfl_up(x, off); if (lane >= off) x += y; }
    if (lane == 63) wsum[w] = x;
    __syncthreads();
    if (w == 0 && lane < 16){
      int sv = wsum[lane];
      #pragma unroll
      for (int off = 1; off < 16; off <<= 1){ int y = __shfl_up(sv, off); if (lane >= off) sv += y; }
      wsum[lane] = sv;
    }
    __syncthreads();
    int base = sbase + (w > 0 ? wsum[w-1] : 0);
    if (i < n) offsets[i+1] = base + x;
    __syncthreads();
    if (t == 0) sbase += wsum[15];
    __syncthreads();
  }
  if (t == 0) offsets[0] = 0;
}

__global__ __launch_bounds__(256) void scatter_kernel(const int* __restrict__ ei,
                                                      const float* __restrict__ ea,
                                                      const int* __restrict__ offsets,
                                                      int* __restrict__ cursor,
                                                      int4* __restrict__ srcattr){
  int e = blockIdx.x*256 + threadIdx.x;
  if (e < NE){
    int dstn = ei[NE + e];
    int pos  = atomicAdd(&cursor[dstn], 1);
    int idx  = offsets[dstn] + pos;
    srcattr[idx] = make_int4(ei[e], __float_as_int(ea[2*e]), __float_as_int(ea[2*e+1]), 0);
  }
}

// -------------------------------------------------- conv weight pre-transform (bf16)
__global__ __launch_bounds__(256) void prep_weights(
    const float* __restrict__ w1, const float* __restrict__ w2,
    unsigned short* __restrict__ W1t, unsigned short* __restrict__ W2t)
{
  int t = threadIdx.x;
  if (blockIdx.x == 0){
    for (int i = t; i < 3072; i += 256){
      int j = i & 7, oc = (i >> 3) & 31, g = (i >> 8) & 3, m = i >> 10;
      int tap = m*4 + g;
      float v = (tap < 9 && j < 6) ? w1[oc*54 + j*9 + tap] : 0.f;
      W1t[i] = f2bf(v);
    }
  } else {
    for (int i = t; i < 18432; i += 256){
      int j = i & 7, oc = (i >> 3) & 63, g = (i >> 9) & 3, tap = i >> 11;
      int ic = g*8 + j;
      W2t[i] = f2bf(w2[oc*288 + ic*9 + tap]);
    }
  }
}

// -------------------------------------------------- GEMM weight pre-transform: frag-linear hi/lo
// Wf[((ks*8+nt)*64 + l)*8 + j] = W[ks*32 + (l>>4)*8 + j][nt*16 + (l&15)]
__global__ __launch_bounds__(256) void prep_gemm(
    const float* __restrict__ W, int total,
    unsigned short* __restrict__ Wh, unsigned short* __restrict__ Wl)
{
  for (int i = blockIdx.x*256 + threadIdx.x; i < total; i += gridDim.x*256){
    int j = i & 7, lx = (i >> 3) & 63, nt = (i >> 9) & 7, ks = i >> 12;
    int k = ks*32 + (lx >> 4)*8 + j;
    int col = nt*16 + (lx & 15);
    float v = W[k*128 + col];
    unsigned short h16 = f2bf(v);
    Wh[i] = h16;
    Wl[i] = f2bf(v - bf2f(h16));
  }
}

// -------------------------------------------- UV + sym encoder, MFMA implicit GEMM
__global__ __launch_bounds__(256, 3) void uv_mfma_kernel(
    const float* __restrict__ x_vis, const float* __restrict__ x_sym,
    const unsigned short* __restrict__ W1t, const unsigned short* __restrict__ W2t,
    const float* __restrict__ b1, const float* __restrict__ b2,
    const float* __restrict__ fcw, const float* __restrict__ fcb,
    const float* __restrict__ s1w, const float* __restrict__ s1b,
    const float* __restrict__ s2w, const float* __restrict__ s2b,
    float* __restrict__ x192)
{
  __shared__ __align__(16) unsigned short xic[4*800];
  __shared__ __align__(16) unsigned short c1p[4*4000];
  __shared__ float pooled[4][64];
  __shared__ float symh[4][64];

  const int t = threadIdx.x;
  const int w = t >> 6, l = t & 63;
  const int g = l >> 4, r16 = l & 15;
  const int xb = r16 & 7, yb = r16 >> 3;
  const int n = blockIdx.x*4 + w;

  uint4 B1[3][2];
  #pragma unroll
  for (int m = 0; m < 3; m++)
    #pragma unroll
    for (int nt = 0; nt < 2; nt++)
      B1[m][nt] = *(const uint4*)(W1t + m*1024 + g*256 + (nt*16 + r16)*8);

  uint4 z4 = {0,0,0,0};
  for (int i = t; i < 400;  i += 256) ((uint4*)xic)[i] = z4;
  for (int i = t; i < 2000; i += 256) ((uint4*)c1p)[i] = z4;
  __syncthreads();

  {
    const float* xv = x_vis + (size_t)blockIdx.x * 4 * 384;
    for (int i = t; i < 1536; i += 256){
      int nl = i / 384, rem = i - nl*384;
      int ic = rem >> 6, yx = rem & 63, y = yx >> 3, x = yx & 7;
      xic[nl*800 + ((y+1)*10 + (x+1))*8 + ic] = f2bf(xv[i]);
    }
  }
  __syncthreads();

  const int t0 = g;     const int dy0 = t0/3, dx0 = t0%3;
  const int t1 = 4 + g; const int dy1 = t1/3, dx1 = t1%3;
  const int dy2 = 2, dx2 = 2;

  const float b1a = b1[r16], b1c = b1[16 + r16];
  f32x4 acc1[4][2];
  #pragma unroll
  for (int mt = 0; mt < 4; mt++){
    acc1[mt][0] = (f32x4){b1a, b1a, b1a, b1a};
    acc1[mt][1] = (f32x4){b1c, b1c, b1c, b1c};
  }
  const unsigned short* xn = xic + w*800;
  #pragma unroll
  for (int mt = 0; mt < 4; mt++){
    const int Y = mt*2 + yb;
    bf16x8 A0 = ld_frag(xn + (Y+dy0)*80 + (xb+dx0)*8);
    bf16x8 A1 = ld_frag(xn + (Y+dy1)*80 + (xb+dx1)*8);
    bf16x8 A2 = ld_frag(xn + (Y+dy2)*80 + (xb+dx2)*8);
    #pragma unroll
    for (int nt = 0; nt < 2; nt++){
      acc1[mt][nt] = __builtin_amdgcn_mfma_f32_16x16x32_bf16(A0, __builtin_bit_cast(bf16x8, B1[0][nt]), acc1[mt][nt], 0,0,0);
      acc1[mt][nt] = __builtin_amdgcn_mfma_f32_16x16x32_bf16(A1, __builtin_bit_cast(bf16x8, B1[1][nt]), acc1[mt][nt], 0,0,0);
      acc1[mt][nt] = __builtin_amdgcn_mfma_f32_16x16x32_bf16(A2, __builtin_bit_cast(bf16x8, B1[2][nt]), acc1[mt][nt], 0,0,0);
    }
  }
  unsigned short* cn = c1p + w*4000;
  #pragma unroll
  for (int mt = 0; mt < 4; mt++)
    #pragma unroll
    for (int nt = 0; nt < 2; nt++)
      #pragma unroll
      for (int j = 0; j < 4; j++){
        int rowl = g*4 + j;
        int y = mt*2 + (rowl >> 3), x = rowl & 7;
        float v = acc1[mt][nt][j]; v = v > 0.f ? v : 0.f;
        cn[((y+1)*10 + (x+1))*40 + nt*16 + r16] = f2bf(v);
      }
  __syncthreads();

  float b2v[4];
  #pragma unroll
  for (int nt = 0; nt < 4; nt++) b2v[nt] = b2[nt*16 + r16];
  f32x4 acc2[4][4];
  #pragma unroll
  for (int mt = 0; mt < 4; mt++)
    #pragma unroll
    for (int nt = 0; nt < 4; nt++)
      acc2[mt][nt] = (f32x4){b2v[nt], b2v[nt], b2v[nt], b2v[nt]};

  #pragma unroll
  for (int tap = 0; tap < 9; tap++){
    const int dy = tap/3, dx = tap%3;
    uint4 Bv[4];
    #pragma unroll
    for (int nt = 0; nt < 4; nt++)
      Bv[nt] = *(const uint4*)(W2t + tap*2048 + g*512 + (nt*16 + r16)*8);
    uint4 Av[4];
    #pragma unroll
    for (int mt = 0; mt < 4; mt++){
      int Y = mt*2 + yb + dy, X = xb + dx;
      Av[mt] = *(const uint4*)(cn + (Y*10 + X)*40 + g*8);
    }
    #pragma unroll
    for (int mt = 0; mt < 4; mt++)
      #pragma unroll
      for (int nt = 0; nt < 4; nt++)
        acc2[mt][nt] = __builtin_amdgcn_mfma_f32_16x16x32_bf16(
            __builtin_bit_cast(bf16x8, Av[mt]), __builtin_bit_cast(bf16x8, Bv[nt]), acc2[mt][nt], 0,0,0);
  }

  #pragma unroll
  for (int nt = 0; nt < 4; nt++){
    float s = 0.f;
    #pragma unroll
    for (int mt = 0; mt < 4; mt++)
      #pragma unroll
      for (int j = 0; j < 4; j++){
        float v = acc2[mt][nt][j]; s += (v > 0.f ? v : 0.f);
      }
    s += __shfl_xor(s, 16);
    s += __shfl_xor(s, 32);
    if (l < 16) pooled[w][nt*16 + l] = s * (1.f/64.f);
  }
  {
    const float* xs = x_sym + (size_t)n*3;
    float a = s1b[l] + xs[0]*s1w[l] + xs[1]*s1w[64+l] + xs[2]*s1w[128+l];
    symh[w][l] = a > 0.f ? a : 0.f;
  }
  __syncthreads();

  {
    const int c0 = 2*l;
    float a0 = fcb[c0], a1 = fcb[c0+1];
    #pragma unroll 8
    for (int k = 0; k < 64; k++){
      float p = pooled[w][k];
      float2 wv = *(const float2*)(fcw + k*128 + c0);
      a0 = fmaf(p, wv.x, a0);
      a1 = fmaf(p, wv.y, a1);
    }
    float* xo = x192 + (size_t)n*192;
    *(float2*)(xo + c0) = make_float2(a0, a1);
    float a = s2b[l];
    #pragma unroll 8
    for (int k = 0; k < 64; k++) a = fmaf(symh[w][k], s2w[k*64 + l], a);
    xo[128 + l] = a > 0.f ? a : 0.f;
  }
}

// ---------------- node GEMM: h = x@W + b via split-bf16 MFMA; fused s,d dots.
// wave = 16 rows x 128 cols. A-frag row=l&15, k=(l>>4)*8+j; D: row=(l>>4)*4+j, col=l&15.
template<int K>
__global__ __launch_bounds__(256) void node_gemm(
    const float* __restrict__ xin,
    const unsigned short* __restrict__ Wh, const unsigned short* __restrict__ Wl,
    const float* __restrict__ b,
    const float* __restrict__ asrc, const float* __restrict__ adst,
    float* __restrict__ h_out, float* __restrict__ s_out, float* __restrict__ d_out)
{
  const int w = threadIdx.x >> 6, l = threadIdx.x & 63;
  const int g = l >> 4, r16 = l & 15;
  const int wid = blockIdx.x*4 + w;
  if (wid >= NND/16) return;
  const int rowbase = wid*16;

  f32x4 acc[8];
  #pragma unroll
  for (int nt = 0; nt < 8; nt++){
    float bv = b[nt*16 + r16];
    acc[nt] = (f32x4){bv, bv, bv, bv};
  }

  const float* xr = xin + (size_t)(rowbase + r16)*K + g*8;
  #pragma unroll 2
  for (int ks = 0; ks < K/32; ks++){
    float4 xa = *(const float4*)(xr + ks*32);
    float4 xb = *(const float4*)(xr + ks*32 + 4);
    float xs[8] = {xa.x,xa.y,xa.z,xa.w,xb.x,xb.y,xb.z,xb.w};
    bf16x8 Ah, Al;
    #pragma unroll
    for (int j = 0; j < 8; j++){
      unsigned short h16 = f2bf(xs[j]);
      Ah[j] = (short)h16;
      Al[j] = (short)f2bf(xs[j] - bf2f(h16));
    }
    #pragma unroll
    for (int nt = 0; nt < 8; nt++){
      const int fo = (((ks*8 + nt)*64 + l)*8);
      bf16x8 Bh = ld_frag(Wh + fo);
      bf16x8 Bl = ld_frag(Wl + fo);
      acc[nt] = __builtin_amdgcn_mfma_f32_16x16x32_bf16(Ah, Bh, acc[nt], 0,0,0);
      acc[nt] = __builtin_amdgcn_mfma_f32_16x16x32_bf16(Al, Bh, acc[nt], 0,0,0);
      acc[nt] = __builtin_amdgcn_mfma_f32_16x16x32_bf16(Ah, Bl, acc[nt], 0,0,0);
    }
  }

  // write h
  #pragma unroll
  for (int nt = 0; nt < 8; nt++)
    #pragma unroll
    for (int j = 0; j < 4; j++)
      h_out[(size_t)(rowbase + g*4 + j)*128 + nt*16 + r16] = acc[nt][j];

  // fused s,d: per-head dot over that head's 32 channels
  float as_v[8], ad_v[8];
  #pragma unroll
  for (int nt = 0; nt < 8; nt++){
    as_v[nt] = asrc[nt*16 + r16];
    ad_v[nt] = adst[nt*16 + r16];
  }
  float sp[4][4], dp[4][4];
  #pragma unroll
  for (int hd = 0; hd < 4; hd++)
    #pragma unroll
    for (int j = 0; j < 4; j++){
      sp[hd][j] = acc[2*hd][j]*as_v[2*hd] + acc[2*hd+1][j]*as_v[2*hd+1];
      dp[hd][j] = acc[2*hd][j]*ad_v[2*hd] + acc[2*hd+1][j]*ad_v[2*hd+1];
    }
  #pragma unroll
  for (int o = 1; o < 16; o <<= 1)
    #pragma unroll
    for (int hd = 0; hd < 4; hd++)
      #pragma unroll
      for (int j = 0; j < 4; j++){
        sp[hd][j] += __shfl_xor(sp[hd][j], o);
        dp[hd][j] += __shfl_xor(dp[hd][j], o);
      }
  #pragma unroll
  for (int hd = 0; hd < 4; hd++){
    if (r16 == hd)
      #pragma unroll
      for (int j = 0; j < 4; j++)
        s_out[(rowbase + g*4 + j)*4 + hd] = sp[hd][j];
    if (r16 == 8 + hd)
      #pragma unroll
      for (int j = 0; j < 4; j++)
        d_out[(rowbase + g*4 + j)*4 + hd] = dp[hd][j];
  }
}

// -------------------------------------------- GAT aggregation v2, wave per dst node
__global__ __launch_bounds__(256) void gat_aggregate(
    const float* __restrict__ sarr, const float* __restrict__ darr, const float* __restrict__ h,
    const int4* __restrict__ srcattr, const int* __restrict__ offsets,
    const float* __restrict__ We, const float* __restrict__ be,
    const float* __restrict__ aedge, const float* __restrict__ Wg, const float* __restrict__ bgp,
    float* __restrict__ xout)
{
  __shared__ int2 ew[4][2][4][64];   // [wave][buf][head][edge] = {w_bits, src}
  const int l  = threadIdx.x & 63;
  const int w  = threadIdx.x >> 6;
  const int v  = blockIdx.x*4 + w;
  const int hd = l >> 4;
  const int c0 = 2*l;

  // per-head edge-logit projections
  float ae0 = aedge[hd*32 + (c0&31)];
  float ae1 = aedge[hd*32 + ((c0+1)&31)];
  float we00 = We[c0], we01 = We[c0+1], we10 = We[128+c0], we11 = We[128+c0+1];
  float beA = be[c0], beB = be[c0+1];
  float p0 = we00*ae0 + we01*ae1;
  float p1 = we10*ae0 + we11*ae1;
  float pc = beA*ae0 + beB*ae1;
  #pragma unroll
  for (int o = 1; o < 16; o <<= 1){ p0 += __shfl_xor(p0,o); p1 += __shfl_xor(p1,o); pc += __shfl_xor(pc,o); }
  float P00=__shfl(p0,0), P01=__shfl(p0,16), P02=__shfl(p0,32), P03=__shfl(p0,48);
  float P10=__shfl(p1,0), P11=__shfl(p1,16), P12=__shfl(p1,32), P13=__shfl(p1,48);
  float PC0=__shfl(pc,0), PC1=__shfl(pc,16), PC2=__shfl(pc,32), PC3=__shfl(pc,48);
  const float wg0 = Wg[0], wg1 = Wg[1], bgv = bgp[0];

  const int off = offsets[v];
  const int deg = offsets[v+1] - off;
  const float4 d4 = *(const float4*)(darr + (size_t)v*4);

  float dn0=0.f,dn1=0.f,dn2=0.f,dn3=0.f;
  float Sm0=0.f,Sm1=0.f,Sm2=0.f,Sm3=0.f;
  float S00=0.f,S01=0.f,S02=0.f,S03=0.f;
  float S10=0.f,S11=0.f,S12=0.f,S13=0.f;
  float accx=0.f, accy=0.f;

  int pb = 0;
  for (int base = 0; base < deg; base += 64, pb ^= 1){
    int ii = base + l;
    float w0=0.f,w1=0.f,w2=0.f,w3=0.f; int sj=0;
    if (ii < deg){
      int4 sa = srcattr[off + ii];
      sj = sa.x;
      float a0 = __int_as_float(sa.y), a1 = __int_as_float(sa.z);
      const float4 sv = *(const float4*)(sarr + (size_t)sj*4);
      float e0 = __expf(leaky02(sv.x + d4.x + a0*P00 + a1*P10 + PC0));
      float e1 = __expf(leaky02(sv.y + d4.y + a0*P01 + a1*P11 + PC1));
      float e2 = __expf(leaky02(sv.z + d4.z + a0*P02 + a1*P12 + PC2));
      float e3 = __expf(leaky02(sv.w + d4.w + a0*P03 + a1*P13 + PC3));
      float gt = 1.f/(1.f + __expf(-(a0*wg0 + a1*wg1 + bgv)));
      dn0 += e0; dn1 += e1; dn2 += e2; dn3 += e3;
      w0 = gt*e0; w1 = gt*e1; w2 = gt*e2; w3 = gt*e3;
      Sm0 += w0; Sm1 += w1; Sm2 += w2; Sm3 += w3;
      S00 += w0*a0; S01 += w1*a0; S02 += w2*a0; S03 += w3*a0;
      S10 += w0*a1; S11 += w1*a1; S12 += w2*a1; S13 += w3*a1;
    }
    ew[w][pb][0][l] = make_int2(__float_as_int(w0), sj);
    ew[w][pb][1][l] = make_int2(__float_as_int(w1), sj);
    ew[w][pb][2][l] = make_int2(__float_as_int(w2), sj);
    ew[w][pb][3][l] = make_int2(__float_as_int(w3), sj);
    asm volatile("s_waitcnt lgkmcnt(0)" ::: "memory");
    const int2* eb = &ew[w][pb][hd][0];
    int lim = min(64, deg - base);
    #pragma unroll 8
    for (int j = 0; j < lim; j++){
      int2 ws = eb[j];
      float wv = __int_as_float(ws.x);
      const float2 hv = *(const float2*)(h + ((size_t)ws.y << 7) + c0);
      accx = fmaf(hv.x, wv, accx);
      accy = fmaf(hv.y, wv, accy);
    }
  }

  #pragma unroll
  for (int o = 1; o < 64; o <<= 1){
    dn0 += __shfl_xor(dn0,o); dn1 += __shfl_xor(dn1,o); dn2 += __shfl_xor(dn2,o); dn3 += __shfl_xor(dn3,o);
    Sm0 += __shfl_xor(Sm0,o); Sm1 += __shfl_xor(Sm1,o); Sm2 += __shfl_xor(Sm2,o); Sm3 += __shfl_xor(Sm3,o);
    S00 += __shfl_xor(S00,o); S01 += __shfl_xor(S01,o); S02 += __shfl_xor(S02,o); S03 += __shfl_xor(S03,o);
    S10 += __shfl_xor(S10,o); S11 += __shfl_xor(S11,o); S12 += __shfl_xor(S12,o); S13 += __shfl_xor(S13,o);
  }
  float den = (hd==0)?dn0:(hd==1)?dn1:(hd==2)?dn2:dn3;
  float Smh = (hd==0)?Sm0:(hd==1)?Sm1:(hd==2)?Sm2:Sm3;
  float S0h = (hd==0)?S00:(hd==1)?S01:(hd==2)?S02:S03;
  float S1h = (hd==0)?S10:(hd==1)?S11:(hd==2)?S12:S13;
  float rden = 1.f/(den + 1e-16f);
  float ox = (accx + beA*Smh + we00*S0h + we10*S1h) * rden;
  float oy = (accy + beB*Smh + we01*S0h + we11*S1h) * rden;
  ox = ox > 0.f ? ox : (__expf(ox) - 1.f);
  oy = oy > 0.f ? oy : (__expf(oy) - 1.f);
  *(float2*)(xout + (size_t)v*128 + c0) = make_float2(ox, oy);
}

// ---------------------------------------------------------------- classifier
__global__ __launch_bounds__(256) void classifier_kernel(
    const float* __restrict__ x, const float* __restrict__ w1c, const float* __restrict__ b1c,
    const float* __restrict__ w2c, const float* __restrict__ b2c, float* __restrict__ out)
{
  __shared__ float sh[4][64];
  const int wid = threadIdx.x >> 6, l = threadIdx.x & 63;
  const int v = blockIdx.x*4 + wid;
  const int vu = __builtin_amdgcn_readfirstlane(v);
  const float* xr = x + (size_t)vu*128;
  float a = b1c[l];
  #pragma unroll 4
  for (int k = 0; k < 128; k++) a = fmaf(xr[k], w1c[k*64 + l], a);
  a = a > 0.f ? a : 0.f;
  sh[wid][l] = a;
  __syncthreads();
  if (l < 25){
    float o = b2c[l];
    #pragma unroll 4
    for (int k = 0; k < 64; k++) o = fmaf(sh[wid][k], w2c[k*25 + l], o);
    out[(size_t)v*25 + l] = o;
  }
}

// ---------------------------------------------------------------- launch
extern "C" void kernel_launch(void* const* d_in, const int* in_sizes, int n_in,
                              void* d_out, int out_size, void* d_ws, size_t ws_size,
                              hipStream_t stream)
{
  (void)in_sizes; (void)n_in; (void)out_size; (void)ws_size;
  const float* x_vis   = (const float*)d_in[0];
  const float* x_sym   = (const float*)d_in[1];
  const int*   ei      = (const int*)  d_in[2];
  const float* ea      = (const float*)d_in[3];
  const float* c1w     = (const float*)d_in[4];
  const float* c1b     = (const float*)d_in[5];
  const float* c2w     = (const float*)d_in[6];
  const float* c2b     = (const float*)d_in[7];
  const float* fcw     = (const float*)d_in[8];
  const float* fcb     = (const float*)d_in[9];
  const float* s1w     = (const float*)d_in[10];
  const float* s1b     = (const float*)d_in[11];
  const float* s2w     = (const float*)d_in[12];
  const float* s2b     = (const float*)d_in[13];
  const float* g1W     = (const float*)d_in[14];
  const float* g1b     = (const float*)d_in[15];
  const float* g1We    = (const float*)d_in[16];
  const float* g1be    = (const float*)d_in[17];
  const float* g1asrc  = (const float*)d_in[18];
  const float* g1adst  = (const float*)d_in[19];
  const float* g1aedge = (const float*)d_in[20];
  const float* g1Wg    = (const float*)d_in[21];
  const float* g1bg    = (const float*)d_in[22];
  const float* g2W     = (const float*)d_in[23];
  const float* g2b     = (const float*)d_in[24];
  const float* g2We    = (const float*)d_in[25];
  const float* g2be    = (const float*)d_in[26];
  const float* g2asrc  = (const float*)d_in[27];
  const float* g2adst  = (const float*)d_in[28];
  const float* g2aedge = (const float*)d_in[29];
  const float* g2Wg    = (const float*)d_in[30];
  const float* g2bg    = (const float*)d_in[31];
  const float* cw1     = (const float*)d_in[32];
  const float* cb1     = (const float*)d_in[33];
  const float* cw2     = (const float*)d_in[34];
  const float* cb2     = (const float*)d_in[35];

  size_t off = 0;
  auto take = [&](size_t bytes) -> void* {
    off = (off + 255) & ~(size_t)255;
    void* p = (char*)d_ws + off;
    off += bytes;
    return p;
  };
  int*   cnt     = (int*)  take((size_t)NND*4);
  int*   offs    = (int*)  take((size_t)(NND+1)*4);
  int4*  srcattr = (int4*) take((size_t)NE*16);
  float* x192    = (float*)take((size_t)NND*192*4);
  float* hbuf    = (float*)take((size_t)NND*128*4);
  float* sbuf    = (float*)take((size_t)NND*4*4);
  float* dbuf    = (float*)take((size_t)NND*4*4);
  float* x2      = (float*)take((size_t)NND*128*4);
  unsigned short* W1t = (unsigned short*)take(3072*2);
  unsigned short* W2t = (unsigned short*)take(18432*2);
  unsigned short* G1h = (unsigned short*)take(24576*2);
  unsigned short* G1l = (unsigned short*)take(24576*2);
  unsigned short* G2h = (unsigned short*)take(16384*2);
  unsigned short* G2l = (unsigned short*)take(16384*2);
  float* x3      = x192;   // x192 dead after node_gemm<192>; reuse as layer-2 output

  // weight pre-transforms
  prep_weights<<<2, 256, 0, stream>>>(c1w, c2w, W1t, W2t);
  prep_gemm<<<96, 256, 0, stream>>>(g1W, 24576, G1h, G1l);
  prep_gemm<<<64, 256, 0, stream>>>(g2W, 16384, G2h, G2l);

  // CSR build (graph identical for both GAT layers)
  hipMemsetAsync(cnt, 0, (size_t)NND*4, stream);
  hist_kernel<<<(NE+255)/256, 256, 0, stream>>>(ei, cnt);
  scan_kernel<<<1, 1024, 0, stream>>>(cnt, offs, NND);
  hipMemsetAsync(cnt, 0, (size_t)NND*4, stream);
  scatter_kernel<<<(NE+255)/256, 256, 0, stream>>>(ei, ea, offs, cnt, srcattr);

  // encoders (MFMA)
  uv_mfma_kernel<<<NND/4, 256, 0, stream>>>(x_vis, x_sym, W1t, W2t, c1b, c2b,
                                            fcw, fcb, s1w, s1b, s2w, s2b, x192);
  // GAT layer 1
  node_gemm<192><<<(NND/16 + 3)/4, 256, 0, stream>>>(x192, G1h, G1l, g1b, g1asrc, g1adst,
                                                     hbuf, sbuf, dbuf);
  gat_aggregate<<<NND/4, 256, 0, stream>>>(sbuf, dbuf, hbuf, srcattr, offs,
                                           g1We, g1be, g1aedge, g1Wg, g1bg, x2);
  // GAT layer 2
  node_gemm<128><<<(NND/16 + 3)/4, 256, 0, stream>>>(x2, G2h, G2l, g2b, g2asrc, g2adst,
                                                     hbuf, sbuf, dbuf);
  gat_aggregate<<<NND/4, 256, 0, stream>>>(sbuf, dbuf, hbuf, srcattr, offs,
                                           g2We, g2be, g2aedge, g2Wg, g2bg, x3);
  // classifier
  classifier_kernel<<<NND/4, 256, 0, stream>>>(x3, cw1, cb1, cw2, cb2, (float*)d_out);
}

// Round 4
// 780.437 us; speedup vs baseline: 3.7343x; 1.0813x over previous
//
#include <hip/hip_runtime.h>

#define NND 50000
#define NE  1600000

typedef __attribute__((ext_vector_type(8))) short bf16x8;
typedef __attribute__((ext_vector_type(4))) float f32x4;

__device__ __forceinline__ float leaky02(float x){ return x > 0.f ? x : 0.2f*x; }
__device__ __forceinline__ unsigned short f2bf(float f){
  unsigned u = __float_as_uint(f);
  u = (u + 0x7fffu + ((u >> 16) & 1u)) >> 16;
  return (unsigned short)u;
}
__device__ __forceinline__ float bf2f(unsigned short h){
  return __uint_as_float(((unsigned)h) << 16);
}
__device__ __forceinline__ bf16x8 ld_frag(const unsigned short* p){
  return __builtin_bit_cast(bf16x8, *(const uint4*)p);
}

// ---------------------------------------------------------------- CSR build
__global__ __launch_bounds__(256) void hist_kernel(const int* __restrict__ ei,
                                                   int* __restrict__ cnt){
  int e = blockIdx.x*256 + threadIdx.x;
  if (e < NE) atomicAdd(&cnt[ei[NE + e]], 1);
}

__global__ __launch_bounds__(1024) void scan_kernel(const int* __restrict__ cnt,
                                                    int* __restrict__ offsets, int n){
  __shared__ int wsum[16];
  __shared__ int sbase;
  int t = threadIdx.x, lane = t & 63, w = t >> 6;
  if (t == 0) sbase = 0;
  __syncthreads();
  for (int start = 0; start < n; start += 1024){
    int i = start + t;
    int x = (i < n) ? cnt[i] : 0;
    #pragma unroll
    for (int off = 1; off < 64; off <<= 1){ int y = __shfl_up(x, off); if (lane >= off) x += y; }
    if (lane == 63) wsum[w] = x;
    __syncthreads();
    if (w == 0 && lane < 16){
      int sv = wsum[lane];
      #pragma unroll
      for (int off = 1; off < 16; off <<= 1){ int y = __shfl_up(sv, off); if (lane >= off) sv += y; }
      wsum[lane] = sv;
    }
    __syncthreads();
    int base = sbase + (w > 0 ? wsum[w-1] : 0);
    if (i < n) offsets[i+1] = base + x;
    __syncthreads();
    if (t == 0) sbase += wsum[15];
    __syncthreads();
  }
  if (t == 0) offsets[0] = 0;
}

__global__ __launch_bounds__(256) void scatter_kernel(const int* __restrict__ ei,
                                                      const float* __restrict__ ea,
                                                      const int* __restrict__ offsets,
                                                      int* __restrict__ cursor,
                                                      int4* __restrict__ srcattr){
  int e = blockIdx.x*256 + threadIdx.x;
  if (e < NE){
    int dstn = ei[NE + e];
    int pos  = atomicAdd(&cursor[dstn], 1);
    int idx  = offsets[dstn] + pos;
    srcattr[idx] = make_int4(ei[e], __float_as_int(ea[2*e]), __float_as_int(ea[2*e+1]), 0);
  }
}

// -------------------------------------------------- conv weight pre-transform (bf16)
__global__ __launch_bounds__(256) void prep_weights(
    const float* __restrict__ w1, const float* __restrict__ w2,
    unsigned short* __restrict__ W1t, unsigned short* __restrict__ W2t)
{
  int t = threadIdx.x;
  if (blockIdx.x == 0){
    for (int i = t; i < 3072; i += 256){
      int j = i & 7, oc = (i >> 3) & 31, g = (i >> 8) & 3, m = i >> 10;
      int tap = m*4 + g;
      float v = (tap < 9 && j < 6) ? w1[oc*54 + j*9 + tap] : 0.f;
      W1t[i] = f2bf(v);
    }
  } else {
    for (int i = t; i < 18432; i += 256){
      int j = i & 7, oc = (i >> 3) & 63, g = (i >> 9) & 3, tap = i >> 11;
      int ic = g*8 + j;
      W2t[i] = f2bf(w2[oc*288 + ic*9 + tap]);
    }
  }
}

// -------------------------------------------------- fold uvfc into layer-1 W: Weff[128][128]
// rows 0..63  : fcw @ g1W[0:128,:]      (pooled path)
// rows 64..127: g1W[128:192,:]          (sym path)
// beff = g1b + fcb @ g1W[0:128,:]
__global__ __launch_bounds__(256) void prep_fold(
    const float* __restrict__ fcw, const float* __restrict__ fcb,
    const float* __restrict__ g1W, const float* __restrict__ g1b,
    float* __restrict__ Weff, float* __restrict__ beff)
{
  int idx = blockIdx.x*256 + threadIdx.x;
  if (idx < 16384){
    int r = idx >> 7, c = idx & 127;
    float acc;
    if (r < 64){
      acc = 0.f;
      #pragma unroll 4
      for (int m = 0; m < 128; m++) acc += fcw[r*128 + m] * g1W[m*128 + c];
    } else {
      acc = g1W[(64 + r)*128 + c];
    }
    Weff[idx] = acc;
  }
  if (blockIdx.x == 0 && threadIdx.x < 128){
    int c = threadIdx.x;
    float acc = g1b[c];
    #pragma unroll 4
    for (int m = 0; m < 128; m++) acc += fcb[m] * g1W[m*128 + c];
    beff[c] = acc;
  }
}

// -------------------------------------------------- GEMM weight pre-transform: frag-linear hi/lo
// Wf[((ks*8+nt)*64 + l)*8 + j] = W[ks*32 + (l>>4)*8 + j][nt*16 + (l&15)]   (K=128 -> total 16384)
__global__ __launch_bounds__(256) void prep_gemm(
    const float* __restrict__ W, int total,
    unsigned short* __restrict__ Wh, unsigned short* __restrict__ Wl)
{
  for (int i = blockIdx.x*256 + threadIdx.x; i < total; i += gridDim.x*256){
    int j = i & 7, lx = (i >> 3) & 63, nt = (i >> 9) & 7, ks = i >> 12;
    int k = ks*32 + (lx >> 4)*8 + j;
    int col = nt*16 + (lx & 15);
    float v = W[k*128 + col];
    unsigned short h16 = f2bf(v);
    Wh[i] = h16;
    Wl[i] = f2bf(v - bf2f(h16));
  }
}

// -------------------------------------------- UV + sym encoder, MFMA, 1 node/wave, NO barriers
// writes x128[n] = [pooled(64) | sym2(64)]
__global__ __launch_bounds__(128, 4) void uv_mfma_kernel(
    const float* __restrict__ x_vis, const float* __restrict__ x_sym,
    const unsigned short* __restrict__ W1t, const unsigned short* __restrict__ W2t,
    const float* __restrict__ b1, const float* __restrict__ b2,
    const float* __restrict__ s1w, const float* __restrict__ s1b,
    const float* __restrict__ s2w, const float* __restrict__ s2b,
    float* __restrict__ x128)
{
  __shared__ __align__(16) unsigned short xic[2*800];    // per-node [10][10][8ic] bf16
  __shared__ __align__(16) unsigned short c1p[2*4000];   // per-node [10][10][40] bf16
  __shared__ float symh[2][64];

  const int t = threadIdx.x;
  const int w = t >> 6, l = t & 63;
  const int g = l >> 4, r16 = l & 15;
  const int xb = r16 & 7, yb = r16 >> 3;
  const int n = blockIdx.x*2 + w;

  // prefetch conv1 B fragments (global, L1/L2-broadcast)
  uint4 B1[3][2];
  #pragma unroll
  for (int m = 0; m < 3; m++)
    #pragma unroll
    for (int nt = 0; nt < 2; nt++)
      B1[m][nt] = *(const uint4*)(W1t + m*1024 + g*256 + (nt*16 + r16)*8);

  // zero this wave's LDS (borders must be 0)
  uint4 z4 = {0,0,0,0};
  {
    uint4* zx = (uint4*)(xic + w*800);
    for (int i = l; i < 100; i += 64) zx[i] = z4;
    uint4* zc = (uint4*)(c1p + w*4000);
    for (int i = l; i < 500; i += 64) zc[i] = z4;
  }

  // stage x_vis -> xic interior (bf16), wave-private
  {
    const float* xv = x_vis + (size_t)n*384;
    for (int i = l; i < 384; i += 64){
      int ic = i >> 6, yx = i & 63, y = yx >> 3, x = yx & 7;
      xic[w*800 + ((y+1)*10 + (x+1))*8 + ic] = f2bf(xv[i]);
    }
  }

  // ---- conv1: 3 MFMAs, 4 taps packed per MFMA into K=32
  const int t0 = g;     const int dy0 = t0/3, dx0 = t0%3;
  const int t1 = 4 + g; const int dy1 = t1/3, dx1 = t1%3;
  const int dy2 = 2, dx2 = 2;

  const float b1a = b1[r16], b1c = b1[16 + r16];
  f32x4 acc1[4][2];
  #pragma unroll
  for (int mt = 0; mt < 4; mt++){
    acc1[mt][0] = (f32x4){b1a, b1a, b1a, b1a};
    acc1[mt][1] = (f32x4){b1c, b1c, b1c, b1c};
  }
  const unsigned short* xn = xic + w*800;
  #pragma unroll
  for (int mt = 0; mt < 4; mt++){
    const int Y = mt*2 + yb;
    bf16x8 A0 = ld_frag(xn + (Y+dy0)*80 + (xb+dx0)*8);
    bf16x8 A1 = ld_frag(xn + (Y+dy1)*80 + (xb+dx1)*8);
    bf16x8 A2 = ld_frag(xn + (Y+dy2)*80 + (xb+dx2)*8);
    #pragma unroll
    for (int nt = 0; nt < 2; nt++){
      acc1[mt][nt] = __builtin_amdgcn_mfma_f32_16x16x32_bf16(A0, __builtin_bit_cast(bf16x8, B1[0][nt]), acc1[mt][nt], 0,0,0);
      acc1[mt][nt] = __builtin_amdgcn_mfma_f32_16x16x32_bf16(A1, __builtin_bit_cast(bf16x8, B1[1][nt]), acc1[mt][nt], 0,0,0);
      acc1[mt][nt] = __builtin_amdgcn_mfma_f32_16x16x32_bf16(A2, __builtin_bit_cast(bf16x8, B1[2][nt]), acc1[mt][nt], 0,0,0);
    }
  }
  unsigned short* cn = c1p + w*4000;
  #pragma unroll
  for (int mt = 0; mt < 4; mt++)
    #pragma unroll
    for (int nt = 0; nt < 2; nt++)
      #pragma unroll
      for (int j = 0; j < 4; j++){
        int rowl = g*4 + j;
        int y = mt*2 + (rowl >> 3), x = rowl & 7;
        float v = acc1[mt][nt][j]; v = v > 0.f ? v : 0.f;
        cn[((y+1)*10 + (x+1))*40 + nt*16 + r16] = f2bf(v);
      }

  // ---- conv2: tap-loop implicit GEMM, 9 taps x K=32, tiles 4M x 4N
  float b2v[4];
  #pragma unroll
  for (int nt = 0; nt < 4; nt++) b2v[nt] = b2[nt*16 + r16];
  f32x4 acc2[4][4];
  #pragma unroll
  for (int mt = 0; mt < 4; mt++)
    #pragma unroll
    for (int nt = 0; nt < 4; nt++)
      acc2[mt][nt] = (f32x4){b2v[nt], b2v[nt], b2v[nt], b2v[nt]};

  #pragma unroll
  for (int tap = 0; tap < 9; tap++){
    const int dy = tap/3, dx = tap%3;
    uint4 Bv[4];
    #pragma unroll
    for (int nt = 0; nt < 4; nt++)
      Bv[nt] = *(const uint4*)(W2t + tap*2048 + g*512 + (nt*16 + r16)*8);
    uint4 Av[4];
    #pragma unroll
    for (int mt = 0; mt < 4; mt++){
      int Y = mt*2 + yb + dy, X = xb + dx;
      Av[mt] = *(const uint4*)(cn + (Y*10 + X)*40 + g*8);
    }
    #pragma unroll
    for (int mt = 0; mt < 4; mt++)
      #pragma unroll
      for (int nt = 0; nt < 4; nt++)
        acc2[mt][nt] = __builtin_amdgcn_mfma_f32_16x16x32_bf16(
            __builtin_bit_cast(bf16x8, Av[mt]), __builtin_bit_cast(bf16x8, Bv[nt]), acc2[mt][nt], 0,0,0);
  }

  // relu + mean pool over 64 px -> x128[0:64]
  float* xo = x128 + (size_t)n*128;
  #pragma unroll
  for (int nt = 0; nt < 4; nt++){
    float s = 0.f;
    #pragma unroll
    for (int mt = 0; mt < 4; mt++)
      #pragma unroll
      for (int j = 0; j < 4; j++){
        float v = acc2[mt][nt][j]; s += (v > 0.f ? v : 0.f);
      }
    s += __shfl_xor(s, 16);
    s += __shfl_xor(s, 32);
    if (l < 16) xo[nt*16 + l] = s * (1.f/64.f);
  }
  // sym layer 1 (wave-private)
  {
    const float* xs = x_sym + (size_t)n*3;
    float a = s1b[l] + xs[0]*s1w[l] + xs[1]*s1w[64+l] + xs[2]*s1w[128+l];
    symh[w][l] = a > 0.f ? a : 0.f;
  }
  // sym layer 2 -> x128[64:128]
  {
    float a = s2b[l];
    #pragma unroll 8
    for (int k = 0; k < 64; k++) a = fmaf(symh[w][k], s2w[k*64 + l], a);
    xo[64 + l] = a > 0.f ? a : 0.f;
  }
}

// ---------------- node GEMM: h = x@W + b via split-bf16 MFMA; fused s,d dots; h stored bf16.
template<int K>
__global__ __launch_bounds__(256) void node_gemm(
    const float* __restrict__ xin,
    const unsigned short* __restrict__ Wh, const unsigned short* __restrict__ Wl,
    const float* __restrict__ b,
    const float* __restrict__ asrc, const float* __restrict__ adst,
    unsigned short* __restrict__ h_out, float* __restrict__ s_out, float* __restrict__ d_out)
{
  const int w = threadIdx.x >> 6, l = threadIdx.x & 63;
  const int g = l >> 4, r16 = l & 15;
  const int wid = blockIdx.x*4 + w;
  if (wid >= NND/16) return;
  const int rowbase = wid*16;

  f32x4 acc[8];
  #pragma unroll
  for (int nt = 0; nt < 8; nt++){
    float bv = b[nt*16 + r16];
    acc[nt] = (f32x4){bv, bv, bv, bv};
  }

  const float* xr = xin + (size_t)(rowbase + r16)*K + g*8;
  #pragma unroll 2
  for (int ks = 0; ks < K/32; ks++){
    float4 xa = *(const float4*)(xr + ks*32);
    float4 xb = *(const float4*)(xr + ks*32 + 4);
    float xs[8] = {xa.x,xa.y,xa.z,xa.w,xb.x,xb.y,xb.z,xb.w};
    bf16x8 Ah, Al;
    #pragma unroll
    for (int j = 0; j < 8; j++){
      unsigned short h16 = f2bf(xs[j]);
      Ah[j] = (short)h16;
      Al[j] = (short)f2bf(xs[j] - bf2f(h16));
    }
    #pragma unroll
    for (int nt = 0; nt < 8; nt++){
      const int fo = (((ks*8 + nt)*64 + l)*8);
      bf16x8 Bh = ld_frag(Wh + fo);
      bf16x8 Bl = ld_frag(Wl + fo);
      acc[nt] = __builtin_amdgcn_mfma_f32_16x16x32_bf16(Ah, Bh, acc[nt], 0,0,0);
      acc[nt] = __builtin_amdgcn_mfma_f32_16x16x32_bf16(Al, Bh, acc[nt], 0,0,0);
      acc[nt] = __builtin_amdgcn_mfma_f32_16x16x32_bf16(Ah, Bl, acc[nt], 0,0,0);
    }
  }

  // write h (bf16)
  #pragma unroll
  for (int nt = 0; nt < 8; nt++)
    #pragma unroll
    for (int j = 0; j < 4; j++)
      h_out[(size_t)(rowbase + g*4 + j)*128 + nt*16 + r16] = f2bf(acc[nt][j]);

  // fused s,d: per-head dot over that head's 32 channels
  float as_v[8], ad_v[8];
  #pragma unroll
  for (int nt = 0; nt < 8; nt++){
    as_v[nt] = asrc[nt*16 + r16];
    ad_v[nt] = adst[nt*16 + r16];
  }
  float sp[4][4], dp[4][4];
  #pragma unroll
  for (int hd = 0; hd < 4; hd++)
    #pragma unroll
    for (int j = 0; j < 4; j++){
      sp[hd][j] = acc[2*hd][j]*as_v[2*hd] + acc[2*hd+1][j]*as_v[2*hd+1];
      dp[hd][j] = acc[2*hd][j]*ad_v[2*hd] + acc[2*hd+1][j]*ad_v[2*hd+1];
    }
  #pragma unroll
  for (int o = 1; o < 16; o <<= 1)
    #pragma unroll
    for (int hd = 0; hd < 4; hd++)
      #pragma unroll
      for (int j = 0; j < 4; j++){
        sp[hd][j] += __shfl_xor(sp[hd][j], o);
        dp[hd][j] += __shfl_xor(dp[hd][j], o);
      }
  #pragma unroll
  for (int hd = 0; hd < 4; hd++){
    if (r16 == hd)
      #pragma unroll
      for (int j = 0; j < 4; j++)
        s_out[(rowbase + g*4 + j)*4 + hd] = sp[hd][j];
    if (r16 == 8 + hd)
      #pragma unroll
      for (int j = 0; j < 4; j++)
        d_out[(rowbase + g*4 + j)*4 + hd] = dp[hd][j];
  }
}

// -------------------------------------------- GAT aggregation, wave per dst node, bf16 h gather
__global__ __launch_bounds__(256) void gat_aggregate(
    const float* __restrict__ sarr, const float* __restrict__ darr,
    const unsigned short* __restrict__ hb,
    const int4* __restrict__ srcattr, const int* __restrict__ offsets,
    const float* __restrict__ We, const float* __restrict__ be,
    const float* __restrict__ aedge, const float* __restrict__ Wg, const float* __restrict__ bgp,
    float* __restrict__ xout)
{
  __shared__ int2 ew[4][2][4][64];   // [wave][buf][head][edge] = {w_bits, src}
  const int l  = threadIdx.x & 63;
  const int w  = threadIdx.x >> 6;
  const int v  = blockIdx.x*4 + w;
  const int hd = l >> 4;
  const int c0 = 2*l;

  float ae0 = aedge[hd*32 + (c0&31)];
  float ae1 = aedge[hd*32 + ((c0+1)&31)];
  float we00 = We[c0], we01 = We[c0+1], we10 = We[128+c0], we11 = We[128+c0+1];
  float beA = be[c0], beB = be[c0+1];
  float p0 = we00*ae0 + we01*ae1;
  float p1 = we10*ae0 + we11*ae1;
  float pc = beA*ae0 + beB*ae1;
  #pragma unroll
  for (int o = 1; o < 16; o <<= 1){ p0 += __shfl_xor(p0,o); p1 += __shfl_xor(p1,o); pc += __shfl_xor(pc,o); }
  float P00=__shfl(p0,0), P01=__shfl(p0,16), P02=__shfl(p0,32), P03=__shfl(p0,48);
  float P10=__shfl(p1,0), P11=__shfl(p1,16), P12=__shfl(p1,32), P13=__shfl(p1,48);
  float PC0=__shfl(pc,0), PC1=__shfl(pc,16), PC2=__shfl(pc,32), PC3=__shfl(pc,48);
  const float wg0 = Wg[0], wg1 = Wg[1], bgv = bgp[0];

  const int off = offsets[v];
  const int deg = offsets[v+1] - off;
  const float4 d4 = *(const float4*)(darr + (size_t)v*4);

  float dn0=0.f,dn1=0.f,dn2=0.f,dn3=0.f;
  float Sm0=0.f,Sm1=0.f,Sm2=0.f,Sm3=0.f;
  float S00=0.f,S01=0.f,S02=0.f,S03=0.f;
  float S10=0.f,S11=0.f,S12=0.f,S13=0.f;
  float accx=0.f, accy=0.f;

  int pb = 0;
  for (int base = 0; base < deg; base += 64, pb ^= 1){
    int ii = base + l;
    float w0=0.f,w1=0.f,w2=0.f,w3=0.f; int sj=0;
    if (ii < deg){
      int4 sa = srcattr[off + ii];
      sj = sa.x;
      float a0 = __int_as_float(sa.y), a1 = __int_as_float(sa.z);
      const float4 sv = *(const float4*)(sarr + (size_t)sj*4);
      float e0 = __expf(leaky02(sv.x + d4.x + a0*P00 + a1*P10 + PC0));
      float e1 = __expf(leaky02(sv.y + d4.y + a0*P01 + a1*P11 + PC1));
      float e2 = __expf(leaky02(sv.z + d4.z + a0*P02 + a1*P12 + PC2));
      float e3 = __expf(leaky02(sv.w + d4.w + a0*P03 + a1*P13 + PC3));
      float gt = 1.f/(1.f + __expf(-(a0*wg0 + a1*wg1 + bgv)));
      dn0 += e0; dn1 += e1; dn2 += e2; dn3 += e3;
      w0 = gt*e0; w1 = gt*e1; w2 = gt*e2; w3 = gt*e3;
      Sm0 += w0; Sm1 += w1; Sm2 += w2; Sm3 += w3;
      S00 += w0*a0; S01 += w1*a0; S02 += w2*a0; S03 += w3*a0;
      S10 += w0*a1; S11 += w1*a1; S12 += w2*a1; S13 += w3*a1;
    }
    ew[w][pb][0][l] = make_int2(__float_as_int(w0), sj);
    ew[w][pb][1][l] = make_int2(__float_as_int(w1), sj);
    ew[w][pb][2][l] = make_int2(__float_as_int(w2), sj);
    ew[w][pb][3][l] = make_int2(__float_as_int(w3), sj);
    asm volatile("s_waitcnt lgkmcnt(0)" ::: "memory");
    const int2* eb = &ew[w][pb][hd][0];
    int lim = min(64, deg - base);
    #pragma unroll 8
    for (int j = 0; j < lim; j++){
      int2 ws = eb[j];
      float wv = __int_as_float(ws.x);
      unsigned hv = *(const unsigned*)(hb + (((size_t)ws.y) << 7) + c0);
      accx = fmaf(__uint_as_float(hv << 16), wv, accx);
      accy = fmaf(__uint_as_float(hv & 0xffff0000u), wv, accy);
    }
  }

  #pragma unroll
  for (int o = 1; o < 64; o <<= 1){
    dn0 += __shfl_xor(dn0,o); dn1 += __shfl_xor(dn1,o); dn2 += __shfl_xor(dn2,o); dn3 += __shfl_xor(dn3,o);
    Sm0 += __shfl_xor(Sm0,o); Sm1 += __shfl_xor(Sm1,o); Sm2 += __shfl_xor(Sm2,o); Sm3 += __shfl_xor(Sm3,o);
    S00 += __shfl_xor(S00,o); S01 += __shfl_xor(S01,o); S02 += __shfl_xor(S02,o); S03 += __shfl_xor(S03,o);
    S10 += __shfl_xor(S10,o); S11 += __shfl_xor(S11,o); S12 += __shfl_xor(S12,o); S13 += __shfl_xor(S13,o);
  }
  float den = (hd==0)?dn0:(hd==1)?dn1:(hd==2)?dn2:dn3;
  float Smh = (hd==0)?Sm0:(hd==1)?Sm1:(hd==2)?Sm2:Sm3;
  float S0h = (hd==0)?S00:(hd==1)?S01:(hd==2)?S02:S03;
  float S1h = (hd==0)?S10:(hd==1)?S11:(hd==2)?S12:S13;
  float rden = 1.f/(den + 1e-16f);
  float ox = (accx + beA*Smh + we00*S0h + we10*S1h) * rden;
  float oy = (accy + beB*Smh + we01*S0h + we11*S1h) * rden;
  ox = ox > 0.f ? ox : (__expf(ox) - 1.f);
  oy = oy > 0.f ? oy : (__expf(oy) - 1.f);
  *(float2*)(xout + (size_t)v*128 + c0) = make_float2(ox, oy);
}

// ---------------------------------------------------------------- classifier
__global__ __launch_bounds__(256) void classifier_kernel(
    const float* __restrict__ x, const float* __restrict__ w1c, const float* __restrict__ b1c,
    const float* __restrict__ w2c, const float* __restrict__ b2c, float* __restrict__ out)
{
  __shared__ float sh[4][64];
  const int wid = threadIdx.x >> 6, l = threadIdx.x & 63;
  const int v = blockIdx.x*4 + wid;
  const int vu = __builtin_amdgcn_readfirstlane(v);
  const float* xr = x + (size_t)vu*128;
  float a = b1c[l];
  #pragma unroll 4
  for (int k = 0; k < 128; k++) a = fmaf(xr[k], w1c[k*64 + l], a);
  a = a > 0.f ? a : 0.f;
  sh[wid][l] = a;
  __syncthreads();
  if (l < 25){
    float o = b2c[l];
    #pragma unroll 4
    for (int k = 0; k < 64; k++) o = fmaf(sh[wid][k], w2c[k*25 + l], o);
    out[(size_t)v*25 + l] = o;
  }
}

// ---------------------------------------------------------------- launch
extern "C" void kernel_launch(void* const* d_in, const int* in_sizes, int n_in,
                              void* d_out, int out_size, void* d_ws, size_t ws_size,
                              hipStream_t stream)
{
  (void)in_sizes; (void)n_in; (void)out_size; (void)ws_size;
  const float* x_vis   = (const float*)d_in[0];
  const float* x_sym   = (const float*)d_in[1];
  const int*   ei      = (const int*)  d_in[2];
  const float* ea      = (const float*)d_in[3];
  const float* c1w     = (const float*)d_in[4];
  const float* c1b     = (const float*)d_in[5];
  const float* c2w     = (const float*)d_in[6];
  const float* c2b     = (const float*)d_in[7];
  const float* fcw     = (const float*)d_in[8];
  const float* fcb     = (const float*)d_in[9];
  const float* s1w     = (const float*)d_in[10];
  const float* s1b     = (const float*)d_in[11];
  const float* s2w     = (const float*)d_in[12];
  const float* s2b     = (const float*)d_in[13];
  const float* g1W     = (const float*)d_in[14];
  const float* g1b     = (const float*)d_in[15];
  const float* g1We    = (const float*)d_in[16];
  const float* g1be    = (const float*)d_in[17];
  const float* g1asrc  = (const float*)d_in[18];
  const float* g1adst  = (const float*)d_in[19];
  const float* g1aedge = (const float*)d_in[20];
  const float* g1Wg    = (const float*)d_in[21];
  const float* g1bg    = (const float*)d_in[22];
  const float* g2W     = (const float*)d_in[23];
  const float* g2b     = (const float*)d_in[24];
  const float* g2We    = (const float*)d_in[25];
  const float* g2be    = (const float*)d_in[26];
  const float* g2asrc  = (const float*)d_in[27];
  const float* g2adst  = (const float*)d_in[28];
  const float* g2aedge = (const float*)d_in[29];
  const float* g2Wg    = (const float*)d_in[30];
  const float* g2bg    = (const float*)d_in[31];
  const float* cw1     = (const float*)d_in[32];
  const float* cb1     = (const float*)d_in[33];
  const float* cw2     = (const float*)d_in[34];
  const float* cb2     = (const float*)d_in[35];

  size_t off = 0;
  auto take = [&](size_t bytes) -> void* {
    off = (off + 255) & ~(size_t)255;
    void* p = (char*)d_ws + off;
    off += bytes;
    return p;
  };
  int*   cnt     = (int*)  take((size_t)NND*4);
  int*   offs    = (int*)  take((size_t)(NND+1)*4);
  int4*  srcattr = (int4*) take((size_t)NE*16);
  float* x128    = (float*)take((size_t)NND*128*4);
  unsigned short* hb = (unsigned short*)take((size_t)NND*128*2);
  float* sbuf    = (float*)take((size_t)NND*4*4);
  float* dbuf    = (float*)take((size_t)NND*4*4);
  float* x2      = (float*)take((size_t)NND*128*4);
  unsigned short* W1t = (unsigned short*)take(3072*2);
  unsigned short* W2t = (unsigned short*)take(18432*2);
  float* Weff    = (float*)take(16384*4);
  float* beff    = (float*)take(128*4);
  unsigned short* G1h = (unsigned short*)take(16384*2);
  unsigned short* G1l = (unsigned short*)take(16384*2);
  unsigned short* G2h = (unsigned short*)take(16384*2);
  unsigned short* G2l = (unsigned short*)take(16384*2);
  float* x3      = x128;   // x128 dead after node_gemm layer-1; reuse as layer-2 output

  // weight pre-transforms
  prep_weights<<<2, 256, 0, stream>>>(c1w, c2w, W1t, W2t);
  prep_fold<<<64, 256, 0, stream>>>(fcw, fcb, g1W, g1b, Weff, beff);
  prep_gemm<<<64, 256, 0, stream>>>(Weff, 16384, G1h, G1l);
  prep_gemm<<<64, 256, 0, stream>>>(g2W, 16384, G2h, G2l);

  // CSR build (graph identical for both GAT layers)
  hipMemsetAsync(cnt, 0, (size_t)NND*4, stream);
  hist_kernel<<<(NE+255)/256, 256, 0, stream>>>(ei, cnt);
  scan_kernel<<<1, 1024, 0, stream>>>(cnt, offs, NND);
  hipMemsetAsync(cnt, 0, (size_t)NND*4, stream);
  scatter_kernel<<<(NE+255)/256, 256, 0, stream>>>(ei, ea, offs, cnt, srcattr);

  // encoders (MFMA, 2 nodes/block, no barriers)
  uv_mfma_kernel<<<NND/2, 128, 0, stream>>>(x_vis, x_sym, W1t, W2t, c1b, c2b,
                                            s1w, s1b, s2w, s2b, x128);
  // GAT layer 1 (uvfc folded into Weff)
  node_gemm<128><<<(NND/16 + 3)/4, 256, 0, stream>>>(x128, G1h, G1l, beff, g1asrc, g1adst,
                                                     hb, sbuf, dbuf);
  gat_aggregate<<<NND/4, 256, 0, stream>>>(sbuf, dbuf, hb, srcattr, offs,
                                           g1We, g1be, g1aedge, g1Wg, g1bg, x2);
  // GAT layer 2
  node_gemm<128><<<(NND/16 + 3)/4, 256, 0, stream>>>(x2, G2h, G2l, g2b, g2asrc, g2adst,
                                                     hb, sbuf, dbuf);
  gat_aggregate<<<NND/4, 256, 0, stream>>>(sbuf, dbuf, hb, srcattr, offs,
                                           g2We, g2be, g2aedge, g2Wg, g2bg, x3);
  // classifier
  classifier_kernel<<<NND/4, 256, 0, stream>>>(x3, cw1, cb1, cw2, cb2, (float*)d_out);
}

// Round 5
// 713.036 us; speedup vs baseline: 4.0872x; 1.0945x over previous
//
#include <hip/hip_runtime.h>

#define NND 50000
#define NE  1600000

typedef __attribute__((ext_vector_type(8))) short bf16x8;
typedef __attribute__((ext_vector_type(4))) float f32x4;

__device__ __forceinline__ float leaky02(float x){ return x > 0.f ? x : 0.2f*x; }
__device__ __forceinline__ unsigned short f2bf(float f){
  unsigned u = __float_as_uint(f);
  u = (u + 0x7fffu + ((u >> 16) & 1u)) >> 16;
  return (unsigned short)u;
}
__device__ __forceinline__ float bf2f(unsigned short h){
  return __uint_as_float(((unsigned)h) << 16);
}
__device__ __forceinline__ bf16x8 ld_frag(const unsigned short* p){
  return __builtin_bit_cast(bf16x8, *(const uint4*)p);
}

// ---------------------------------------------------------------- CSR build
__global__ __launch_bounds__(256) void hist_kernel(const int* __restrict__ ei,
                                                   int* __restrict__ cnt){
  int e = blockIdx.x*256 + threadIdx.x;
  if (e < NE) atomicAdd(&cnt[ei[NE + e]], 1);
}

__global__ __launch_bounds__(1024) void scan_kernel(const int* __restrict__ cnt,
                                                    int* __restrict__ offsets, int n){
  __shared__ int wsum[16];
  __shared__ int sbase;
  int t = threadIdx.x, lane = t & 63, w = t >> 6;
  if (t == 0) sbase = 0;
  __syncthreads();
  for (int start = 0; start < n; start += 1024){
    int i = start + t;
    int x = (i < n) ? cnt[i] : 0;
    #pragma unroll
    for (int off = 1; off < 64; off <<= 1){ int y = __shfl_up(x, off); if (lane >= off) x += y; }
    if (lane == 63) wsum[w] = x;
    __syncthreads();
    if (w == 0 && lane < 16){
      int sv = wsum[lane];
      #pragma unroll
      for (int off = 1; off < 16; off <<= 1){ int y = __shfl_up(sv, off); if (lane >= off) sv += y; }
      wsum[lane] = sv;
    }
    __syncthreads();
    int base = sbase + (w > 0 ? wsum[w-1] : 0);
    if (i < n) offsets[i+1] = base + x;
    __syncthreads();
    if (t == 0) sbase += wsum[15];
    __syncthreads();
  }
  if (t == 0) offsets[0] = 0;
}

__global__ __launch_bounds__(256) void scatter_kernel(const int* __restrict__ ei,
                                                      const float* __restrict__ ea,
                                                      const int* __restrict__ offsets,
                                                      int* __restrict__ cursor,
                                                      int4* __restrict__ srcattr){
  int e = blockIdx.x*256 + threadIdx.x;
  if (e < NE){
    int dstn = ei[NE + e];
    int pos  = atomicAdd(&cursor[dstn], 1);
    int idx  = offsets[dstn] + pos;
    srcattr[idx] = make_int4(ei[e], __float_as_int(ea[2*e]), __float_as_int(ea[2*e+1]), 0);
  }
}

// -------------------------------------------------- conv weight pre-transform (bf16)
__global__ __launch_bounds__(256) void prep_weights(
    const float* __restrict__ w1, const float* __restrict__ w2,
    unsigned short* __restrict__ W1t, unsigned short* __restrict__ W2t)
{
  int t = threadIdx.x;
  if (blockIdx.x == 0){
    for (int i = t; i < 3072; i += 256){
      int j = i & 7, oc = (i >> 3) & 31, g = (i >> 8) & 3, m = i >> 10;
      int tap = m*4 + g;
      float v = (tap < 9 && j < 6) ? w1[oc*54 + j*9 + tap] : 0.f;
      W1t[i] = f2bf(v);
    }
  } else {
    for (int i = t; i < 18432; i += 256){
      int j = i & 7, oc = (i >> 3) & 63, g = (i >> 9) & 3, tap = i >> 11;
      int ic = g*8 + j;
      W2t[i] = f2bf(w2[oc*288 + ic*9 + tap]);
    }
  }
}

// -------------------------------------------------- fold uvfc into layer-1 W: Weff[128][128]
__global__ __launch_bounds__(256) void prep_fold(
    const float* __restrict__ fcw, const float* __restrict__ fcb,
    const float* __restrict__ g1W, const float* __restrict__ g1b,
    float* __restrict__ Weff, float* __restrict__ beff)
{
  int idx = blockIdx.x*256 + threadIdx.x;
  if (idx < 16384){
    int r = idx >> 7, c = idx & 127;
    float acc;
    if (r < 64){
      acc = 0.f;
      #pragma unroll 4
      for (int m = 0; m < 128; m++) acc += fcw[r*128 + m] * g1W[m*128 + c];
    } else {
      acc = g1W[(64 + r)*128 + c];
    }
    Weff[idx] = acc;
  }
  if (blockIdx.x == 0 && threadIdx.x < 128){
    int c = threadIdx.x;
    float acc = g1b[c];
    #pragma unroll 4
    for (int m = 0; m < 128; m++) acc += fcb[m] * g1W[m*128 + c];
    beff[c] = acc;
  }
}

// -------------------------------------------------- GEMM weight pre-transform: frag-linear hi/lo
__global__ __launch_bounds__(256) void prep_gemm(
    const float* __restrict__ W, int total,
    unsigned short* __restrict__ Wh, unsigned short* __restrict__ Wl)
{
  for (int i = blockIdx.x*256 + threadIdx.x; i < total; i += gridDim.x*256){
    int j = i & 7, lx = (i >> 3) & 63, nt = (i >> 9) & 7, ks = i >> 12;
    int k = ks*32 + (lx >> 4)*8 + j;
    int col = nt*16 + (lx & 15);
    float v = W[k*128 + col];
    unsigned short h16 = f2bf(v);
    Wh[i] = h16;
    Wl[i] = f2bf(v - bf2f(h16));
  }
}

// -------------------------------------------- UV + sym encoder, MFMA, W2 resident in LDS
// 256 threads = 4 waves = 4 nodes. Conv2 inner loop is 100% LDS + MFMA.
__global__ __launch_bounds__(256, 2) void uv_mfma_kernel(
    const float* __restrict__ x_vis, const float* __restrict__ x_sym,
    const unsigned short* __restrict__ W1t, const unsigned short* __restrict__ W2t,
    const float* __restrict__ b1, const float* __restrict__ b2,
    const float* __restrict__ s1w, const float* __restrict__ s1b,
    const float* __restrict__ s2w, const float* __restrict__ s2b,
    float* __restrict__ x128)
{
  __shared__ __align__(16) unsigned short Wlds[18432];   // 36 KB W2t copy (block-shared)
  __shared__ __align__(16) unsigned short xic[4*800];    // per-node [10][10][8ic] bf16
  __shared__ __align__(16) unsigned short c1p[4*4000];   // per-node [10][10][40] bf16
  __shared__ float symh[4][64];

  const int t = threadIdx.x;
  const int w = t >> 6, l = t & 63;
  const int g = l >> 4, r16 = l & 15;
  const int xb = r16 & 7, yb = r16 >> 3;
  const int n = blockIdx.x*4 + w;

  // cooperative stage of W2t -> LDS (2304 uint4, 9 per thread, coalesced)
  {
    const uint4* src = (const uint4*)W2t;
    uint4* dst = (uint4*)Wlds;
    #pragma unroll
    for (int i = 0; i < 9; i++) dst[t + i*256] = src[t + i*256];
  }

  // zero this wave's node buffers (borders must be 0)
  uint4 z4 = {0,0,0,0};
  {
    uint4* zx = (uint4*)(xic + w*800);
    #pragma unroll
    for (int i = 0; i < 2; i++) if (l + i*64 < 100) zx[l + i*64] = z4;
    uint4* zc = (uint4*)(c1p + w*4000);
    #pragma unroll
    for (int i = 0; i < 8; i++) if (l + i*64 < 500) zc[l + i*64] = z4;
  }

  // stage x_vis -> xic interior (bf16), wave-private
  {
    const float* xv = x_vis + (size_t)n*384;
    #pragma unroll
    for (int it = 0; it < 6; it++){
      int i = l + it*64;
      int ic = i >> 6, yx = i & 63, y = yx >> 3, x = yx & 7;
      xic[w*800 + ((y+1)*10 + (x+1))*8 + ic] = f2bf(xv[i]);
    }
  }

  // conv1 B fragments from global (6 KB, L2-hot)
  uint4 B1[3][2];
  #pragma unroll
  for (int m = 0; m < 3; m++)
    #pragma unroll
    for (int nt = 0; nt < 2; nt++)
      B1[m][nt] = *(const uint4*)(W1t + m*1024 + g*256 + (nt*16 + r16)*8);

  // ---- conv1: 3 MFMAs, 4 taps packed per MFMA into K=32
  const int t0 = g;     const int dy0 = t0/3, dx0 = t0%3;
  const int t1 = 4 + g; const int dy1 = t1/3, dx1 = t1%3;
  const int dy2 = 2, dx2 = 2;

  const float b1a = b1[r16], b1c = b1[16 + r16];
  f32x4 acc1[4][2];
  #pragma unroll
  for (int mt = 0; mt < 4; mt++){
    acc1[mt][0] = (f32x4){b1a, b1a, b1a, b1a};
    acc1[mt][1] = (f32x4){b1c, b1c, b1c, b1c};
  }
  const unsigned short* xn = xic + w*800;
  #pragma unroll
  for (int mt = 0; mt < 4; mt++){
    const int Y = mt*2 + yb;
    bf16x8 A0 = ld_frag(xn + (Y+dy0)*80 + (xb+dx0)*8);
    bf16x8 A1 = ld_frag(xn + (Y+dy1)*80 + (xb+dx1)*8);
    bf16x8 A2 = ld_frag(xn + (Y+dy2)*80 + (xb+dx2)*8);
    #pragma unroll
    for (int nt = 0; nt < 2; nt++){
      acc1[mt][nt] = __builtin_amdgcn_mfma_f32_16x16x32_bf16(A0, __builtin_bit_cast(bf16x8, B1[0][nt]), acc1[mt][nt], 0,0,0);
      acc1[mt][nt] = __builtin_amdgcn_mfma_f32_16x16x32_bf16(A1, __builtin_bit_cast(bf16x8, B1[1][nt]), acc1[mt][nt], 0,0,0);
      acc1[mt][nt] = __builtin_amdgcn_mfma_f32_16x16x32_bf16(A2, __builtin_bit_cast(bf16x8, B1[2][nt]), acc1[mt][nt], 0,0,0);
    }
  }
  unsigned short* cn = c1p + w*4000;
  #pragma unroll
  for (int mt = 0; mt < 4; mt++)
    #pragma unroll
    for (int nt = 0; nt < 2; nt++)
      #pragma unroll
      for (int j = 0; j < 4; j++){
        int rowl = g*4 + j;
        int y = mt*2 + (rowl >> 3), x = rowl & 7;
        float v = acc1[mt][nt][j]; v = v > 0.f ? v : 0.f;
        cn[((y+1)*10 + (x+1))*40 + nt*16 + r16] = f2bf(v);
      }

  __syncthreads();   // Wlds ready (and own c1p writes drained)

  // ---- conv2: tap-loop implicit GEMM, all operands in LDS
  float b2v[4];
  #pragma unroll
  for (int nt = 0; nt < 4; nt++) b2v[nt] = b2[nt*16 + r16];
  f32x4 acc2[4][4];
  #pragma unroll
  for (int mt = 0; mt < 4; mt++)
    #pragma unroll
    for (int nt = 0; nt < 4; nt++)
      acc2[mt][nt] = (f32x4){b2v[nt], b2v[nt], b2v[nt], b2v[nt]};

  #pragma unroll
  for (int tap = 0; tap < 9; tap++){
    const int dy = tap/3, dx = tap%3;
    uint4 Bv[4];
    #pragma unroll
    for (int nt = 0; nt < 4; nt++)
      Bv[nt] = *(const uint4*)(Wlds + tap*2048 + g*512 + (nt*16 + r16)*8);
    uint4 Av[4];
    #pragma unroll
    for (int mt = 0; mt < 4; mt++){
      int Y = mt*2 + yb + dy, X = xb + dx;
      Av[mt] = *(const uint4*)(cn + (Y*10 + X)*40 + g*8);
    }
    #pragma unroll
    for (int mt = 0; mt < 4; mt++)
      #pragma unroll
      for (int nt = 0; nt < 4; nt++)
        acc2[mt][nt] = __builtin_amdgcn_mfma_f32_16x16x32_bf16(
            __builtin_bit_cast(bf16x8, Av[mt]), __builtin_bit_cast(bf16x8, Bv[nt]), acc2[mt][nt], 0,0,0);
  }

  // relu + mean pool over 64 px -> x128[0:64]
  float* xo = x128 + (size_t)n*128;
  #pragma unroll
  for (int nt = 0; nt < 4; nt++){
    float s = 0.f;
    #pragma unroll
    for (int mt = 0; mt < 4; mt++)
      #pragma unroll
      for (int j = 0; j < 4; j++){
        float v = acc2[mt][nt][j]; s += (v > 0.f ? v : 0.f);
      }
    s += __shfl_xor(s, 16);
    s += __shfl_xor(s, 32);
    if (l < 16) xo[nt*16 + l] = s * (1.f/64.f);
  }
  // sym layer 1 (wave-private)
  {
    const float* xs = x_sym + (size_t)n*3;
    float a = s1b[l] + xs[0]*s1w[l] + xs[1]*s1w[64+l] + xs[2]*s1w[128+l];
    symh[w][l] = a > 0.f ? a : 0.f;
  }
  // sym layer 2 -> x128[64:128]
  {
    float a = s2b[l];
    #pragma unroll 8
    for (int k = 0; k < 64; k++) a = fmaf(symh[w][k], s2w[k*64 + l], a);
    xo[64 + l] = a > 0.f ? a : 0.f;
  }
}

// ---------------- node GEMM: h = x@W + b via split-bf16 MFMA; fused s,d dots; h stored bf16.
template<int K>
__global__ __launch_bounds__(256) void node_gemm(
    const float* __restrict__ xin,
    const unsigned short* __restrict__ Wh, const unsigned short* __restrict__ Wl,
    const float* __restrict__ b,
    const float* __restrict__ asrc, const float* __restrict__ adst,
    unsigned short* __restrict__ h_out, float* __restrict__ s_out, float* __restrict__ d_out)
{
  const int w = threadIdx.x >> 6, l = threadIdx.x & 63;
  const int g = l >> 4, r16 = l & 15;
  const int wid = blockIdx.x*4 + w;
  if (wid >= NND/16) return;
  const int rowbase = wid*16;

  f32x4 acc[8];
  #pragma unroll
  for (int nt = 0; nt < 8; nt++){
    float bv = b[nt*16 + r16];
    acc[nt] = (f32x4){bv, bv, bv, bv};
  }

  const float* xr = xin + (size_t)(rowbase + r16)*K + g*8;
  #pragma unroll 2
  for (int ks = 0; ks < K/32; ks++){
    float4 xa = *(const float4*)(xr + ks*32);
    float4 xb = *(const float4*)(xr + ks*32 + 4);
    float xs[8] = {xa.x,xa.y,xa.z,xa.w,xb.x,xb.y,xb.z,xb.w};
    bf16x8 Ah, Al;
    #pragma unroll
    for (int j = 0; j < 8; j++){
      unsigned short h16 = f2bf(xs[j]);
      Ah[j] = (short)h16;
      Al[j] = (short)f2bf(xs[j] - bf2f(h16));
    }
    #pragma unroll
    for (int nt = 0; nt < 8; nt++){
      const int fo = (((ks*8 + nt)*64 + l)*8);
      bf16x8 Bh = ld_frag(Wh + fo);
      bf16x8 Bl = ld_frag(Wl + fo);
      acc[nt] = __builtin_amdgcn_mfma_f32_16x16x32_bf16(Ah, Bh, acc[nt], 0,0,0);
      acc[nt] = __builtin_amdgcn_mfma_f32_16x16x32_bf16(Al, Bh, acc[nt], 0,0,0);
      acc[nt] = __builtin_amdgcn_mfma_f32_16x16x32_bf16(Ah, Bl, acc[nt], 0,0,0);
    }
  }

  // write h (bf16)
  #pragma unroll
  for (int nt = 0; nt < 8; nt++)
    #pragma unroll
    for (int j = 0; j < 4; j++)
      h_out[(size_t)(rowbase + g*4 + j)*128 + nt*16 + r16] = f2bf(acc[nt][j]);

  // fused s,d: per-head dot over that head's 32 channels
  float as_v[8], ad_v[8];
  #pragma unroll
  for (int nt = 0; nt < 8; nt++){
    as_v[nt] = asrc[nt*16 + r16];
    ad_v[nt] = adst[nt*16 + r16];
  }
  float sp[4][4], dp[4][4];
  #pragma unroll
  for (int hd = 0; hd < 4; hd++)
    #pragma unroll
    for (int j = 0; j < 4; j++){
      sp[hd][j] = acc[2*hd][j]*as_v[2*hd] + acc[2*hd+1][j]*as_v[2*hd+1];
      dp[hd][j] = acc[2*hd][j]*ad_v[2*hd] + acc[2*hd+1][j]*ad_v[2*hd+1];
    }
  #pragma unroll
  for (int o = 1; o < 16; o <<= 1)
    #pragma unroll
    for (int hd = 0; hd < 4; hd++)
      #pragma unroll
      for (int j = 0; j < 4; j++){
        sp[hd][j] += __shfl_xor(sp[hd][j], o);
        dp[hd][j] += __shfl_xor(dp[hd][j], o);
      }
  #pragma unroll
  for (int hd = 0; hd < 4; hd++){
    if (r16 == hd)
      #pragma unroll
      for (int j = 0; j < 4; j++)
        s_out[(rowbase + g*4 + j)*4 + hd] = sp[hd][j];
    if (r16 == 8 + hd)
      #pragma unroll
      for (int j = 0; j < 4; j++)
        d_out[(rowbase + g*4 + j)*4 + hd] = dp[hd][j];
  }
}

// -------------------------------------------- GAT aggregation, wave per dst node, bf16 h gather
__global__ __launch_bounds__(256) void gat_aggregate(
    const float* __restrict__ sarr, const float* __restrict__ darr,
    const unsigned short* __restrict__ hb,
    const int4* __restrict__ srcattr, const int* __restrict__ offsets,
    const float* __restrict__ We, const float* __restrict__ be,
    const float* __restrict__ aedge, const float* __restrict__ Wg, const float* __restrict__ bgp,
    float* __restrict__ xout)
{
  __shared__ int2 ew[4][2][4][64];   // [wave][buf][head][edge] = {w_bits, src}
  const int l  = threadIdx.x & 63;
  const int w  = threadIdx.x >> 6;
  const int v  = blockIdx.x*4 + w;
  const int hd = l >> 4;
  const int c0 = 2*l;

  float ae0 = aedge[hd*32 + (c0&31)];
  float ae1 = aedge[hd*32 + ((c0+1)&31)];
  float we00 = We[c0], we01 = We[c0+1], we10 = We[128+c0], we11 = We[128+c0+1];
  float beA = be[c0], beB = be[c0+1];
  float p0 = we00*ae0 + we01*ae1;
  float p1 = we10*ae0 + we11*ae1;
  float pc = beA*ae0 + beB*ae1;
  #pragma unroll
  for (int o = 1; o < 16; o <<= 1){ p0 += __shfl_xor(p0,o); p1 += __shfl_xor(p1,o); pc += __shfl_xor(pc,o); }
  float P00=__shfl(p0,0), P01=__shfl(p0,16), P02=__shfl(p0,32), P03=__shfl(p0,48);
  float P10=__shfl(p1,0), P11=__shfl(p1,16), P12=__shfl(p1,32), P13=__shfl(p1,48);
  float PC0=__shfl(pc,0), PC1=__shfl(pc,16), PC2=__shfl(pc,32), PC3=__shfl(pc,48);
  const float wg0 = Wg[0], wg1 = Wg[1], bgv = bgp[0];

  const int off = offsets[v];
  const int deg = offsets[v+1] - off;
  const float4 d4 = *(const float4*)(darr + (size_t)v*4);

  float dn0=0.f,dn1=0.f,dn2=0.f,dn3=0.f;
  float Sm0=0.f,Sm1=0.f,Sm2=0.f,Sm3=0.f;
  float S00=0.f,S01=0.f,S02=0.f,S03=0.f;
  float S10=0.f,S11=0.f,S12=0.f,S13=0.f;
  float accx=0.f, accy=0.f;

  int pb = 0;
  for (int base = 0; base < deg; base += 64, pb ^= 1){
    int ii = base + l;
    float w0=0.f,w1=0.f,w2=0.f,w3=0.f; int sj=0;
    if (ii < deg){
      int4 sa = srcattr[off + ii];
      sj = sa.x;
      float a0 = __int_as_float(sa.y), a1 = __int_as_float(sa.z);
      const float4 sv = *(const float4*)(sarr + (size_t)sj*4);
      float e0 = __expf(leaky02(sv.x + d4.x + a0*P00 + a1*P10 + PC0));
      float e1 = __expf(leaky02(sv.y + d4.y + a0*P01 + a1*P11 + PC1));
      float e2 = __expf(leaky02(sv.z + d4.z + a0*P02 + a1*P12 + PC2));
      float e3 = __expf(leaky02(sv.w + d4.w + a0*P03 + a1*P13 + PC3));
      float gt = 1.f/(1.f + __expf(-(a0*wg0 + a1*wg1 + bgv)));
      dn0 += e0; dn1 += e1; dn2 += e2; dn3 += e3;
      w0 = gt*e0; w1 = gt*e1; w2 = gt*e2; w3 = gt*e3;
      Sm0 += w0; Sm1 += w1; Sm2 += w2; Sm3 += w3;
      S00 += w0*a0; S01 += w1*a0; S02 += w2*a0; S03 += w3*a0;
      S10 += w0*a1; S11 += w1*a1; S12 += w2*a1; S13 += w3*a1;
    }
    ew[w][pb][0][l] = make_int2(__float_as_int(w0), sj);
    ew[w][pb][1][l] = make_int2(__float_as_int(w1), sj);
    ew[w][pb][2][l] = make_int2(__float_as_int(w2), sj);
    ew[w][pb][3][l] = make_int2(__float_as_int(w3), sj);
    asm volatile("s_waitcnt lgkmcnt(0)" ::: "memory");
    const int2* eb = &ew[w][pb][hd][0];
    int lim = min(64, deg - base);
    #pragma unroll 8
    for (int j = 0; j < lim; j++){
      int2 ws = eb[j];
      float wv = __int_as_float(ws.x);
      unsigned hv = *(const unsigned*)(hb + (((size_t)ws.y) << 7) + c0);
      accx = fmaf(__uint_as_float(hv << 16), wv, accx);
      accy = fmaf(__uint_as_float(hv & 0xffff0000u), wv, accy);
    }
  }

  #pragma unroll
  for (int o = 1; o < 64; o <<= 1){
    dn0 += __shfl_xor(dn0,o); dn1 += __shfl_xor(dn1,o); dn2 += __shfl_xor(dn2,o); dn3 += __shfl_xor(dn3,o);
    Sm0 += __shfl_xor(Sm0,o); Sm1 += __shfl_xor(Sm1,o); Sm2 += __shfl_xor(Sm2,o); Sm3 += __shfl_xor(Sm3,o);
    S00 += __shfl_xor(S00,o); S01 += __shfl_xor(S01,o); S02 += __shfl_xor(S02,o); S03 += __shfl_xor(S03,o);
    S10 += __shfl_xor(S10,o); S11 += __shfl_xor(S11,o); S12 += __shfl_xor(S12,o); S13 += __shfl_xor(S13,o);
  }
  float den = (hd==0)?dn0:(hd==1)?dn1:(hd==2)?dn2:dn3;
  float Smh = (hd==0)?Sm0:(hd==1)?Sm1:(hd==2)?Sm2:Sm3;
  float S0h = (hd==0)?S00:(hd==1)?S01:(hd==2)?S02:S03;
  float S1h = (hd==0)?S10:(hd==1)?S11:(hd==2)?S12:S13;
  float rden = 1.f/(den + 1e-16f);
  float ox = (accx + beA*Smh + we00*S0h + we10*S1h) * rden;
  float oy = (accy + beB*Smh + we01*S0h + we11*S1h) * rden;
  ox = ox > 0.f ? ox : (__expf(ox) - 1.f);
  oy = oy > 0.f ? oy : (__expf(oy) - 1.f);
  *(float2*)(xout + (size_t)v*128 + c0) = make_float2(ox, oy);
}

// ---------------------------------------------------------------- classifier
__global__ __launch_bounds__(256) void classifier_kernel(
    const float* __restrict__ x, const float* __restrict__ w1c, const float* __restrict__ b1c,
    const float* __restrict__ w2c, const float* __restrict__ b2c, float* __restrict__ out)
{
  __shared__ float sh[4][64];
  const int wid = threadIdx.x >> 6, l = threadIdx.x & 63;
  const int v = blockIdx.x*4 + wid;
  const int vu = __builtin_amdgcn_readfirstlane(v);
  const float* xr = x + (size_t)vu*128;
  float a = b1c[l];
  #pragma unroll 4
  for (int k = 0; k < 128; k++) a = fmaf(xr[k], w1c[k*64 + l], a);
  a = a > 0.f ? a : 0.f;
  sh[wid][l] = a;
  __syncthreads();
  if (l < 25){
    float o = b2c[l];
    #pragma unroll 4
    for (int k = 0; k < 64; k++) o = fmaf(sh[wid][k], w2c[k*25 + l], o);
    out[(size_t)v*25 + l] = o;
  }
}

// ---------------------------------------------------------------- launch
extern "C" void kernel_launch(void* const* d_in, const int* in_sizes, int n_in,
                              void* d_out, int out_size, void* d_ws, size_t ws_size,
                              hipStream_t stream)
{
  (void)in_sizes; (void)n_in; (void)out_size; (void)ws_size;
  const float* x_vis   = (const float*)d_in[0];
  const float* x_sym   = (const float*)d_in[1];
  const int*   ei      = (const int*)  d_in[2];
  const float* ea      = (const float*)d_in[3];
  const float* c1w     = (const float*)d_in[4];
  const float* c1b     = (const float*)d_in[5];
  const float* c2w     = (const float*)d_in[6];
  const float* c2b     = (const float*)d_in[7];
  const float* fcw     = (const float*)d_in[8];
  const float* fcb     = (const float*)d_in[9];
  const float* s1w     = (const float*)d_in[10];
  const float* s1b     = (const float*)d_in[11];
  const float* s2w     = (const float*)d_in[12];
  const float* s2b     = (const float*)d_in[13];
  const float* g1W     = (const float*)d_in[14];
  const float* g1b     = (const float*)d_in[15];
  const float* g1We    = (const float*)d_in[16];
  const float* g1be    = (const float*)d_in[17];
  const float* g1asrc  = (const float*)d_in[18];
  const float* g1adst  = (const float*)d_in[19];
  const float* g1aedge = (const float*)d_in[20];
  const float* g1Wg    = (const float*)d_in[21];
  const float* g1bg    = (const float*)d_in[22];
  const float* g2W     = (const float*)d_in[23];
  const float* g2b     = (const float*)d_in[24];
  const float* g2We    = (const float*)d_in[25];
  const float* g2be    = (const float*)d_in[26];
  const float* g2asrc  = (const float*)d_in[27];
  const float* g2adst  = (const float*)d_in[28];
  const float* g2aedge = (const float*)d_in[29];
  const float* g2Wg    = (const float*)d_in[30];
  const float* g2bg    = (const float*)d_in[31];
  const float* cw1     = (const float*)d_in[32];
  const float* cb1     = (const float*)d_in[33];
  const float* cw2     = (const float*)d_in[34];
  const float* cb2     = (const float*)d_in[35];

  size_t off = 0;
  auto take = [&](size_t bytes) -> void* {
    off = (off + 255) & ~(size_t)255;
    void* p = (char*)d_ws + off;
    off += bytes;
    return p;
  };
  int*   cnt     = (int*)  take((size_t)NND*4);
  int*   offs    = (int*)  take((size_t)(NND+1)*4);
  int4*  srcattr = (int4*) take((size_t)NE*16);
  float* x128    = (float*)take((size_t)NND*128*4);
  unsigned short* hb = (unsigned short*)take((size_t)NND*128*2);
  float* sbuf    = (float*)take((size_t)NND*4*4);
  float* dbuf    = (float*)take((size_t)NND*4*4);
  float* x2      = (float*)take((size_t)NND*128*4);
  unsigned short* W1t = (unsigned short*)take(3072*2);
  unsigned short* W2t = (unsigned short*)take(18432*2);
  float* Weff    = (float*)take(16384*4);
  float* beff    = (float*)take(128*4);
  unsigned short* G1h = (unsigned short*)take(16384*2);
  unsigned short* G1l = (unsigned short*)take(16384*2);
  unsigned short* G2h = (unsigned short*)take(16384*2);
  unsigned short* G2l = (unsigned short*)take(16384*2);
  float* x3      = x128;   // x128 dead after node_gemm layer-1; reuse as layer-2 output

  // weight pre-transforms
  prep_weights<<<2, 256, 0, stream>>>(c1w, c2w, W1t, W2t);
  prep_fold<<<64, 256, 0, stream>>>(fcw, fcb, g1W, g1b, Weff, beff);
  prep_gemm<<<64, 256, 0, stream>>>(Weff, 16384, G1h, G1l);
  prep_gemm<<<64, 256, 0, stream>>>(g2W, 16384, G2h, G2l);

  // CSR build (graph identical for both GAT layers)
  hipMemsetAsync(cnt, 0, (size_t)NND*4, stream);
  hist_kernel<<<(NE+255)/256, 256, 0, stream>>>(ei, cnt);
  scan_kernel<<<1, 1024, 0, stream>>>(cnt, offs, NND);
  hipMemsetAsync(cnt, 0, (size_t)NND*4, stream);
  scatter_kernel<<<(NE+255)/256, 256, 0, stream>>>(ei, ea, offs, cnt, srcattr);

  // encoders (MFMA, 4 nodes/block, W2 in LDS)
  uv_mfma_kernel<<<NND/4, 256, 0, stream>>>(x_vis, x_sym, W1t, W2t, c1b, c2b,
                                            s1w, s1b, s2w, s2b, x128);
  // GAT layer 1 (uvfc folded into Weff)
  node_gemm<128><<<(NND/16 + 3)/4, 256, 0, stream>>>(x128, G1h, G1l, beff, g1asrc, g1adst,
                                                     hb, sbuf, dbuf);
  gat_aggregate<<<NND/4, 256, 0, stream>>>(sbuf, dbuf, hb, srcattr, offs,
                                           g1We, g1be, g1aedge, g1Wg, g1bg, x2);
  // GAT layer 2
  node_gemm<128><<<(NND/16 + 3)/4, 256, 0, stream>>>(x2, G2h, G2l, g2b, g2asrc, g2adst,
                                                     hb, sbuf, dbuf);
  gat_aggregate<<<NND/4, 256, 0, stream>>>(sbuf, dbuf, hb, srcattr, offs,
                                           g2We, g2be, g2aedge, g2Wg, g2bg, x3);
  // classifier
  classifier_kernel<<<NND/4, 256, 0, stream>>>(x3, cw1, cb1, cw2, cb2, (float*)d_out);
}

// Round 6
// 666.378 us; speedup vs baseline: 4.3734x; 1.0700x over previous
//
#include <hip/hip_runtime.h>

#define NND 50000
#define NE  1600000

typedef __attribute__((ext_vector_type(8))) short bf16x8;
typedef __attribute__((ext_vector_type(4))) float f32x4;

__device__ __forceinline__ float leaky02(float x){ return x > 0.f ? x : 0.2f*x; }
__device__ __forceinline__ unsigned short f2bf(float f){
  unsigned u = __float_as_uint(f);
  u = (u + 0x7fffu + ((u >> 16) & 1u)) >> 16;
  return (unsigned short)u;
}
__device__ __forceinline__ float bf2f(unsigned short h){
  return __uint_as_float(((unsigned)h) << 16);
}
__device__ __forceinline__ bf16x8 ld_frag(const unsigned short* p){
  return __builtin_bit_cast(bf16x8, *(const uint4*)p);
}

// ---------------------------------------------------------------- CSR build
__global__ __launch_bounds__(256) void hist_kernel(const int* __restrict__ ei,
                                                   int* __restrict__ cnt){
  int e = blockIdx.x*256 + threadIdx.x;
  if (e < NE) atomicAdd(&cnt[ei[NE + e]], 1);
}

__global__ __launch_bounds__(1024) void scan_kernel(const int* __restrict__ cnt,
                                                    int* __restrict__ offsets, int n){
  __shared__ int wsum[16];
  __shared__ int sbase;
  int t = threadIdx.x, lane = t & 63, w = t >> 6;
  if (t == 0) sbase = 0;
  __syncthreads();
  for (int start = 0; start < n; start += 1024){
    int i = start + t;
    int x = (i < n) ? cnt[i] : 0;
    #pragma unroll
    for (int off = 1; off < 64; off <<= 1){ int y = __shfl_up(x, off); if (lane >= off) x += y; }
    if (lane == 63) wsum[w] = x;
    __syncthreads();
    if (w == 0 && lane < 16){
      int sv = wsum[lane];
      #pragma unroll
      for (int off = 1; off < 16; off <<= 1){ int y = __shfl_up(sv, off); if (lane >= off) sv += y; }
      wsum[lane] = sv;
    }
    __syncthreads();
    int base = sbase + (w > 0 ? wsum[w-1] : 0);
    if (i < n) offsets[i+1] = base + x;
    __syncthreads();
    if (t == 0) sbase += wsum[15];
    __syncthreads();
  }
  if (t == 0) offsets[0] = 0;
}

// srcattr packed: {src, bf16(a0) | bf16(a1)<<16}
__global__ __launch_bounds__(256) void scatter_kernel(const int* __restrict__ ei,
                                                      const float* __restrict__ ea,
                                                      const int* __restrict__ offsets,
                                                      int* __restrict__ cursor,
                                                      int2* __restrict__ srcattr){
  int e = blockIdx.x*256 + threadIdx.x;
  if (e < NE){
    int dstn = ei[NE + e];
    int pos  = atomicAdd(&cursor[dstn], 1);
    float2 a = *(const float2*)(ea + 2*e);
    unsigned pa = (unsigned)f2bf(a.x) | ((unsigned)f2bf(a.y) << 16);
    srcattr[offsets[dstn] + pos] = make_int2(ei[e], (int)pa);
  }
}

// -------------------------------------------------- conv weight pre-transform (bf16)
__global__ __launch_bounds__(256) void prep_weights(
    const float* __restrict__ w1, const float* __restrict__ w2,
    unsigned short* __restrict__ W1t, unsigned short* __restrict__ W2t)
{
  int t = threadIdx.x;
  if (blockIdx.x == 0){
    for (int i = t; i < 3072; i += 256){
      int j = i & 7, oc = (i >> 3) & 31, g = (i >> 8) & 3, m = i >> 10;
      int tap = m*4 + g;
      float v = (tap < 9 && j < 6) ? w1[oc*54 + j*9 + tap] : 0.f;
      W1t[i] = f2bf(v);
    }
  } else {
    for (int i = t; i < 18432; i += 256){
      int j = i & 7, oc = (i >> 3) & 63, g = (i >> 9) & 3, tap = i >> 11;
      int ic = g*8 + j;
      W2t[i] = f2bf(w2[oc*288 + ic*9 + tap]);
    }
  }
}

// -------------------------------------------------- fold uvfc into layer-1 W: Weff[128][128]
__global__ __launch_bounds__(256) void prep_fold(
    const float* __restrict__ fcw, const float* __restrict__ fcb,
    const float* __restrict__ g1W, const float* __restrict__ g1b,
    float* __restrict__ Weff, float* __restrict__ beff)
{
  int idx = blockIdx.x*256 + threadIdx.x;
  if (idx < 16384){
    int r = idx >> 7, c = idx & 127;
    float acc;
    if (r < 64){
      acc = 0.f;
      #pragma unroll 4
      for (int m = 0; m < 128; m++) acc += fcw[r*128 + m] * g1W[m*128 + c];
    } else {
      acc = g1W[(64 + r)*128 + c];
    }
    Weff[idx] = acc;
  }
  if (blockIdx.x == 0 && threadIdx.x < 128){
    int c = threadIdx.x;
    float acc = g1b[c];
    #pragma unroll 4
    for (int m = 0; m < 128; m++) acc += fcb[m] * g1W[m*128 + c];
    beff[c] = acc;
  }
}

// -------------------------------------------------- GEMM weight pre-transform: frag-linear hi/lo
__global__ __launch_bounds__(256) void prep_gemm(
    const float* __restrict__ W, int total,
    unsigned short* __restrict__ Wh, unsigned short* __restrict__ Wl)
{
  for (int i = blockIdx.x*256 + threadIdx.x; i < total; i += gridDim.x*256){
    int j = i & 7, lx = (i >> 3) & 63, nt = (i >> 9) & 7, ks = i >> 12;
    int k = ks*32 + (lx >> 4)*8 + j;
    int col = nt*16 + (lx & 15);
    float v = W[k*128 + col];
    unsigned short h16 = f2bf(v);
    Wh[i] = h16;
    Wl[i] = f2bf(v - bf2f(h16));
  }
}

// -------------------------------------------- UV + sym encoder, MFMA, W2 resident in LDS
__global__ __launch_bounds__(256, 2) void uv_mfma_kernel(
    const float* __restrict__ x_vis, const float* __restrict__ x_sym,
    const unsigned short* __restrict__ W1t, const unsigned short* __restrict__ W2t,
    const float* __restrict__ b1, const float* __restrict__ b2,
    const float* __restrict__ s1w, const float* __restrict__ s1b,
    const float* __restrict__ s2w, const float* __restrict__ s2b,
    float* __restrict__ x128)
{
  __shared__ __align__(16) unsigned short Wlds[18432];
  __shared__ __align__(16) unsigned short xic[4*800];
  __shared__ __align__(16) unsigned short c1p[4*4000];
  __shared__ float symh[4][64];

  const int t = threadIdx.x;
  const int w = t >> 6, l = t & 63;
  const int g = l >> 4, r16 = l & 15;
  const int xb = r16 & 7, yb = r16 >> 3;
  const int n = blockIdx.x*4 + w;

  {
    const uint4* src = (const uint4*)W2t;
    uint4* dst = (uint4*)Wlds;
    #pragma unroll
    for (int i = 0; i < 9; i++) dst[t + i*256] = src[t + i*256];
  }

  uint4 z4 = {0,0,0,0};
  {
    uint4* zx = (uint4*)(xic + w*800);
    #pragma unroll
    for (int i = 0; i < 2; i++) if (l + i*64 < 100) zx[l + i*64] = z4;
    uint4* zc = (uint4*)(c1p + w*4000);
    #pragma unroll
    for (int i = 0; i < 8; i++) if (l + i*64 < 500) zc[l + i*64] = z4;
  }

  {
    const float* xv = x_vis + (size_t)n*384;
    #pragma unroll
    for (int it = 0; it < 6; it++){
      int i = l + it*64;
      int ic = i >> 6, yx = i & 63, y = yx >> 3, x = yx & 7;
      xic[w*800 + ((y+1)*10 + (x+1))*8 + ic] = f2bf(xv[i]);
    }
  }

  uint4 B1[3][2];
  #pragma unroll
  for (int m = 0; m < 3; m++)
    #pragma unroll
    for (int nt = 0; nt < 2; nt++)
      B1[m][nt] = *(const uint4*)(W1t + m*1024 + g*256 + (nt*16 + r16)*8);

  const int t0 = g;     const int dy0 = t0/3, dx0 = t0%3;
  const int t1 = 4 + g; const int dy1 = t1/3, dx1 = t1%3;
  const int dy2 = 2, dx2 = 2;

  const float b1a = b1[r16], b1c = b1[16 + r16];
  f32x4 acc1[4][2];
  #pragma unroll
  for (int mt = 0; mt < 4; mt++){
    acc1[mt][0] = (f32x4){b1a, b1a, b1a, b1a};
    acc1[mt][1] = (f32x4){b1c, b1c, b1c, b1c};
  }
  const unsigned short* xn = xic + w*800;
  #pragma unroll
  for (int mt = 0; mt < 4; mt++){
    const int Y = mt*2 + yb;
    bf16x8 A0 = ld_frag(xn + (Y+dy0)*80 + (xb+dx0)*8);
    bf16x8 A1 = ld_frag(xn + (Y+dy1)*80 + (xb+dx1)*8);
    bf16x8 A2 = ld_frag(xn + (Y+dy2)*80 + (xb+dx2)*8);
    #pragma unroll
    for (int nt = 0; nt < 2; nt++){
      acc1[mt][nt] = __builtin_amdgcn_mfma_f32_16x16x32_bf16(A0, __builtin_bit_cast(bf16x8, B1[0][nt]), acc1[mt][nt], 0,0,0);
      acc1[mt][nt] = __builtin_amdgcn_mfma_f32_16x16x32_bf16(A1, __builtin_bit_cast(bf16x8, B1[1][nt]), acc1[mt][nt], 0,0,0);
      acc1[mt][nt] = __builtin_amdgcn_mfma_f32_16x16x32_bf16(A2, __builtin_bit_cast(bf16x8, B1[2][nt]), acc1[mt][nt], 0,0,0);
    }
  }
  unsigned short* cn = c1p + w*4000;
  #pragma unroll
  for (int mt = 0; mt < 4; mt++)
    #pragma unroll
    for (int nt = 0; nt < 2; nt++)
      #pragma unroll
      for (int j = 0; j < 4; j++){
        int rowl = g*4 + j;
        int y = mt*2 + (rowl >> 3), x = rowl & 7;
        float v = acc1[mt][nt][j]; v = v > 0.f ? v : 0.f;
        cn[((y+1)*10 + (x+1))*40 + nt*16 + r16] = f2bf(v);
      }

  __syncthreads();   // Wlds ready (and own c1p writes drained)

  float b2v[4];
  #pragma unroll
  for (int nt = 0; nt < 4; nt++) b2v[nt] = b2[nt*16 + r16];
  f32x4 acc2[4][4];
  #pragma unroll
  for (int mt = 0; mt < 4; mt++)
    #pragma unroll
    for (int nt = 0; nt < 4; nt++)
      acc2[mt][nt] = (f32x4){b2v[nt], b2v[nt], b2v[nt], b2v[nt]};

  #pragma unroll
  for (int tap = 0; tap < 9; tap++){
    const int dy = tap/3, dx = tap%3;
    uint4 Bv[4];
    #pragma unroll
    for (int nt = 0; nt < 4; nt++)
      Bv[nt] = *(const uint4*)(Wlds + tap*2048 + g*512 + (nt*16 + r16)*8);
    uint4 Av[4];
    #pragma unroll
    for (int mt = 0; mt < 4; mt++){
      int Y = mt*2 + yb + dy, X = xb + dx;
      Av[mt] = *(const uint4*)(cn + (Y*10 + X)*40 + g*8);
    }
    #pragma unroll
    for (int mt = 0; mt < 4; mt++)
      #pragma unroll
      for (int nt = 0; nt < 4; nt++)
        acc2[mt][nt] = __builtin_amdgcn_mfma_f32_16x16x32_bf16(
            __builtin_bit_cast(bf16x8, Av[mt]), __builtin_bit_cast(bf16x8, Bv[nt]), acc2[mt][nt], 0,0,0);
  }

  float* xo = x128 + (size_t)n*128;
  #pragma unroll
  for (int nt = 0; nt < 4; nt++){
    float s = 0.f;
    #pragma unroll
    for (int mt = 0; mt < 4; mt++)
      #pragma unroll
      for (int j = 0; j < 4; j++){
        float v = acc2[mt][nt][j]; s += (v > 0.f ? v : 0.f);
      }
    s += __shfl_xor(s, 16);
    s += __shfl_xor(s, 32);
    if (l < 16) xo[nt*16 + l] = s * (1.f/64.f);
  }
  {
    const float* xs = x_sym + (size_t)n*3;
    float a = s1b[l] + xs[0]*s1w[l] + xs[1]*s1w[64+l] + xs[2]*s1w[128+l];
    symh[w][l] = a > 0.f ? a : 0.f;
  }
  {
    float a = s2b[l];
    #pragma unroll 8
    for (int k = 0; k < 64; k++) a = fmaf(symh[w][k], s2w[k*64 + l], a);
    xo[64 + l] = a > 0.f ? a : 0.f;
  }
}

// ---------------- node GEMM: h = x@W + b via split-bf16 MFMA; fused s,d dots; h stored bf16.
template<int K>
__global__ __launch_bounds__(256) void node_gemm(
    const float* __restrict__ xin,
    const unsigned short* __restrict__ Wh, const unsigned short* __restrict__ Wl,
    const float* __restrict__ b,
    const float* __restrict__ asrc, const float* __restrict__ adst,
    unsigned short* __restrict__ h_out, float* __restrict__ s_out, float* __restrict__ d_out)
{
  const int w = threadIdx.x >> 6, l = threadIdx.x & 63;
  const int g = l >> 4, r16 = l & 15;
  const int wid = blockIdx.x*4 + w;
  if (wid >= NND/16) return;
  const int rowbase = wid*16;

  f32x4 acc[8];
  #pragma unroll
  for (int nt = 0; nt < 8; nt++){
    float bv = b[nt*16 + r16];
    acc[nt] = (f32x4){bv, bv, bv, bv};
  }

  const float* xr = xin + (size_t)(rowbase + r16)*K + g*8;
  #pragma unroll 2
  for (int ks = 0; ks < K/32; ks++){
    float4 xa = *(const float4*)(xr + ks*32);
    float4 xb = *(const float4*)(xr + ks*32 + 4);
    float xs[8] = {xa.x,xa.y,xa.z,xa.w,xb.x,xb.y,xb.z,xb.w};
    bf16x8 Ah, Al;
    #pragma unroll
    for (int j = 0; j < 8; j++){
      unsigned short h16 = f2bf(xs[j]);
      Ah[j] = (short)h16;
      Al[j] = (short)f2bf(xs[j] - bf2f(h16));
    }
    #pragma unroll
    for (int nt = 0; nt < 8; nt++){
      const int fo = (((ks*8 + nt)*64 + l)*8);
      bf16x8 Bh = ld_frag(Wh + fo);
      bf16x8 Bl = ld_frag(Wl + fo);
      acc[nt] = __builtin_amdgcn_mfma_f32_16x16x32_bf16(Ah, Bh, acc[nt], 0,0,0);
      acc[nt] = __builtin_amdgcn_mfma_f32_16x16x32_bf16(Al, Bh, acc[nt], 0,0,0);
      acc[nt] = __builtin_amdgcn_mfma_f32_16x16x32_bf16(Ah, Bl, acc[nt], 0,0,0);
    }
  }

  #pragma unroll
  for (int nt = 0; nt < 8; nt++)
    #pragma unroll
    for (int j = 0; j < 4; j++)
      h_out[(size_t)(rowbase + g*4 + j)*128 + nt*16 + r16] = f2bf(acc[nt][j]);

  float as_v[8], ad_v[8];
  #pragma unroll
  for (int nt = 0; nt < 8; nt++){
    as_v[nt] = asrc[nt*16 + r16];
    ad_v[nt] = adst[nt*16 + r16];
  }
  float sp[4][4], dp[4][4];
  #pragma unroll
  for (int hd = 0; hd < 4; hd++)
    #pragma unroll
    for (int j = 0; j < 4; j++){
      sp[hd][j] = acc[2*hd][j]*as_v[2*hd] + acc[2*hd+1][j]*as_v[2*hd+1];
      dp[hd][j] = acc[2*hd][j]*ad_v[2*hd] + acc[2*hd+1][j]*ad_v[2*hd+1];
    }
  #pragma unroll
  for (int o = 1; o < 16; o <<= 1)
    #pragma unroll
    for (int hd = 0; hd < 4; hd++)
      #pragma unroll
      for (int j = 0; j < 4; j++){
        sp[hd][j] += __shfl_xor(sp[hd][j], o);
        dp[hd][j] += __shfl_xor(dp[hd][j], o);
      }
  #pragma unroll
  for (int hd = 0; hd < 4; hd++){
    if (r16 == hd)
      #pragma unroll
      for (int j = 0; j < 4; j++)
        s_out[(rowbase + g*4 + j)*4 + hd] = sp[hd][j];
    if (r16 == 8 + hd)
      #pragma unroll
      for (int j = 0; j < 4; j++)
        d_out[(rowbase + g*4 + j)*4 + hd] = dp[hd][j];
  }
}

// -------------------------------------------- GAT aggregation, wave per dst node
// inner loop: 2 edges/iter, lane reads 4 bf16 channels (uint2) of edge j+(l>>5).
// FUSE_CLS: final layer fuses classifier, writes d_out[v*25..] instead of xout.
template<bool FUSE_CLS>
__global__ __launch_bounds__(256) void gat_aggregate(
    const float* __restrict__ sarr, const float* __restrict__ darr,
    const unsigned short* __restrict__ hb,
    const int2* __restrict__ srcattr, const int* __restrict__ offsets,
    const float* __restrict__ We, const float* __restrict__ be,
    const float* __restrict__ aedge, const float* __restrict__ Wg, const float* __restrict__ bgp,
    float* __restrict__ xout,
    const float* __restrict__ cw1, const float* __restrict__ cb1,
    const float* __restrict__ cw2, const float* __restrict__ cb2,
    float* __restrict__ out)
{
  __shared__ int2 ew[4][2][4][64];   // [wave][buf][head][edge] = {w_bits, src}
  __shared__ float xrow[4][128];
  __shared__ float hrow[4][64];
  const int l  = threadIdx.x & 63;
  const int w  = threadIdx.x >> 6;
  const int v  = blockIdx.x*4 + w;
  const int hd = l >> 4;
  const int c0 = 2*l;
  const int eoff = l >> 5;           // which of the 2 edges this lane gathers
  const int hd2  = (l & 31) >> 3;    // head of this lane's channel quad
  const int c4   = (l & 31) * 4;     // first channel of the quad

  // per-head edge-logit projections (P = We^T a_edge per head, PC = be^T a_edge)
  float ae0 = aedge[hd*32 + (c0&31)];
  float ae1 = aedge[hd*32 + ((c0+1)&31)];
  float we00 = We[c0], we01 = We[c0+1], we10 = We[128+c0], we11 = We[128+c0+1];
  float beA = be[c0], beB = be[c0+1];
  float p0 = we00*ae0 + we01*ae1;
  float p1 = we10*ae0 + we11*ae1;
  float pc = beA*ae0 + beB*ae1;
  #pragma unroll
  for (int o = 1; o < 16; o <<= 1){ p0 += __shfl_xor(p0,o); p1 += __shfl_xor(p1,o); pc += __shfl_xor(pc,o); }
  float P00=__shfl(p0,0), P01=__shfl(p0,16), P02=__shfl(p0,32), P03=__shfl(p0,48);
  float P10=__shfl(p1,0), P11=__shfl(p1,16), P12=__shfl(p1,32), P13=__shfl(p1,48);
  float PC0=__shfl(pc,0), PC1=__shfl(pc,16), PC2=__shfl(pc,32), PC3=__shfl(pc,48);
  const float wg0 = Wg[0], wg1 = Wg[1], bgv = bgp[0];

  const int off = offsets[v];
  const int deg = offsets[v+1] - off;
  const float4 d4 = *(const float4*)(darr + (size_t)v*4);

  float dn0=0.f,dn1=0.f,dn2=0.f,dn3=0.f;
  float Sm0=0.f,Sm1=0.f,Sm2=0.f,Sm3=0.f;
  float S00=0.f,S01=0.f,S02=0.f,S03=0.f;
  float S10=0.f,S11=0.f,S12=0.f,S13=0.f;
  float4 acc4 = make_float4(0.f, 0.f, 0.f, 0.f);

  int pb = 0;
  for (int base = 0; base < deg; base += 64, pb ^= 1){
    int ii = base + l;
    float w0=0.f,w1=0.f,w2=0.f,w3=0.f; int sj=0;
    if (ii < deg){
      int2 sa = srcattr[off + ii];
      sj = sa.x;
      unsigned pa = (unsigned)sa.y;
      float a0 = __uint_as_float(pa << 16);
      float a1 = __uint_as_float(pa & 0xffff0000u);
      const float4 sv = *(const float4*)(sarr + (size_t)sj*4);
      float e0 = __expf(leaky02(sv.x + d4.x + a0*P00 + a1*P10 + PC0));
      float e1 = __expf(leaky02(sv.y + d4.y + a0*P01 + a1*P11 + PC1));
      float e2 = __expf(leaky02(sv.z + d4.z + a0*P02 + a1*P12 + PC2));
      float e3 = __expf(leaky02(sv.w + d4.w + a0*P03 + a1*P13 + PC3));
      float gt = 1.f/(1.f + __expf(-(a0*wg0 + a1*wg1 + bgv)));
      dn0 += e0; dn1 += e1; dn2 += e2; dn3 += e3;
      w0 = gt*e0; w1 = gt*e1; w2 = gt*e2; w3 = gt*e3;
      Sm0 += w0; Sm1 += w1; Sm2 += w2; Sm3 += w3;
      S00 += w0*a0; S01 += w1*a0; S02 += w2*a0; S03 += w3*a0;
      S10 += w0*a1; S11 += w1*a1; S12 += w2*a1; S13 += w3*a1;
    }
    ew[w][pb][0][l] = make_int2(__float_as_int(w0), sj);
    ew[w][pb][1][l] = make_int2(__float_as_int(w1), sj);
    ew[w][pb][2][l] = make_int2(__float_as_int(w2), sj);
    ew[w][pb][3][l] = make_int2(__float_as_int(w3), sj);
    asm volatile("s_waitcnt lgkmcnt(0)" ::: "memory");
    const int2* eb2 = &ew[w][pb][hd2][0];
    int lim = min(64, deg - base);
    #pragma unroll 4
    for (int j = 0; j < lim; j += 2){
      int2 ws = eb2[j + eoff];
      float wv = __int_as_float(ws.x);
      uint2 hv = *(const uint2*)(hb + (((size_t)ws.y) << 7) + c4);
      acc4.x = fmaf(__uint_as_float(hv.x << 16),        wv, acc4.x);
      acc4.y = fmaf(__uint_as_float(hv.x & 0xffff0000u), wv, acc4.y);
      acc4.z = fmaf(__uint_as_float(hv.y << 16),        wv, acc4.z);
      acc4.w = fmaf(__uint_as_float(hv.y & 0xffff0000u), wv, acc4.w);
    }
  }

  // combine the two edge-halves (lanes l and l+32 hold same channels)
  acc4.x += __shfl_xor(acc4.x, 32);
  acc4.y += __shfl_xor(acc4.y, 32);
  acc4.z += __shfl_xor(acc4.z, 32);
  acc4.w += __shfl_xor(acc4.w, 32);

  #pragma unroll
  for (int o = 1; o < 64; o <<= 1){
    dn0 += __shfl_xor(dn0,o); dn1 += __shfl_xor(dn1,o); dn2 += __shfl_xor(dn2,o); dn3 += __shfl_xor(dn3,o);
    Sm0 += __shfl_xor(Sm0,o); Sm1 += __shfl_xor(Sm1,o); Sm2 += __shfl_xor(Sm2,o); Sm3 += __shfl_xor(Sm3,o);
    S00 += __shfl_xor(S00,o); S01 += __shfl_xor(S01,o); S02 += __shfl_xor(S02,o); S03 += __shfl_xor(S03,o);
    S10 += __shfl_xor(S10,o); S11 += __shfl_xor(S11,o); S12 += __shfl_xor(S12,o); S13 += __shfl_xor(S13,o);
  }
  float den = (hd2==0)?dn0:(hd2==1)?dn1:(hd2==2)?dn2:dn3;
  float Smh = (hd2==0)?Sm0:(hd2==1)?Sm1:(hd2==2)?Sm2:Sm3;
  float S0h = (hd2==0)?S00:(hd2==1)?S01:(hd2==2)?S02:S03;
  float S1h = (hd2==0)?S10:(hd2==1)?S11:(hd2==2)?S12:S13;
  float rden = 1.f/(den + 1e-16f);
  float4 be4 = *(const float4*)(be + c4);
  float4 w04 = *(const float4*)(We + c4);
  float4 w14 = *(const float4*)(We + 128 + c4);
  float4 o4;
  o4.x = (acc4.x + be4.x*Smh + w04.x*S0h + w14.x*S1h) * rden;
  o4.y = (acc4.y + be4.y*Smh + w04.y*S0h + w14.y*S1h) * rden;
  o4.z = (acc4.z + be4.z*Smh + w04.z*S0h + w14.z*S1h) * rden;
  o4.w = (acc4.w + be4.w*Smh + w04.w*S0h + w14.w*S1h) * rden;
  o4.x = o4.x > 0.f ? o4.x : (__expf(o4.x) - 1.f);
  o4.y = o4.y > 0.f ? o4.y : (__expf(o4.y) - 1.f);
  o4.z = o4.z > 0.f ? o4.z : (__expf(o4.z) - 1.f);
  o4.w = o4.w > 0.f ? o4.w : (__expf(o4.w) - 1.f);

  if constexpr (!FUSE_CLS){
    if (l < 32) *(float4*)(xout + (size_t)v*128 + c4) = o4;
  } else {
    // classifier fused: 128 -> relu 64 -> 25
    if (l < 32) *(float4*)&xrow[w][c4] = o4;
    asm volatile("s_waitcnt lgkmcnt(0)" ::: "memory");
    float a = cb1[l];
    #pragma unroll 8
    for (int k = 0; k < 128; k++) a = fmaf(xrow[w][k], cw1[k*64 + l], a);
    hrow[w][l] = a > 0.f ? a : 0.f;
    asm volatile("s_waitcnt lgkmcnt(0)" ::: "memory");
    if (l < 25){
      float o = cb2[l];
      #pragma unroll 8
      for (int k = 0; k < 64; k++) o = fmaf(hrow[w][k], cw2[k*25 + l], o);
      out[(size_t)v*25 + l] = o;
    }
  }
}

// ---------------------------------------------------------------- launch
extern "C" void kernel_launch(void* const* d_in, const int* in_sizes, int n_in,
                              void* d_out, int out_size, void* d_ws, size_t ws_size,
                              hipStream_t stream)
{
  (void)in_sizes; (void)n_in; (void)out_size; (void)ws_size;
  const float* x_vis   = (const float*)d_in[0];
  const float* x_sym   = (const float*)d_in[1];
  const int*   ei      = (const int*)  d_in[2];
  const float* ea      = (const float*)d_in[3];
  const float* c1w     = (const float*)d_in[4];
  const float* c1b     = (const float*)d_in[5];
  const float* c2w     = (const float*)d_in[6];
  const float* c2b     = (const float*)d_in[7];
  const float* fcw     = (const float*)d_in[8];
  const float* fcb     = (const float*)d_in[9];
  const float* s1w     = (const float*)d_in[10];
  const float* s1b     = (const float*)d_in[11];
  const float* s2w     = (const float*)d_in[12];
  const float* s2b     = (const float*)d_in[13];
  const float* g1W     = (const float*)d_in[14];
  const float* g1b     = (const float*)d_in[15];
  const float* g1We    = (const float*)d_in[16];
  const float* g1be    = (const float*)d_in[17];
  const float* g1asrc  = (const float*)d_in[18];
  const float* g1adst  = (const float*)d_in[19];
  const float* g1aedge = (const float*)d_in[20];
  const float* g1Wg    = (const float*)d_in[21];
  const float* g1bg    = (const float*)d_in[22];
  const float* g2W     = (const float*)d_in[23];
  const float* g2b     = (const float*)d_in[24];
  const float* g2We    = (const float*)d_in[25];
  const float* g2be    = (const float*)d_in[26];
  const float* g2asrc  = (const float*)d_in[27];
  const float* g2adst  = (const float*)d_in[28];
  const float* g2aedge = (const float*)d_in[29];
  const float* g2Wg    = (const float*)d_in[30];
  const float* g2bg    = (const float*)d_in[31];
  const float* cw1     = (const float*)d_in[32];
  const float* cb1     = (const float*)d_in[33];
  const float* cw2     = (const float*)d_in[34];
  const float* cb2     = (const float*)d_in[35];

  size_t off = 0;
  auto take = [&](size_t bytes) -> void* {
    off = (off + 255) & ~(size_t)255;
    void* p = (char*)d_ws + off;
    off += bytes;
    return p;
  };
  int*   cnt     = (int*)  take((size_t)NND*4);
  int*   offs    = (int*)  take((size_t)(NND+1)*4);
  int2*  srcattr = (int2*) take((size_t)NE*8);
  float* x128    = (float*)take((size_t)NND*128*4);
  unsigned short* hb = (unsigned short*)take((size_t)NND*128*2);
  float* sbuf    = (float*)take((size_t)NND*4*4);
  float* dbuf    = (float*)take((size_t)NND*4*4);
  float* x2      = (float*)take((size_t)NND*128*4);
  unsigned short* W1t = (unsigned short*)take(3072*2);
  unsigned short* W2t = (unsigned short*)take(18432*2);
  float* Weff    = (float*)take(16384*4);
  float* beff    = (float*)take(128*4);
  unsigned short* G1h = (unsigned short*)take(16384*2);
  unsigned short* G1l = (unsigned short*)take(16384*2);
  unsigned short* G2h = (unsigned short*)take(16384*2);
  unsigned short* G2l = (unsigned short*)take(16384*2);

  // weight pre-transforms
  prep_weights<<<2, 256, 0, stream>>>(c1w, c2w, W1t, W2t);
  prep_fold<<<64, 256, 0, stream>>>(fcw, fcb, g1W, g1b, Weff, beff);
  prep_gemm<<<64, 256, 0, stream>>>(Weff, 16384, G1h, G1l);
  prep_gemm<<<64, 256, 0, stream>>>(g2W, 16384, G2h, G2l);

  // CSR build (graph identical for both GAT layers)
  hipMemsetAsync(cnt, 0, (size_t)NND*4, stream);
  hist_kernel<<<(NE+255)/256, 256, 0, stream>>>(ei, cnt);
  scan_kernel<<<1, 1024, 0, stream>>>(cnt, offs, NND);
  hipMemsetAsync(cnt, 0, (size_t)NND*4, stream);
  scatter_kernel<<<(NE+255)/256, 256, 0, stream>>>(ei, ea, offs, cnt, srcattr);

  // encoders (MFMA, 4 nodes/block, W2 in LDS)
  uv_mfma_kernel<<<NND/4, 256, 0, stream>>>(x_vis, x_sym, W1t, W2t, c1b, c2b,
                                            s1w, s1b, s2w, s2b, x128);
  // GAT layer 1 (uvfc folded into Weff)
  node_gemm<128><<<(NND/16 + 3)/4, 256, 0, stream>>>(x128, G1h, G1l, beff, g1asrc, g1adst,
                                                     hb, sbuf, dbuf);
  gat_aggregate<false><<<NND/4, 256, 0, stream>>>(sbuf, dbuf, hb, srcattr, offs,
                                                  g1We, g1be, g1aedge, g1Wg, g1bg, x2,
                                                  nullptr, nullptr, nullptr, nullptr, nullptr);
  // GAT layer 2 + fused classifier
  node_gemm<128><<<(NND/16 + 3)/4, 256, 0, stream>>>(x2, G2h, G2l, g2b, g2asrc, g2adst,
                                                     hb, sbuf, dbuf);
  gat_aggregate<true><<<NND/4, 256, 0, stream>>>(sbuf, dbuf, hb, srcattr, offs,
                                                 g2We, g2be, g2aedge, g2Wg, g2bg, nullptr,
                                                 cw1, cb1, cw2, cb2, (float*)d_out);
}

// Round 7
// 601.902 us; speedup vs baseline: 4.8419x; 1.1071x over previous
//
#include <hip/hip_runtime.h>

#define NND 50000
#define NE  1600000
#define SCAN_B 196   // ceil(NND/256)

typedef __attribute__((ext_vector_type(8))) short bf16x8;
typedef __attribute__((ext_vector_type(4))) float f32x4;

__device__ __forceinline__ float leaky02(float x){ return x > 0.f ? x : 0.2f*x; }
__device__ __forceinline__ unsigned short f2bf(float f){
  unsigned u = __float_as_uint(f);
  u = (u + 0x7fffu + ((u >> 16) & 1u)) >> 16;
  return (unsigned short)u;
}
__device__ __forceinline__ float bf2f(unsigned short h){
  return __uint_as_float(((unsigned)h) << 16);
}
__device__ __forceinline__ bf16x8 ld_frag(const unsigned short* p){
  return __builtin_bit_cast(bf16x8, *(const uint4*)p);
}

// ---------------------------------------------------------------- CSR build
__global__ __launch_bounds__(256) void hist_kernel(const int* __restrict__ ei,
                                                   int* __restrict__ cnt){
  int e = blockIdx.x*256 + threadIdx.x;
  if (e < NE) atomicAdd(&cnt[ei[NE + e]], 1);
}

// multiblock scan: local inclusive scan + block sums
__global__ __launch_bounds__(256) void scan1_kernel(const int* __restrict__ cnt,
                                                    int* __restrict__ offsets,
                                                    int* __restrict__ bsum){
  __shared__ int wsum[4];
  int t = threadIdx.x, lane = t & 63, wv = t >> 6;
  int i = blockIdx.x*256 + t;
  int x = (i < NND) ? cnt[i] : 0;
  int s = x;
  #pragma unroll
  for (int o = 1; o < 64; o <<= 1){ int y = __shfl_up(s, o); if (lane >= o) s += y; }
  if (lane == 63) wsum[wv] = s;
  __syncthreads();
  if (t == 0){
    int a = wsum[0], b = wsum[1], c = wsum[2];
    wsum[0] = 0; wsum[1] = a; wsum[2] = a + b; wsum[3] = a + b + c;
  }
  __syncthreads();
  s += wsum[wv];
  if (i < NND) offsets[i+1] = s;
  if (t == 255) bsum[blockIdx.x] = s;
}

__global__ __launch_bounds__(256) void scan2_kernel(const int* __restrict__ bsum,
                                                    int* __restrict__ bbase){
  __shared__ int wsum[4];
  int t = threadIdx.x, lane = t & 63, wv = t >> 6;
  int x = (t < SCAN_B) ? bsum[t] : 0;
  int s = x;
  #pragma unroll
  for (int o = 1; o < 64; o <<= 1){ int y = __shfl_up(s, o); if (lane >= o) s += y; }
  if (lane == 63) wsum[wv] = s;
  __syncthreads();
  if (t == 0){
    int a = wsum[0], b = wsum[1], c = wsum[2];
    wsum[0] = 0; wsum[1] = a; wsum[2] = a + b; wsum[3] = a + b + c;
  }
  __syncthreads();
  s += wsum[wv];
  if (t < SCAN_B) bbase[t] = s - x;   // exclusive
}

__global__ __launch_bounds__(256) void scan3_kernel(int* __restrict__ offsets,
                                                    const int* __restrict__ bbase){
  int i = blockIdx.x*256 + threadIdx.x;
  int add = bbase[blockIdx.x];
  if (i < NND) offsets[i+1] += add;
  if (i == 0) offsets[0] = 0;
}

// srcattr packed: {src, bf16(a0) | bf16(a1)<<16}; cursor = cnt (counts, consumed via atomicSub)
__global__ __launch_bounds__(256) void scatter_kernel(const int* __restrict__ ei,
                                                      const float* __restrict__ ea,
                                                      const int* __restrict__ offsets,
                                                      int* __restrict__ cnt,
                                                      int2* __restrict__ srcattr){
  int e = blockIdx.x*256 + threadIdx.x;
  if (e < NE){
    int dstn = ei[NE + e];
    int pos  = atomicSub(&cnt[dstn], 1) - 1;
    float2 a = *(const float2*)(ea + 2*e);
    unsigned pa = (unsigned)f2bf(a.x) | ((unsigned)f2bf(a.y) << 16);
    srcattr[offsets[dstn] + pos] = make_int2(ei[e], (int)pa);
  }
}

// -------------------------------------------------- conv weight pre-transform (bf16)
__global__ __launch_bounds__(256) void prep_weights(
    const float* __restrict__ w1, const float* __restrict__ w2,
    unsigned short* __restrict__ W1t, unsigned short* __restrict__ W2t)
{
  int t = threadIdx.x;
  if (blockIdx.x == 0){
    for (int i = t; i < 3072; i += 256){
      int j = i & 7, oc = (i >> 3) & 31, g = (i >> 8) & 3, m = i >> 10;
      int tap = m*4 + g;
      float v = (tap < 9 && j < 6) ? w1[oc*54 + j*9 + tap] : 0.f;
      W1t[i] = f2bf(v);
    }
  } else {
    for (int i = t; i < 18432; i += 256){
      int j = i & 7, oc = (i >> 3) & 63, g = (i >> 9) & 3, tap = i >> 11;
      int ic = g*8 + j;
      W2t[i] = f2bf(w2[oc*288 + ic*9 + tap]);
    }
  }
}

// -------------------------------------------------- fold uvfc into layer-1 W: Weff[128][128]
__global__ __launch_bounds__(256) void prep_fold(
    const float* __restrict__ fcw, const float* __restrict__ fcb,
    const float* __restrict__ g1W, const float* __restrict__ g1b,
    float* __restrict__ Weff, float* __restrict__ beff)
{
  int idx = blockIdx.x*256 + threadIdx.x;
  if (idx < 16384){
    int r = idx >> 7, c = idx & 127;
    float acc;
    if (r < 64){
      acc = 0.f;
      #pragma unroll 4
      for (int m = 0; m < 128; m++) acc += fcw[r*128 + m] * g1W[m*128 + c];
    } else {
      acc = g1W[(64 + r)*128 + c];
    }
    Weff[idx] = acc;
  }
  if (blockIdx.x == 0 && threadIdx.x < 128){
    int c = threadIdx.x;
    float acc = g1b[c];
    #pragma unroll 4
    for (int m = 0; m < 128; m++) acc += fcb[m] * g1W[m*128 + c];
    beff[c] = acc;
  }
}

// -------------------------------------------------- GEMM weight pre-transform: frag-linear hi/lo
__global__ __launch_bounds__(256) void prep_gemm(
    const float* __restrict__ W, int total,
    unsigned short* __restrict__ Wh, unsigned short* __restrict__ Wl)
{
  for (int i = blockIdx.x*256 + threadIdx.x; i < total; i += gridDim.x*256){
    int j = i & 7, lx = (i >> 3) & 63, nt = (i >> 9) & 7, ks = i >> 12;
    int k = ks*32 + (lx >> 4)*8 + j;
    int col = nt*16 + (lx & 15);
    float v = W[k*128 + col];
    unsigned short h16 = f2bf(v);
    Wh[i] = h16;
    Wl[i] = f2bf(v - bf2f(h16));
  }
}

// -------------------------------------------- UV + sym encoder, MFMA, W2 resident in LDS
__global__ __launch_bounds__(256, 2) void uv_mfma_kernel(
    const float* __restrict__ x_vis, const float* __restrict__ x_sym,
    const unsigned short* __restrict__ W1t, const unsigned short* __restrict__ W2t,
    const float* __restrict__ b1, const float* __restrict__ b2,
    const float* __restrict__ s1w, const float* __restrict__ s1b,
    const float* __restrict__ s2w, const float* __restrict__ s2b,
    float* __restrict__ x128)
{
  __shared__ __align__(16) unsigned short Wlds[18432];
  __shared__ __align__(16) unsigned short xic[4*800];
  __shared__ __align__(16) unsigned short c1p[4*4000];
  __shared__ float symh[4][64];

  const int t = threadIdx.x;
  const int w = t >> 6, l = t & 63;
  const int g = l >> 4, r16 = l & 15;
  const int xb = r16 & 7, yb = r16 >> 3;
  const int n = blockIdx.x*4 + w;

  {
    const uint4* src = (const uint4*)W2t;
    uint4* dst = (uint4*)Wlds;
    #pragma unroll
    for (int i = 0; i < 9; i++) dst[t + i*256] = src[t + i*256];
  }

  uint4 z4 = {0,0,0,0};
  {
    uint4* zx = (uint4*)(xic + w*800);
    #pragma unroll
    for (int i = 0; i < 2; i++) if (l + i*64 < 100) zx[l + i*64] = z4;
    uint4* zc = (uint4*)(c1p + w*4000);
    #pragma unroll
    for (int i = 0; i < 8; i++) if (l + i*64 < 500) zc[l + i*64] = z4;
  }

  {
    const float* xv = x_vis + (size_t)n*384;
    #pragma unroll
    for (int it = 0; it < 6; it++){
      int i = l + it*64;
      int ic = i >> 6, yx = i & 63, y = yx >> 3, x = yx & 7;
      xic[w*800 + ((y+1)*10 + (x+1))*8 + ic] = f2bf(xv[i]);
    }
  }

  uint4 B1[3][2];
  #pragma unroll
  for (int m = 0; m < 3; m++)
    #pragma unroll
    for (int nt = 0; nt < 2; nt++)
      B1[m][nt] = *(const uint4*)(W1t + m*1024 + g*256 + (nt*16 + r16)*8);

  const int t0 = g;     const int dy0 = t0/3, dx0 = t0%3;
  const int t1 = 4 + g; const int dy1 = t1/3, dx1 = t1%3;
  const int dy2 = 2, dx2 = 2;

  const float b1a = b1[r16], b1c = b1[16 + r16];
  f32x4 acc1[4][2];
  #pragma unroll
  for (int mt = 0; mt < 4; mt++){
    acc1[mt][0] = (f32x4){b1a, b1a, b1a, b1a};
    acc1[mt][1] = (f32x4){b1c, b1c, b1c, b1c};
  }
  const unsigned short* xn = xic + w*800;
  #pragma unroll
  for (int mt = 0; mt < 4; mt++){
    const int Y = mt*2 + yb;
    bf16x8 A0 = ld_frag(xn + (Y+dy0)*80 + (xb+dx0)*8);
    bf16x8 A1 = ld_frag(xn + (Y+dy1)*80 + (xb+dx1)*8);
    bf16x8 A2 = ld_frag(xn + (Y+dy2)*80 + (xb+dx2)*8);
    #pragma unroll
    for (int nt = 0; nt < 2; nt++){
      acc1[mt][nt] = __builtin_amdgcn_mfma_f32_16x16x32_bf16(A0, __builtin_bit_cast(bf16x8, B1[0][nt]), acc1[mt][nt], 0,0,0);
      acc1[mt][nt] = __builtin_amdgcn_mfma_f32_16x16x32_bf16(A1, __builtin_bit_cast(bf16x8, B1[1][nt]), acc1[mt][nt], 0,0,0);
      acc1[mt][nt] = __builtin_amdgcn_mfma_f32_16x16x32_bf16(A2, __builtin_bit_cast(bf16x8, B1[2][nt]), acc1[mt][nt], 0,0,0);
    }
  }
  unsigned short* cn = c1p + w*4000;
  #pragma unroll
  for (int mt = 0; mt < 4; mt++)
    #pragma unroll
    for (int nt = 0; nt < 2; nt++)
      #pragma unroll
      for (int j = 0; j < 4; j++){
        int rowl = g*4 + j;
        int y = mt*2 + (rowl >> 3), x = rowl & 7;
        float v = acc1[mt][nt][j]; v = v > 0.f ? v : 0.f;
        cn[((y+1)*10 + (x+1))*40 + nt*16 + r16] = f2bf(v);
      }

  __syncthreads();   // Wlds ready (and own c1p writes drained)

  float b2v[4];
  #pragma unroll
  for (int nt = 0; nt < 4; nt++) b2v[nt] = b2[nt*16 + r16];
  f32x4 acc2[4][4];
  #pragma unroll
  for (int mt = 0; mt < 4; mt++)
    #pragma unroll
    for (int nt = 0; nt < 4; nt++)
      acc2[mt][nt] = (f32x4){b2v[nt], b2v[nt], b2v[nt], b2v[nt]};

  #pragma unroll
  for (int tap = 0; tap < 9; tap++){
    const int dy = tap/3, dx = tap%3;
    uint4 Bv[4];
    #pragma unroll
    for (int nt = 0; nt < 4; nt++)
      Bv[nt] = *(const uint4*)(Wlds + tap*2048 + g*512 + (nt*16 + r16)*8);
    uint4 Av[4];
    #pragma unroll
    for (int mt = 0; mt < 4; mt++){
      int Y = mt*2 + yb + dy, X = xb + dx;
      Av[mt] = *(const uint4*)(cn + (Y*10 + X)*40 + g*8);
    }
    #pragma unroll
    for (int mt = 0; mt < 4; mt++)
      #pragma unroll
      for (int nt = 0; nt < 4; nt++)
        acc2[mt][nt] = __builtin_amdgcn_mfma_f32_16x16x32_bf16(
            __builtin_bit_cast(bf16x8, Av[mt]), __builtin_bit_cast(bf16x8, Bv[nt]), acc2[mt][nt], 0,0,0);
  }

  float* xo = x128 + (size_t)n*128;
  #pragma unroll
  for (int nt = 0; nt < 4; nt++){
    float s = 0.f;
    #pragma unroll
    for (int mt = 0; mt < 4; mt++)
      #pragma unroll
      for (int j = 0; j < 4; j++){
        float v = acc2[mt][nt][j]; s += (v > 0.f ? v : 0.f);
      }
    s += __shfl_xor(s, 16);
    s += __shfl_xor(s, 32);
    if (l < 16) xo[nt*16 + l] = s * (1.f/64.f);
  }
  {
    const float* xs = x_sym + (size_t)n*3;
    float a = s1b[l] + xs[0]*s1w[l] + xs[1]*s1w[64+l] + xs[2]*s1w[128+l];
    symh[w][l] = a > 0.f ? a : 0.f;
  }
  {
    float a = s2b[l];
    #pragma unroll 8
    for (int k = 0; k < 64; k++) a = fmaf(symh[w][k], s2w[k*64 + l], a);
    xo[64 + l] = a > 0.f ? a : 0.f;
  }
}

// ---------------- node GEMM: h = x@W + b via split-bf16 MFMA; fused s,d dots; h stored bf16.
template<int K>
__global__ __launch_bounds__(256) void node_gemm(
    const float* __restrict__ xin,
    const unsigned short* __restrict__ Wh, const unsigned short* __restrict__ Wl,
    const float* __restrict__ b,
    const float* __restrict__ asrc, const float* __restrict__ adst,
    unsigned short* __restrict__ h_out, float* __restrict__ s_out, float* __restrict__ d_out)
{
  const int w = threadIdx.x >> 6, l = threadIdx.x & 63;
  const int g = l >> 4, r16 = l & 15;
  const int wid = blockIdx.x*4 + w;
  if (wid >= NND/16) return;
  const int rowbase = wid*16;

  f32x4 acc[8];
  #pragma unroll
  for (int nt = 0; nt < 8; nt++){
    float bv = b[nt*16 + r16];
    acc[nt] = (f32x4){bv, bv, bv, bv};
  }

  const float* xr = xin + (size_t)(rowbase + r16)*K + g*8;
  #pragma unroll 2
  for (int ks = 0; ks < K/32; ks++){
    float4 xa = *(const float4*)(xr + ks*32);
    float4 xb = *(const float4*)(xr + ks*32 + 4);
    float xs[8] = {xa.x,xa.y,xa.z,xa.w,xb.x,xb.y,xb.z,xb.w};
    bf16x8 Ah, Al;
    #pragma unroll
    for (int j = 0; j < 8; j++){
      unsigned short h16 = f2bf(xs[j]);
      Ah[j] = (short)h16;
      Al[j] = (short)f2bf(xs[j] - bf2f(h16));
    }
    #pragma unroll
    for (int nt = 0; nt < 8; nt++){
      const int fo = (((ks*8 + nt)*64 + l)*8);
      bf16x8 Bh = ld_frag(Wh + fo);
      bf16x8 Bl = ld_frag(Wl + fo);
      acc[nt] = __builtin_amdgcn_mfma_f32_16x16x32_bf16(Ah, Bh, acc[nt], 0,0,0);
      acc[nt] = __builtin_amdgcn_mfma_f32_16x16x32_bf16(Al, Bh, acc[nt], 0,0,0);
      acc[nt] = __builtin_amdgcn_mfma_f32_16x16x32_bf16(Ah, Bl, acc[nt], 0,0,0);
    }
  }

  #pragma unroll
  for (int nt = 0; nt < 8; nt++)
    #pragma unroll
    for (int j = 0; j < 4; j++)
      h_out[(size_t)(rowbase + g*4 + j)*128 + nt*16 + r16] = f2bf(acc[nt][j]);

  float as_v[8], ad_v[8];
  #pragma unroll
  for (int nt = 0; nt < 8; nt++){
    as_v[nt] = asrc[nt*16 + r16];
    ad_v[nt] = adst[nt*16 + r16];
  }
  float sp[4][4], dp[4][4];
  #pragma unroll
  for (int hd = 0; hd < 4; hd++)
    #pragma unroll
    for (int j = 0; j < 4; j++){
      sp[hd][j] = acc[2*hd][j]*as_v[2*hd] + acc[2*hd+1][j]*as_v[2*hd+1];
      dp[hd][j] = acc[2*hd][j]*ad_v[2*hd] + acc[2*hd+1][j]*ad_v[2*hd+1];
    }
  #pragma unroll
  for (int o = 1; o < 16; o <<= 1)
    #pragma unroll
    for (int hd = 0; hd < 4; hd++)
      #pragma unroll
      for (int j = 0; j < 4; j++){
        sp[hd][j] += __shfl_xor(sp[hd][j], o);
        dp[hd][j] += __shfl_xor(dp[hd][j], o);
      }
  #pragma unroll
  for (int hd = 0; hd < 4; hd++){
    if (r16 == hd)
      #pragma unroll
      for (int j = 0; j < 4; j++)
        s_out[(rowbase + g*4 + j)*4 + hd] = sp[hd][j];
    if (r16 == 8 + hd)
      #pragma unroll
      for (int j = 0; j < 4; j++)
        d_out[(rowbase + g*4 + j)*4 + hd] = dp[hd][j];
  }
}

// -------------------------------------------- GAT aggregation v3: (edge x head) phase-1,
// 4-edge/uint4 phase-2. wave per dst node.
template<bool FUSE_CLS>
__global__ __launch_bounds__(256) void gat_aggregate(
    const float* __restrict__ sarr, const float* __restrict__ darr,
    const unsigned short* __restrict__ hb,
    const int2* __restrict__ srcattr, const int* __restrict__ offsets,
    const float* __restrict__ We, const float* __restrict__ be,
    const float* __restrict__ aedge, const float* __restrict__ Wg, const float* __restrict__ bgp,
    float* __restrict__ xout,
    const float* __restrict__ cw1, const float* __restrict__ cb1,
    const float* __restrict__ cw2, const float* __restrict__ cb2,
    float* __restrict__ out)
{
  __shared__ int2 ew[4][2][4][64];   // [wave][buf][head][edge] = {w_bits, src}
  __shared__ float xrow[4][128];
  __shared__ float hrow[4][64];
  const int l   = threadIdx.x & 63;
  const int w   = threadIdx.x >> 6;
  const int v   = blockIdx.x*4 + w;
  const int hd  = l >> 4;        // phase-1 head / phase-2 edge offset
  const int e16 = l & 15;        // phase-1 edge slot / phase-2 channel block
  const int c0  = 2*l;
  const int c8  = e16 * 8;       // phase-2 channel base (8 ch/lane)
  const int hd2 = e16 >> 2;      // head of this lane's channel block

  // own-head logit projections: p0 = We[0,:]·aedge[hd], p1 = We[1,:]·aedge[hd], pc = be·aedge[hd]
  float ae0 = aedge[hd*32 + (c0 & 31)];
  float ae1 = aedge[hd*32 + ((c0+1) & 31)];
  float p0 = We[c0]*ae0 + We[c0+1]*ae1;
  float p1 = We[128+c0]*ae0 + We[128+c0+1]*ae1;
  float pc = be[c0]*ae0 + be[c0+1]*ae1;
  #pragma unroll
  for (int o = 1; o < 16; o <<= 1){ p0 += __shfl_xor(p0,o); p1 += __shfl_xor(p1,o); pc += __shfl_xor(pc,o); }
  const float wg0 = Wg[0], wg1 = Wg[1], bgv = bgp[0];

  const int off = offsets[v];
  const int deg = offsets[v+1] - off;
  const float dh = darr[(size_t)v*4 + hd];

  float dn = 0.f, Sm = 0.f, S0 = 0.f, S1 = 0.f;
  float acc[8] = {0.f,0.f,0.f,0.f,0.f,0.f,0.f,0.f};

  int pb = 0;
  for (int base = 0; base < deg; base += 64, pb ^= 1){
    // phase 1: 4 sub-iters x (16 edges x 4 heads)
    #pragma unroll
    for (int s = 0; s < 4; s++){
      int ii = base + s*16 + e16;
      float wv = 0.f; int sj = 0;
      if (ii < deg){
        int2 sa = srcattr[off + ii];
        sj = sa.x;
        unsigned pa = (unsigned)sa.y;
        float a0 = __uint_as_float(pa << 16);
        float a1 = __uint_as_float(pa & 0xffff0000u);
        float sv = sarr[(size_t)sj*4 + hd];
        float e  = __expf(leaky02(sv + dh + a0*p0 + a1*p1 + pc));
        float gt = 1.f/(1.f + __expf(-(a0*wg0 + a1*wg1 + bgv)));
        dn += e; wv = gt*e;
        Sm += wv; S0 += wv*a0; S1 += wv*a1;
      }
      ew[w][pb][hd][s*16 + e16] = make_int2(__float_as_int(wv), sj);
    }
    asm volatile("s_waitcnt lgkmcnt(0)" ::: "memory");
    // phase 2: 4 edges/iter, 16 lanes x uint4 = one full h-row per edge
    const int2* eb = &ew[w][pb][hd2][0];
    int lim = deg - base; if (lim > 64) lim = 64;
    #pragma unroll 4
    for (int j = 0; j < lim; j += 4){
      int2 ws2 = eb[j + hd];
      float wv = __int_as_float(ws2.x);
      uint4 hv = *(const uint4*)(hb + (((size_t)ws2.y) << 7) + c8);
      acc[0] = fmaf(__uint_as_float(hv.x << 16),         wv, acc[0]);
      acc[1] = fmaf(__uint_as_float(hv.x & 0xffff0000u), wv, acc[1]);
      acc[2] = fmaf(__uint_as_float(hv.y << 16),         wv, acc[2]);
      acc[3] = fmaf(__uint_as_float(hv.y & 0xffff0000u), wv, acc[3]);
      acc[4] = fmaf(__uint_as_float(hv.z << 16),         wv, acc[4]);
      acc[5] = fmaf(__uint_as_float(hv.z & 0xffff0000u), wv, acc[5]);
      acc[6] = fmaf(__uint_as_float(hv.w << 16),         wv, acc[6]);
      acc[7] = fmaf(__uint_as_float(hv.w & 0xffff0000u), wv, acc[7]);
    }
  }

  // combine phase-2 edge-quarters (lanes l, l^16, l^32 hold same channels)
  #pragma unroll
  for (int k = 0; k < 8; k++){
    acc[k] += __shfl_xor(acc[k], 16);
    acc[k] += __shfl_xor(acc[k], 32);
  }
  // phase-1 reduction within 16-lane head groups
  #pragma unroll
  for (int o = 1; o < 16; o <<= 1){
    dn += __shfl_xor(dn, o); Sm += __shfl_xor(Sm, o);
    S0 += __shfl_xor(S0, o); S1 += __shfl_xor(S1, o);
  }
  // fetch this lane's channel-head scalars
  int srcl = hd2*16 + e16;
  float den = __shfl(dn, srcl);
  float Smh = __shfl(Sm, srcl);
  float S0h = __shfl(S0, srcl);
  float S1h = __shfl(S1, srcl);
  float rden = 1.f/(den + 1e-16f);

  float o8[8];
  #pragma unroll
  for (int k = 0; k < 8; k++){
    float x = (acc[k] + be[c8+k]*Smh + We[c8+k]*S0h + We[128+c8+k]*S1h) * rden;
    o8[k] = x > 0.f ? x : (__expf(x) - 1.f);
  }

  if constexpr (!FUSE_CLS){
    if (l < 16){
      float4 lo = make_float4(o8[0], o8[1], o8[2], o8[3]);
      float4 hi = make_float4(o8[4], o8[5], o8[6], o8[7]);
      *(float4*)(xout + (size_t)v*128 + c8)     = lo;
      *(float4*)(xout + (size_t)v*128 + c8 + 4) = hi;
    }
  } else {
    if (l < 16){
      *(float4*)&xrow[w][c8]     = make_float4(o8[0], o8[1], o8[2], o8[3]);
      *(float4*)&xrow[w][c8 + 4] = make_float4(o8[4], o8[5], o8[6], o8[7]);
    }
    asm volatile("s_waitcnt lgkmcnt(0)" ::: "memory");
    float a = cb1[l];
    #pragma unroll 8
    for (int k = 0; k < 128; k++) a = fmaf(xrow[w][k], cw1[k*64 + l], a);
    hrow[w][l] = a > 0.f ? a : 0.f;
    asm volatile("s_waitcnt lgkmcnt(0)" ::: "memory");
    if (l < 25){
      float o = cb2[l];
      #pragma unroll 8
      for (int k = 0; k < 64; k++) o = fmaf(hrow[w][k], cw2[k*25 + l], o);
      out[(size_t)v*25 + l] = o;
    }
  }
}

// ---------------------------------------------------------------- launch
extern "C" void kernel_launch(void* const* d_in, const int* in_sizes, int n_in,
                              void* d_out, int out_size, void* d_ws, size_t ws_size,
                              hipStream_t stream)
{
  (void)in_sizes; (void)n_in; (void)out_size; (void)ws_size;
  const float* x_vis   = (const float*)d_in[0];
  const float* x_sym   = (const float*)d_in[1];
  const int*   ei      = (const int*)  d_in[2];
  const float* ea      = (const float*)d_in[3];
  const float* c1w     = (const float*)d_in[4];
  const float* c1b     = (const float*)d_in[5];
  const float* c2w     = (const float*)d_in[6];
  const float* c2b     = (const float*)d_in[7];
  const float* fcw     = (const float*)d_in[8];
  const float* fcb     = (const float*)d_in[9];
  const float* s1w     = (const float*)d_in[10];
  const float* s1b     = (const float*)d_in[11];
  const float* s2w     = (const float*)d_in[12];
  const float* s2b     = (const float*)d_in[13];
  const float* g1W     = (const float*)d_in[14];
  const float* g1b     = (const float*)d_in[15];
  const float* g1We    = (const float*)d_in[16];
  const float* g1be    = (const float*)d_in[17];
  const float* g1asrc  = (const float*)d_in[18];
  const float* g1adst  = (const float*)d_in[19];
  const float* g1aedge = (const float*)d_in[20];
  const float* g1Wg    = (const float*)d_in[21];
  const float* g1bg    = (const float*)d_in[22];
  const float* g2W     = (const float*)d_in[23];
  const float* g2b     = (const float*)d_in[24];
  const float* g2We    = (const float*)d_in[25];
  const float* g2be    = (const float*)d_in[26];
  const float* g2asrc  = (const float*)d_in[27];
  const float* g2adst  = (const float*)d_in[28];
  const float* g2aedge = (const float*)d_in[29];
  const float* g2Wg    = (const float*)d_in[30];
  const float* g2bg    = (const float*)d_in[31];
  const float* cw1     = (const float*)d_in[32];
  const float* cb1     = (const float*)d_in[33];
  const float* cw2     = (const float*)d_in[34];
  const float* cb2     = (const float*)d_in[35];

  size_t off = 0;
  auto take = [&](size_t bytes) -> void* {
    off = (off + 255) & ~(size_t)255;
    void* p = (char*)d_ws + off;
    off += bytes;
    return p;
  };
  int*   cnt     = (int*)  take((size_t)NND*4);
  int*   offs    = (int*)  take((size_t)(NND+1)*4);
  int*   bsum    = (int*)  take((size_t)SCAN_B*4);
  int*   bbase   = (int*)  take((size_t)SCAN_B*4);
  int2*  srcattr = (int2*) take((size_t)NE*8);
  float* x128    = (float*)take((size_t)NND*128*4);
  unsigned short* hb = (unsigned short*)take((size_t)NND*128*2);
  float* sbuf    = (float*)take((size_t)NND*4*4);
  float* dbuf    = (float*)take((size_t)NND*4*4);
  float* x2      = (float*)take((size_t)NND*128*4);
  unsigned short* W1t = (unsigned short*)take(3072*2);
  unsigned short* W2t = (unsigned short*)take(18432*2);
  float* Weff    = (float*)take(16384*4);
  float* beff    = (float*)take(128*4);
  unsigned short* G1h = (unsigned short*)take(16384*2);
  unsigned short* G1l = (unsigned short*)take(16384*2);
  unsigned short* G2h = (unsigned short*)take(16384*2);
  unsigned short* G2l = (unsigned short*)take(16384*2);

  // weight pre-transforms
  prep_weights<<<2, 256, 0, stream>>>(c1w, c2w, W1t, W2t);
  prep_fold<<<64, 256, 0, stream>>>(fcw, fcb, g1W, g1b, Weff, beff);
  prep_gemm<<<64, 256, 0, stream>>>(Weff, 16384, G1h, G1l);
  prep_gemm<<<64, 256, 0, stream>>>(g2W, 16384, G2h, G2l);

  // CSR build (graph identical for both GAT layers)
  hipMemsetAsync(cnt, 0, (size_t)NND*4, stream);
  hist_kernel<<<(NE+255)/256, 256, 0, stream>>>(ei, cnt);
  scan1_kernel<<<SCAN_B, 256, 0, stream>>>(cnt, offs, bsum);
  scan2_kernel<<<1, 256, 0, stream>>>(bsum, bbase);
  scan3_kernel<<<SCAN_B, 256, 0, stream>>>(offs, bbase);
  scatter_kernel<<<(NE+255)/256, 256, 0, stream>>>(ei, ea, offs, cnt, srcattr);

  // encoders (MFMA, 4 nodes/block, W2 in LDS)
  uv_mfma_kernel<<<NND/4, 256, 0, stream>>>(x_vis, x_sym, W1t, W2t, c1b, c2b,
                                            s1w, s1b, s2w, s2b, x128);
  // GAT layer 1 (uvfc folded into Weff)
  node_gemm<128><<<(NND/16 + 3)/4, 256, 0, stream>>>(x128, G1h, G1l, beff, g1asrc, g1adst,
                                                     hb, sbuf, dbuf);
  gat_aggregate<false><<<NND/4, 256, 0, stream>>>(sbuf, dbuf, hb, srcattr, offs,
                                                  g1We, g1be, g1aedge, g1Wg, g1bg, x2,
                                                  nullptr, nullptr, nullptr, nullptr, nullptr);
  // GAT layer 2 + fused classifier
  node_gemm<128><<<(NND/16 + 3)/4, 256, 0, stream>>>(x2, G2h, G2l, g2b, g2asrc, g2adst,
                                                     hb, sbuf, dbuf);
  gat_aggregate<true><<<NND/4, 256, 0, stream>>>(sbuf, dbuf, hb, srcattr, offs,
                                                 g2We, g2be, g2aedge, g2Wg, g2bg, nullptr,
                                                 cw1, cb1, cw2, cb2, (float*)d_out);
}

// Round 8
// 590.384 us; speedup vs baseline: 4.9364x; 1.0195x over previous
//
#include <hip/hip_runtime.h>

#define NND 50000
#define NE  1600000
#define SCAN_B 196   // ceil(NND/256)

typedef __attribute__((ext_vector_type(8))) short bf16x8;
typedef __attribute__((ext_vector_type(4))) float f32x4;

__device__ __forceinline__ float leaky02(float x){ return x > 0.f ? x : 0.2f*x; }
__device__ __forceinline__ unsigned short f2bf(float f){
  unsigned u = __float_as_uint(f);
  u = (u + 0x7fffu + ((u >> 16) & 1u)) >> 16;
  return (unsigned short)u;
}
__device__ __forceinline__ float bf2f(unsigned short h){
  return __uint_as_float(((unsigned)h) << 16);
}
__device__ __forceinline__ bf16x8 ld_frag(const unsigned short* p){
  return __builtin_bit_cast(bf16x8, *(const uint4*)p);
}

// ---------------------------------------------------------------- CSR build
__global__ __launch_bounds__(256) void hist_kernel(const int* __restrict__ ei,
                                                   int* __restrict__ cnt){
  int e = blockIdx.x*256 + threadIdx.x;
  if (e < NE) atomicAdd(&cnt[ei[NE + e]], 1);
}

__global__ __launch_bounds__(256) void scan1_kernel(const int* __restrict__ cnt,
                                                    int* __restrict__ offsets,
                                                    int* __restrict__ bsum){
  __shared__ int wsum[4];
  int t = threadIdx.x, lane = t & 63, wv = t >> 6;
  int i = blockIdx.x*256 + t;
  int x = (i < NND) ? cnt[i] : 0;
  int s = x;
  #pragma unroll
  for (int o = 1; o < 64; o <<= 1){ int y = __shfl_up(s, o); if (lane >= o) s += y; }
  if (lane == 63) wsum[wv] = s;
  __syncthreads();
  if (t == 0){
    int a = wsum[0], b = wsum[1], c = wsum[2];
    wsum[0] = 0; wsum[1] = a; wsum[2] = a + b; wsum[3] = a + b + c;
  }
  __syncthreads();
  s += wsum[wv];
  if (i < NND) offsets[i+1] = s;
  if (t == 255) bsum[blockIdx.x] = s;
}

__global__ __launch_bounds__(256) void scan2_kernel(const int* __restrict__ bsum,
                                                    int* __restrict__ bbase){
  __shared__ int wsum[4];
  int t = threadIdx.x, lane = t & 63, wv = t >> 6;
  int x = (t < SCAN_B) ? bsum[t] : 0;
  int s = x;
  #pragma unroll
  for (int o = 1; o < 64; o <<= 1){ int y = __shfl_up(s, o); if (lane >= o) s += y; }
  if (lane == 63) wsum[wv] = s;
  __syncthreads();
  if (t == 0){
    int a = wsum[0], b = wsum[1], c = wsum[2];
    wsum[0] = 0; wsum[1] = a; wsum[2] = a + b; wsum[3] = a + b + c;
  }
  __syncthreads();
  s += wsum[wv];
  if (t < SCAN_B) bbase[t] = s - x;   // exclusive
}

__global__ __launch_bounds__(256) void scan3_kernel(int* __restrict__ offsets,
                                                    const int* __restrict__ bbase){
  int i = blockIdx.x*256 + threadIdx.x;
  int add = bbase[blockIdx.x];
  if (i < NND) offsets[i+1] += add;
  if (i == 0) offsets[0] = 0;
}

// srcattr packed: {src, bf16(a0) | bf16(a1)<<16}; cnt consumed via atomicSub
__global__ __launch_bounds__(256) void scatter_kernel(const int* __restrict__ ei,
                                                      const float* __restrict__ ea,
                                                      const int* __restrict__ offsets,
                                                      int* __restrict__ cnt,
                                                      int2* __restrict__ srcattr){
  int e = blockIdx.x*256 + threadIdx.x;
  if (e < NE){
    int dstn = ei[NE + e];
    int pos  = atomicSub(&cnt[dstn], 1) - 1;
    float2 a = *(const float2*)(ea + 2*e);
    unsigned pa = (unsigned)f2bf(a.x) | ((unsigned)f2bf(a.y) << 16);
    srcattr[offsets[dstn] + pos] = make_int2(ei[e], (int)pa);
  }
}

// -------------------------------------------------- conv weight pre-transform (bf16)
__global__ __launch_bounds__(256) void prep_weights(
    const float* __restrict__ w1, const float* __restrict__ w2,
    unsigned short* __restrict__ W1t, unsigned short* __restrict__ W2t)
{
  int t = threadIdx.x;
  if (blockIdx.x == 0){
    for (int i = t; i < 3072; i += 256){
      int j = i & 7, oc = (i >> 3) & 31, g = (i >> 8) & 3, m = i >> 10;
      int tap = m*4 + g;
      float v = (tap < 9 && j < 6) ? w1[oc*54 + j*9 + tap] : 0.f;
      W1t[i] = f2bf(v);
    }
  } else {
    for (int i = t; i < 18432; i += 256){
      int j = i & 7, oc = (i >> 3) & 63, g = (i >> 9) & 3, tap = i >> 11;
      int ic = g*8 + j;
      W2t[i] = f2bf(w2[oc*288 + ic*9 + tap]);
    }
  }
}

// -------------------------------------------------- fold uvfc into layer-1 W: Weff[128][128]
__global__ __launch_bounds__(256) void prep_fold(
    const float* __restrict__ fcw, const float* __restrict__ fcb,
    const float* __restrict__ g1W, const float* __restrict__ g1b,
    float* __restrict__ Weff, float* __restrict__ beff)
{
  int idx = blockIdx.x*256 + threadIdx.x;
  if (idx < 16384){
    int r = idx >> 7, c = idx & 127;
    float acc;
    if (r < 64){
      acc = 0.f;
      #pragma unroll 4
      for (int m = 0; m < 128; m++) acc += fcw[r*128 + m] * g1W[m*128 + c];
    } else {
      acc = g1W[(64 + r)*128 + c];
    }
    Weff[idx] = acc;
  }
  if (blockIdx.x == 0 && threadIdx.x < 128){
    int c = threadIdx.x;
    float acc = g1b[c];
    #pragma unroll 4
    for (int m = 0; m < 128; m++) acc += fcb[m] * g1W[m*128 + c];
    beff[c] = acc;
  }
}

// -------------------------------------------------- GEMM weight pre-transform: frag-linear hi/lo
__global__ __launch_bounds__(256) void prep_gemm(
    const float* __restrict__ W, int total,
    unsigned short* __restrict__ Wh, unsigned short* __restrict__ Wl)
{
  for (int i = blockIdx.x*256 + threadIdx.x; i < total; i += gridDim.x*256){
    int j = i & 7, lx = (i >> 3) & 63, nt = (i >> 9) & 7, ks = i >> 12;
    int k = ks*32 + (lx >> 4)*8 + j;
    int col = nt*16 + (lx & 15);
    float v = W[k*128 + col];
    unsigned short h16 = f2bf(v);
    Wh[i] = h16;
    Wl[i] = f2bf(v - bf2f(h16));
  }
}

// -------------------------------------------- UV + sym encoder, MFMA, conv2 B in REGISTERS
// 4 waves/block, 1 node/wave, no barriers. All LDS wave-private.
__global__ __launch_bounds__(256, 2) void uv_mfma_kernel(
    const float* __restrict__ x_vis, const float* __restrict__ x_sym,
    const unsigned short* __restrict__ W1t, const unsigned short* __restrict__ W2t,
    const float* __restrict__ b1, const float* __restrict__ b2,
    const float* __restrict__ s1w, const float* __restrict__ s1b,
    const float* __restrict__ s2w, const float* __restrict__ s2b,
    float* __restrict__ x128)
{
  __shared__ __align__(16) unsigned short xic[4*800];    // per-node [10][10][8ic] bf16
  __shared__ __align__(16) unsigned short c1p[4*4000];   // per-node [10][10][40] bf16
  __shared__ float symh[4][64];

  const int t = threadIdx.x;
  const int w = t >> 6, l = t & 63;
  const int g = l >> 4, r16 = l & 15;
  const int xb = r16 & 7, yb = r16 >> 3;
  const int n = blockIdx.x*4 + w;

  // zero this wave's node buffers (borders must be 0)
  uint4 z4 = {0,0,0,0};
  {
    uint4* zx = (uint4*)(xic + w*800);
    #pragma unroll
    for (int i = 0; i < 2; i++) if (l + i*64 < 100) zx[l + i*64] = z4;
    uint4* zc = (uint4*)(c1p + w*4000);
    #pragma unroll
    for (int i = 0; i < 8; i++) if (l + i*64 < 500) zc[l + i*64] = z4;
  }

  // stage x_vis -> xic interior (bf16), wave-private
  {
    const float* xv = x_vis + (size_t)n*384;
    #pragma unroll
    for (int it = 0; it < 6; it++){
      int i = l + it*64;
      int ic = i >> 6, yx = i & 63, y = yx >> 3, x = yx & 7;
      xic[w*800 + ((y+1)*10 + (x+1))*8 + ic] = f2bf(xv[i]);
    }
  }

  // conv1 B fragments from global (6 KB, L2-hot)
  uint4 B1[3][2];
  #pragma unroll
  for (int m = 0; m < 3; m++)
    #pragma unroll
    for (int nt = 0; nt < 2; nt++)
      B1[m][nt] = *(const uint4*)(W1t + m*1024 + g*256 + (nt*16 + r16)*8);

  // ---- conv1: 3 MFMAs, 4 taps packed per MFMA into K=32
  const int t0 = g;     const int dy0 = t0/3, dx0 = t0%3;
  const int t1 = 4 + g; const int dy1 = t1/3, dx1 = t1%3;
  const int dy2 = 2, dx2 = 2;

  const float b1a = b1[r16], b1c = b1[16 + r16];
  f32x4 acc1[4][2];
  #pragma unroll
  for (int mt = 0; mt < 4; mt++){
    acc1[mt][0] = (f32x4){b1a, b1a, b1a, b1a};
    acc1[mt][1] = (f32x4){b1c, b1c, b1c, b1c};
  }
  const unsigned short* xn = xic + w*800;
  #pragma unroll
  for (int mt = 0; mt < 4; mt++){
    const int Y = mt*2 + yb;
    bf16x8 A0 = ld_frag(xn + (Y+dy0)*80 + (xb+dx0)*8);
    bf16x8 A1 = ld_frag(xn + (Y+dy1)*80 + (xb+dx1)*8);
    bf16x8 A2 = ld_frag(xn + (Y+dy2)*80 + (xb+dx2)*8);
    #pragma unroll
    for (int nt = 0; nt < 2; nt++){
      acc1[mt][nt] = __builtin_amdgcn_mfma_f32_16x16x32_bf16(A0, __builtin_bit_cast(bf16x8, B1[0][nt]), acc1[mt][nt], 0,0,0);
      acc1[mt][nt] = __builtin_amdgcn_mfma_f32_16x16x32_bf16(A1, __builtin_bit_cast(bf16x8, B1[1][nt]), acc1[mt][nt], 0,0,0);
      acc1[mt][nt] = __builtin_amdgcn_mfma_f32_16x16x32_bf16(A2, __builtin_bit_cast(bf16x8, B1[2][nt]), acc1[mt][nt], 0,0,0);
    }
  }
  unsigned short* cn = c1p + w*4000;
  #pragma unroll
  for (int mt = 0; mt < 4; mt++)
    #pragma unroll
    for (int nt = 0; nt < 2; nt++)
      #pragma unroll
      for (int j = 0; j < 4; j++){
        int rowl = g*4 + j;
        int y = mt*2 + (rowl >> 3), x = rowl & 7;
        float v = acc1[mt][nt][j]; v = v > 0.f ? v : 0.f;
        cn[((y+1)*10 + (x+1))*40 + nt*16 + r16] = f2bf(v);
      }

  // ---- conv2 B fragments -> registers (36 uint4 = 144 VGPR), L2-broadcast loads.
  // Issued after conv1 so acc1 registers are free; all 36 loads pipeline in vmem.
  uint4 B2[9][4];
  #pragma unroll
  for (int tap = 0; tap < 9; tap++)
    #pragma unroll
    for (int nt = 0; nt < 4; nt++)
      B2[tap][nt] = *(const uint4*)(W2t + tap*2048 + g*512 + (nt*16 + r16)*8);

  // ---- conv2: tap-loop implicit GEMM, A from LDS, B from registers
  float b2v[4];
  #pragma unroll
  for (int nt = 0; nt < 4; nt++) b2v[nt] = b2[nt*16 + r16];
  f32x4 acc2[4][4];
  #pragma unroll
  for (int mt = 0; mt < 4; mt++)
    #pragma unroll
    for (int nt = 0; nt < 4; nt++)
      acc2[mt][nt] = (f32x4){b2v[nt], b2v[nt], b2v[nt], b2v[nt]};

  #pragma unroll
  for (int tap = 0; tap < 9; tap++){
    const int dy = tap/3, dx = tap%3;
    uint4 Av[4];
    #pragma unroll
    for (int mt = 0; mt < 4; mt++){
      int Y = mt*2 + yb + dy, X = xb + dx;
      Av[mt] = *(const uint4*)(cn + (Y*10 + X)*40 + g*8);
    }
    #pragma unroll
    for (int mt = 0; mt < 4; mt++)
      #pragma unroll
      for (int nt = 0; nt < 4; nt++)
        acc2[mt][nt] = __builtin_amdgcn_mfma_f32_16x16x32_bf16(
            __builtin_bit_cast(bf16x8, Av[mt]), __builtin_bit_cast(bf16x8, B2[tap][nt]), acc2[mt][nt], 0,0,0);
  }

  // relu + mean pool over 64 px -> x128[0:64]
  float* xo = x128 + (size_t)n*128;
  #pragma unroll
  for (int nt = 0; nt < 4; nt++){
    float s = 0.f;
    #pragma unroll
    for (int mt = 0; mt < 4; mt++)
      #pragma unroll
      for (int j = 0; j < 4; j++){
        float v = acc2[mt][nt][j]; s += (v > 0.f ? v : 0.f);
      }
    s += __shfl_xor(s, 16);
    s += __shfl_xor(s, 32);
    if (l < 16) xo[nt*16 + l] = s * (1.f/64.f);
  }
  // sym layer 1 (wave-private)
  {
    const float* xs = x_sym + (size_t)n*3;
    float a = s1b[l] + xs[0]*s1w[l] + xs[1]*s1w[64+l] + xs[2]*s1w[128+l];
    symh[w][l] = a > 0.f ? a : 0.f;
  }
  // sym layer 2 -> x128[64:128]
  {
    float a = s2b[l];
    #pragma unroll 8
    for (int k = 0; k < 64; k++) a = fmaf(symh[w][k], s2w[k*64 + l], a);
    xo[64 + l] = a > 0.f ? a : 0.f;
  }
}

// ---------------- node GEMM: h = x@W + b via split-bf16 MFMA; fused s,d dots; h stored bf16.
template<int K>
__global__ __launch_bounds__(256) void node_gemm(
    const float* __restrict__ xin,
    const unsigned short* __restrict__ Wh, const unsigned short* __restrict__ Wl,
    const float* __restrict__ b,
    const float* __restrict__ asrc, const float* __restrict__ adst,
    unsigned short* __restrict__ h_out, float* __restrict__ s_out, float* __restrict__ d_out)
{
  const int w = threadIdx.x >> 6, l = threadIdx.x & 63;
  const int g = l >> 4, r16 = l & 15;
  const int wid = blockIdx.x*4 + w;
  if (wid >= NND/16) return;
  const int rowbase = wid*16;

  f32x4 acc[8];
  #pragma unroll
  for (int nt = 0; nt < 8; nt++){
    float bv = b[nt*16 + r16];
    acc[nt] = (f32x4){bv, bv, bv, bv};
  }

  const float* xr = xin + (size_t)(rowbase + r16)*K + g*8;
  #pragma unroll 2
  for (int ks = 0; ks < K/32; ks++){
    float4 xa = *(const float4*)(xr + ks*32);
    float4 xb = *(const float4*)(xr + ks*32 + 4);
    float xs[8] = {xa.x,xa.y,xa.z,xa.w,xb.x,xb.y,xb.z,xb.w};
    bf16x8 Ah, Al;
    #pragma unroll
    for (int j = 0; j < 8; j++){
      unsigned short h16 = f2bf(xs[j]);
      Ah[j] = (short)h16;
      Al[j] = (short)f2bf(xs[j] - bf2f(h16));
    }
    #pragma unroll
    for (int nt = 0; nt < 8; nt++){
      const int fo = (((ks*8 + nt)*64 + l)*8);
      bf16x8 Bh = ld_frag(Wh + fo);
      bf16x8 Bl = ld_frag(Wl + fo);
      acc[nt] = __builtin_amdgcn_mfma_f32_16x16x32_bf16(Ah, Bh, acc[nt], 0,0,0);
      acc[nt] = __builtin_amdgcn_mfma_f32_16x16x32_bf16(Al, Bh, acc[nt], 0,0,0);
      acc[nt] = __builtin_amdgcn_mfma_f32_16x16x32_bf16(Ah, Bl, acc[nt], 0,0,0);
    }
  }

  #pragma unroll
  for (int nt = 0; nt < 8; nt++)
    #pragma unroll
    for (int j = 0; j < 4; j++)
      h_out[(size_t)(rowbase + g*4 + j)*128 + nt*16 + r16] = f2bf(acc[nt][j]);

  float as_v[8], ad_v[8];
  #pragma unroll
  for (int nt = 0; nt < 8; nt++){
    as_v[nt] = asrc[nt*16 + r16];
    ad_v[nt] = adst[nt*16 + r16];
  }
  float sp[4][4], dp[4][4];
  #pragma unroll
  for (int hd = 0; hd < 4; hd++)
    #pragma unroll
    for (int j = 0; j < 4; j++){
      sp[hd][j] = acc[2*hd][j]*as_v[2*hd] + acc[2*hd+1][j]*as_v[2*hd+1];
      dp[hd][j] = acc[2*hd][j]*ad_v[2*hd] + acc[2*hd+1][j]*ad_v[2*hd+1];
    }
  #pragma unroll
  for (int o = 1; o < 16; o <<= 1)
    #pragma unroll
    for (int hd = 0; hd < 4; hd++)
      #pragma unroll
      for (int j = 0; j < 4; j++){
        sp[hd][j] += __shfl_xor(sp[hd][j], o);
        dp[hd][j] += __shfl_xor(dp[hd][j], o);
      }
  #pragma unroll
  for (int hd = 0; hd < 4; hd++){
    if (r16 == hd)
      #pragma unroll
      for (int j = 0; j < 4; j++)
        s_out[(rowbase + g*4 + j)*4 + hd] = sp[hd][j];
    if (r16 == 8 + hd)
      #pragma unroll
      for (int j = 0; j < 4; j++)
        d_out[(rowbase + g*4 + j)*4 + hd] = dp[hd][j];
  }
}

// -------------------------------------------- GAT aggregation v3: (edge x head) phase-1,
// 4-edge/uint4 phase-2. wave per dst node.
template<bool FUSE_CLS>
__global__ __launch_bounds__(256) void gat_aggregate(
    const float* __restrict__ sarr, const float* __restrict__ darr,
    const unsigned short* __restrict__ hb,
    const int2* __restrict__ srcattr, const int* __restrict__ offsets,
    const float* __restrict__ We, const float* __restrict__ be,
    const float* __restrict__ aedge, const float* __restrict__ Wg, const float* __restrict__ bgp,
    float* __restrict__ xout,
    const float* __restrict__ cw1, const float* __restrict__ cb1,
    const float* __restrict__ cw2, const float* __restrict__ cb2,
    float* __restrict__ out)
{
  __shared__ int2 ew[4][2][4][64];   // [wave][buf][head][edge] = {w_bits, src}
  __shared__ float xrow[4][128];
  __shared__ float hrow[4][64];
  const int l   = threadIdx.x & 63;
  const int w   = threadIdx.x >> 6;
  const int v   = blockIdx.x*4 + w;
  const int hd  = l >> 4;        // phase-1 head / phase-2 edge offset
  const int e16 = l & 15;        // phase-1 edge slot / phase-2 channel block
  const int c0  = 2*l;
  const int c8  = e16 * 8;       // phase-2 channel base (8 ch/lane)
  const int hd2 = e16 >> 2;      // head of this lane's channel block

  float ae0 = aedge[hd*32 + (c0 & 31)];
  float ae1 = aedge[hd*32 + ((c0+1) & 31)];
  float p0 = We[c0]*ae0 + We[c0+1]*ae1;
  float p1 = We[128+c0]*ae0 + We[128+c0+1]*ae1;
  float pc = be[c0]*ae0 + be[c0+1]*ae1;
  #pragma unroll
  for (int o = 1; o < 16; o <<= 1){ p0 += __shfl_xor(p0,o); p1 += __shfl_xor(p1,o); pc += __shfl_xor(pc,o); }
  const float wg0 = Wg[0], wg1 = Wg[1], bgv = bgp[0];

  const int off = offsets[v];
  const int deg = offsets[v+1] - off;
  const float dh = darr[(size_t)v*4 + hd];

  float dn = 0.f, Sm = 0.f, S0 = 0.f, S1 = 0.f;
  float acc[8] = {0.f,0.f,0.f,0.f,0.f,0.f,0.f,0.f};

  int pb = 0;
  for (int base = 0; base < deg; base += 64, pb ^= 1){
    #pragma unroll
    for (int s = 0; s < 4; s++){
      int ii = base + s*16 + e16;
      float wv = 0.f; int sj = 0;
      if (ii < deg){
        int2 sa = srcattr[off + ii];
        sj = sa.x;
        unsigned pa = (unsigned)sa.y;
        float a0 = __uint_as_float(pa << 16);
        float a1 = __uint_as_float(pa & 0xffff0000u);
        float sv = sarr[(size_t)sj*4 + hd];
        float e  = __expf(leaky02(sv + dh + a0*p0 + a1*p1 + pc));
        float gt = 1.f/(1.f + __expf(-(a0*wg0 + a1*wg1 + bgv)));
        dn += e; wv = gt*e;
        Sm += wv; S0 += wv*a0; S1 += wv*a1;
      }
      ew[w][pb][hd][s*16 + e16] = make_int2(__float_as_int(wv), sj);
    }
    asm volatile("s_waitcnt lgkmcnt(0)" ::: "memory");
    const int2* eb = &ew[w][pb][hd2][0];
    int lim = deg - base; if (lim > 64) lim = 64;
    #pragma unroll 4
    for (int j = 0; j < lim; j += 4){
      int2 ws2 = eb[j + hd];
      float wv = __int_as_float(ws2.x);
      uint4 hv = *(const uint4*)(hb + (((size_t)ws2.y) << 7) + c8);
      acc[0] = fmaf(__uint_as_float(hv.x << 16),         wv, acc[0]);
      acc[1] = fmaf(__uint_as_float(hv.x & 0xffff0000u), wv, acc[1]);
      acc[2] = fmaf(__uint_as_float(hv.y << 16),         wv, acc[2]);
      acc[3] = fmaf(__uint_as_float(hv.y & 0xffff0000u), wv, acc[3]);
      acc[4] = fmaf(__uint_as_float(hv.z << 16),         wv, acc[4]);
      acc[5] = fmaf(__uint_as_float(hv.z & 0xffff0000u), wv, acc[5]);
      acc[6] = fmaf(__uint_as_float(hv.w << 16),         wv, acc[6]);
      acc[7] = fmaf(__uint_as_float(hv.w & 0xffff0000u), wv, acc[7]);
    }
  }

  #pragma unroll
  for (int k = 0; k < 8; k++){
    acc[k] += __shfl_xor(acc[k], 16);
    acc[k] += __shfl_xor(acc[k], 32);
  }
  #pragma unroll
  for (int o = 1; o < 16; o <<= 1){
    dn += __shfl_xor(dn, o); Sm += __shfl_xor(Sm, o);
    S0 += __shfl_xor(S0, o); S1 += __shfl_xor(S1, o);
  }
  int srcl = hd2*16 + e16;
  float den = __shfl(dn, srcl);
  float Smh = __shfl(Sm, srcl);
  float S0h = __shfl(S0, srcl);
  float S1h = __shfl(S1, srcl);
  float rden = 1.f/(den + 1e-16f);

  float o8[8];
  #pragma unroll
  for (int k = 0; k < 8; k++){
    float x = (acc[k] + be[c8+k]*Smh + We[c8+k]*S0h + We[128+c8+k]*S1h) * rden;
    o8[k] = x > 0.f ? x : (__expf(x) - 1.f);
  }

  if constexpr (!FUSE_CLS){
    if (l < 16){
      float4 lo = make_float4(o8[0], o8[1], o8[2], o8[3]);
      float4 hi = make_float4(o8[4], o8[5], o8[6], o8[7]);
      *(float4*)(xout + (size_t)v*128 + c8)     = lo;
      *(float4*)(xout + (size_t)v*128 + c8 + 4) = hi;
    }
  } else {
    if (l < 16){
      *(float4*)&xrow[w][c8]     = make_float4(o8[0], o8[1], o8[2], o8[3]);
      *(float4*)&xrow[w][c8 + 4] = make_float4(o8[4], o8[5], o8[6], o8[7]);
    }
    asm volatile("s_waitcnt lgkmcnt(0)" ::: "memory");
    float a = cb1[l];
    #pragma unroll 8
    for (int k = 0; k < 128; k++) a = fmaf(xrow[w][k], cw1[k*64 + l], a);
    hrow[w][l] = a > 0.f ? a : 0.f;
    asm volatile("s_waitcnt lgkmcnt(0)" ::: "memory");
    if (l < 25){
      float o = cb2[l];
      #pragma unroll 8
      for (int k = 0; k < 64; k++) o = fmaf(hrow[w][k], cw2[k*25 + l], o);
      out[(size_t)v*25 + l] = o;
    }
  }
}

// ---------------------------------------------------------------- launch
extern "C" void kernel_launch(void* const* d_in, const int* in_sizes, int n_in,
                              void* d_out, int out_size, void* d_ws, size_t ws_size,
                              hipStream_t stream)
{
  (void)in_sizes; (void)n_in; (void)out_size; (void)ws_size;
  const float* x_vis   = (const float*)d_in[0];
  const float* x_sym   = (const float*)d_in[1];
  const int*   ei      = (const int*)  d_in[2];
  const float* ea      = (const float*)d_in[3];
  const float* c1w     = (const float*)d_in[4];
  const float* c1b     = (const float*)d_in[5];
  const float* c2w     = (const float*)d_in[6];
  const float* c2b     = (const float*)d_in[7];
  const float* fcw     = (const float*)d_in[8];
  const float* fcb     = (const float*)d_in[9];
  const float* s1w     = (const float*)d_in[10];
  const float* s1b     = (const float*)d_in[11];
  const float* s2w     = (const float*)d_in[12];
  const float* s2b     = (const float*)d_in[13];
  const float* g1W     = (const float*)d_in[14];
  const float* g1b     = (const float*)d_in[15];
  const float* g1We    = (const float*)d_in[16];
  const float* g1be    = (const float*)d_in[17];
  const float* g1asrc  = (const float*)d_in[18];
  const float* g1adst  = (const float*)d_in[19];
  const float* g1aedge = (const float*)d_in[20];
  const float* g1Wg    = (const float*)d_in[21];
  const float* g1bg    = (const float*)d_in[22];
  const float* g2W     = (const float*)d_in[23];
  const float* g2b     = (const float*)d_in[24];
  const float* g2We    = (const float*)d_in[25];
  const float* g2be    = (const float*)d_in[26];
  const float* g2asrc  = (const float*)d_in[27];
  const float* g2adst  = (const float*)d_in[28];
  const float* g2aedge = (const float*)d_in[29];
  const float* g2Wg    = (const float*)d_in[30];
  const float* g2bg    = (const float*)d_in[31];
  const float* cw1     = (const float*)d_in[32];
  const float* cb1     = (const float*)d_in[33];
  const float* cw2     = (const float*)d_in[34];
  const float* cb2     = (const float*)d_in[35];

  size_t off = 0;
  auto take = [&](size_t bytes) -> void* {
    off = (off + 255) & ~(size_t)255;
    void* p = (char*)d_ws + off;
    off += bytes;
    return p;
  };
  int*   cnt     = (int*)  take((size_t)NND*4);
  int*   offs    = (int*)  take((size_t)(NND+1)*4);
  int*   bsum    = (int*)  take((size_t)SCAN_B*4);
  int*   bbase   = (int*)  take((size_t)SCAN_B*4);
  int2*  srcattr = (int2*) take((size_t)NE*8);
  float* x128    = (float*)take((size_t)NND*128*4);
  unsigned short* hb = (unsigned short*)take((size_t)NND*128*2);
  float* sbuf    = (float*)take((size_t)NND*4*4);
  float* dbuf    = (float*)take((size_t)NND*4*4);
  float* x2      = (float*)take((size_t)NND*128*4);
  unsigned short* W1t = (unsigned short*)take(3072*2);
  unsigned short* W2t = (unsigned short*)take(18432*2);
  float* Weff    = (float*)take(16384*4);
  float* beff    = (float*)take(128*4);
  unsigned short* G1h = (unsigned short*)take(16384*2);
  unsigned short* G1l = (unsigned short*)take(16384*2);
  unsigned short* G2h = (unsigned short*)take(16384*2);
  unsigned short* G2l = (unsigned short*)take(16384*2);

  // weight pre-transforms
  prep_weights<<<2, 256, 0, stream>>>(c1w, c2w, W1t, W2t);
  prep_fold<<<64, 256, 0, stream>>>(fcw, fcb, g1W, g1b, Weff, beff);
  prep_gemm<<<64, 256, 0, stream>>>(Weff, 16384, G1h, G1l);
  prep_gemm<<<64, 256, 0, stream>>>(g2W, 16384, G2h, G2l);

  // CSR build (graph identical for both GAT layers)
  hipMemsetAsync(cnt, 0, (size_t)NND*4, stream);
  hist_kernel<<<(NE+255)/256, 256, 0, stream>>>(ei, cnt);
  scan1_kernel<<<SCAN_B, 256, 0, stream>>>(cnt, offs, bsum);
  scan2_kernel<<<1, 256, 0, stream>>>(bsum, bbase);
  scan3_kernel<<<SCAN_B, 256, 0, stream>>>(offs, bbase);
  scatter_kernel<<<(NE+255)/256, 256, 0, stream>>>(ei, ea, offs, cnt, srcattr);

  // encoders (MFMA, 4 nodes/block, conv2 B in registers, barrier-free)
  uv_mfma_kernel<<<NND/4, 256, 0, stream>>>(x_vis, x_sym, W1t, W2t, c1b, c2b,
                                            s1w, s1b, s2w, s2b, x128);
  // GAT layer 1 (uvfc folded into Weff)
  node_gemm<128><<<(NND/16 + 3)/4, 256, 0, stream>>>(x128, G1h, G1l, beff, g1asrc, g1adst,
                                                     hb, sbuf, dbuf);
  gat_aggregate<false><<<NND/4, 256, 0, stream>>>(sbuf, dbuf, hb, srcattr, offs,
                                                  g1We, g1be, g1aedge, g1Wg, g1bg, x2,
                                                  nullptr, nullptr, nullptr, nullptr, nullptr);
  // GAT layer 2 + fused classifier
  node_gemm<128><<<(NND/16 + 3)/4, 256, 0, stream>>>(x2, G2h, G2l, g2b, g2asrc, g2adst,
                                                     hb, sbuf, dbuf);
  gat_aggregate<true><<<NND/4, 256, 0, stream>>>(sbuf, dbuf, hb, srcattr, offs,
                                                 g2We, g2be, g2aedge, g2Wg, g2bg, nullptr,
                                                 cw1, cb1, cw2, cb2, (float*)d_out);
}

// Round 9
// 579.251 us; speedup vs baseline: 5.0312x; 1.0192x over previous
//
#include <hip/hip_runtime.h>

#define NND 50000
#define NE  1600000
#define SCAN_B 196   // ceil(NND/256)

typedef __attribute__((ext_vector_type(8))) short bf16x8;
typedef __attribute__((ext_vector_type(4))) float f32x4;

__device__ __forceinline__ float leaky02(float x){ return x > 0.f ? x : 0.2f*x; }
__device__ __forceinline__ unsigned short f2bf(float f){
  unsigned u = __float_as_uint(f);
  u = (u + 0x7fffu + ((u >> 16) & 1u)) >> 16;
  return (unsigned short)u;
}
__device__ __forceinline__ float bf2f(unsigned short h){
  return __uint_as_float(((unsigned)h) << 16);
}
__device__ __forceinline__ unsigned cvt_pk_bf16(float lo, float hi){
  unsigned r;
  asm("v_cvt_pk_bf16_f32 %0, %1, %2" : "=v"(r) : "v"(lo), "v"(hi));
  return r;
}
__device__ __forceinline__ bf16x8 ld_frag(const unsigned short* p){
  return __builtin_bit_cast(bf16x8, *(const uint4*)p);
}

// ---------------------------------------------------------------- CSR build
__global__ __launch_bounds__(256) void hist_kernel(const int* __restrict__ ei,
                                                   int* __restrict__ cnt){
  int e = blockIdx.x*256 + threadIdx.x;
  if (e < NE) atomicAdd(&cnt[ei[NE + e]], 1);
}

__global__ __launch_bounds__(256) void scan1_kernel(const int* __restrict__ cnt,
                                                    int* __restrict__ offsets,
                                                    int* __restrict__ bsum){
  __shared__ int wsum[4];
  int t = threadIdx.x, lane = t & 63, wv = t >> 6;
  int i = blockIdx.x*256 + t;
  int x = (i < NND) ? cnt[i] : 0;
  int s = x;
  #pragma unroll
  for (int o = 1; o < 64; o <<= 1){ int y = __shfl_up(s, o); if (lane >= o) s += y; }
  if (lane == 63) wsum[wv] = s;
  __syncthreads();
  if (t == 0){
    int a = wsum[0], b = wsum[1], c = wsum[2];
    wsum[0] = 0; wsum[1] = a; wsum[2] = a + b; wsum[3] = a + b + c;
  }
  __syncthreads();
  s += wsum[wv];
  if (i < NND) offsets[i+1] = s;
  if (t == 255) bsum[blockIdx.x] = s;
}

// scan3 computes its own block prefix from bsum (no separate scan2 pass)
__global__ __launch_bounds__(256) void scan3_kernel(int* __restrict__ offsets,
                                                    const int* __restrict__ bsum){
  __shared__ int ws[4];
  int t = threadIdx.x, lane = t & 63, wv = t >> 6;
  int bid = blockIdx.x;
  int x = (t < bid) ? bsum[t] : 0;       // bid <= 195 < 256
  #pragma unroll
  for (int o = 1; o < 64; o <<= 1) x += __shfl_xor(x, o);
  if (lane == 0) ws[wv] = x;
  __syncthreads();
  int add = ws[0] + ws[1] + ws[2] + ws[3];
  int i = bid*256 + t;
  if (i < NND) offsets[i+1] += add;
  if (i == 0) offsets[0] = 0;
}

// srcattr packed: {src, bf16(a0) | bf16(a1)<<16}; cnt consumed via atomicSub
__global__ __launch_bounds__(256) void scatter_kernel(const int* __restrict__ ei,
                                                      const float* __restrict__ ea,
                                                      const int* __restrict__ offsets,
                                                      int* __restrict__ cnt,
                                                      int2* __restrict__ srcattr){
  int e = blockIdx.x*256 + threadIdx.x;
  if (e < NE){
    int dstn = ei[NE + e];
    int pos  = atomicSub(&cnt[dstn], 1) - 1;
    float2 a = *(const float2*)(ea + 2*e);
    unsigned pa = (unsigned)f2bf(a.x) | ((unsigned)f2bf(a.y) << 16);
    srcattr[offsets[dstn] + pos] = make_int2(ei[e], (int)pa);
  }
}

// ------------------------------ merged prep A: conv weights (bf16) + uvfc fold into Weff
__global__ __launch_bounds__(256) void prep_wf(
    const float* __restrict__ w1, const float* __restrict__ w2,
    unsigned short* __restrict__ W1t, unsigned short* __restrict__ W2t,
    const float* __restrict__ fcw, const float* __restrict__ fcb,
    const float* __restrict__ g1W, const float* __restrict__ g1b,
    float* __restrict__ Weff, float* __restrict__ beff)
{
  int b = blockIdx.x, t = threadIdx.x;
  if (b == 0){
    for (int i = t; i < 3072; i += 256){
      int j = i & 7, oc = (i >> 3) & 31, g = (i >> 8) & 3, m = i >> 10;
      int tap = m*4 + g;
      float v = (tap < 9 && j < 6) ? w1[oc*54 + j*9 + tap] : 0.f;
      W1t[i] = f2bf(v);
    }
  } else if (b == 1){
    for (int i = t; i < 18432; i += 256){
      int j = i & 7, oc = (i >> 3) & 63, g = (i >> 9) & 3, tap = i >> 11;
      int ic = g*8 + j;
      W2t[i] = f2bf(w2[oc*288 + ic*9 + tap]);
    }
  } else {
    int idx = (b - 2)*256 + t;
    int r = idx >> 7, c = idx & 127;
    float acc;
    if (r < 64){
      acc = 0.f;
      #pragma unroll 4
      for (int m = 0; m < 128; m++) acc += fcw[r*128 + m] * g1W[m*128 + c];
    } else {
      acc = g1W[(64 + r)*128 + c];
    }
    Weff[idx] = acc;
    if (b == 2 && t < 128){
      float bacc = g1b[t];
      #pragma unroll 4
      for (int m = 0; m < 128; m++) bacc = fmaf(fcb[m], g1W[m*128 + t], bacc);
      beff[t] = bacc;
    }
  }
}

// ------------------------------ merged prep B: frag-linear hi/lo for BOTH gemm weights
__global__ __launch_bounds__(256) void prep_gemm2(
    const float* __restrict__ WA, const float* __restrict__ WB,
    unsigned short* __restrict__ G1h, unsigned short* __restrict__ G1l,
    unsigned short* __restrict__ G2h, unsigned short* __restrict__ G2l)
{
  int b = blockIdx.x;
  const float* W = (b < 64) ? WA : WB;
  unsigned short* Wh = (b < 64) ? G1h : G2h;
  unsigned short* Wl = (b < 64) ? G1l : G2l;
  int i = (b & 63)*256 + threadIdx.x;   // 64*256 = 16384 = total
  int j = i & 7, lx = (i >> 3) & 63, nt = (i >> 9) & 7, ks = i >> 12;
  int k = ks*32 + (lx >> 4)*8 + j;
  int col = nt*16 + (lx & 15);
  float v = W[k*128 + col];
  unsigned short h16 = f2bf(v);
  Wh[i] = h16;
  Wl[i] = f2bf(v - bf2f(h16));
}

// -------------------------------------------- UV + sym encoder, MFMA, barrier-free
__global__ __launch_bounds__(256, 2) void uv_mfma_kernel(
    const float* __restrict__ x_vis, const float* __restrict__ x_sym,
    const unsigned short* __restrict__ W1t, const unsigned short* __restrict__ W2t,
    const float* __restrict__ b1, const float* __restrict__ b2,
    const float* __restrict__ s1w, const float* __restrict__ s1b,
    const float* __restrict__ s2w, const float* __restrict__ s2b,
    float* __restrict__ x128)
{
  __shared__ __align__(16) unsigned short xic[4*800];    // per-node [10][10][8ic] bf16
  __shared__ __align__(16) unsigned short c1p[4*4000];   // per-node [10][10][40] bf16
  __shared__ float symh[4][64];

  const int t = threadIdx.x;
  const int w = t >> 6, l = t & 63;
  const int g = l >> 4, r16 = l & 15;
  const int xb = r16 & 7, yb = r16 >> 3;
  const int n = blockIdx.x*4 + w;

  // border-only zeroing (36 border px per 10x10; only read-as-zero cells)
  uint4 z4 = {0,0,0,0};
  if (l < 36){
    int y, x;
    if (l < 10){ y = 0; x = l; }
    else if (l < 20){ y = 9; x = l - 10; }
    else if (l < 28){ y = l - 19; x = 0; }
    else { y = l - 27; x = 9; }
    *(uint4*)(xic + w*800 + (y*10 + x)*8) = z4;
    uint4* cp = (uint4*)(c1p + w*4000 + (y*10 + x)*40);
    cp[0] = z4; cp[1] = z4; cp[2] = z4; cp[3] = z4;   // ch 0..31
  }

  // stage x_vis -> xic interior: lane = pixel, 1 ds_write_b128 (ic6,7 = 0)
  {
    const float* xv = x_vis + (size_t)n*384;
    int y = l >> 3, x = l & 7;
    float v0 = xv[l], v1 = xv[64+l], v2 = xv[128+l];
    float v3 = xv[192+l], v4 = xv[256+l], v5 = xv[320+l];
    uint4 pk;
    pk.x = cvt_pk_bf16(v0, v1);
    pk.y = cvt_pk_bf16(v2, v3);
    pk.z = cvt_pk_bf16(v4, v5);
    pk.w = 0u;
    *(uint4*)(xic + w*800 + ((y+1)*10 + (x+1))*8) = pk;
  }
  asm volatile("" ::: "memory");   // keep staging writes before conv1 reads

  // conv1 B fragments from global (6 KB, L2-hot)
  uint4 B1[3][2];
  #pragma unroll
  for (int m = 0; m < 3; m++)
    #pragma unroll
    for (int nt = 0; nt < 2; nt++)
      B1[m][nt] = *(const uint4*)(W1t + m*1024 + g*256 + (nt*16 + r16)*8);

  // ---- conv1: 3 MFMAs, 4 taps packed per MFMA into K=32
  const int t0 = g;     const int dy0 = t0/3, dx0 = t0%3;
  const int t1 = 4 + g; const int dy1 = t1/3, dx1 = t1%3;
  const int dy2 = 2, dx2 = 2;

  const float b1a = b1[r16], b1c = b1[16 + r16];
  f32x4 acc1[4][2];
  #pragma unroll
  for (int mt = 0; mt < 4; mt++){
    acc1[mt][0] = (f32x4){b1a, b1a, b1a, b1a};
    acc1[mt][1] = (f32x4){b1c, b1c, b1c, b1c};
  }
  const unsigned short* xn = xic + w*800;
  #pragma unroll
  for (int mt = 0; mt < 4; mt++){
    const int Y = mt*2 + yb;
    bf16x8 A0 = ld_frag(xn + (Y+dy0)*80 + (xb+dx0)*8);
    bf16x8 A1 = ld_frag(xn + (Y+dy1)*80 + (xb+dx1)*8);
    bf16x8 A2 = ld_frag(xn + (Y+dy2)*80 + (xb+dx2)*8);
    #pragma unroll
    for (int nt = 0; nt < 2; nt++){
      acc1[mt][nt] = __builtin_amdgcn_mfma_f32_16x16x32_bf16(A0, __builtin_bit_cast(bf16x8, B1[0][nt]), acc1[mt][nt], 0,0,0);
      acc1[mt][nt] = __builtin_amdgcn_mfma_f32_16x16x32_bf16(A1, __builtin_bit_cast(bf16x8, B1[1][nt]), acc1[mt][nt], 0,0,0);
      acc1[mt][nt] = __builtin_amdgcn_mfma_f32_16x16x32_bf16(A2, __builtin_bit_cast(bf16x8, B1[2][nt]), acc1[mt][nt], 0,0,0);
    }
  }
  // conv1 epilogue: relu + pairwise cvt_pk + 2B stores
  unsigned short* cn = c1p + w*4000;
  #pragma unroll
  for (int mt = 0; mt < 4; mt++)
    #pragma unroll
    for (int nt = 0; nt < 2; nt++)
      #pragma unroll
      for (int jp = 0; jp < 2; jp++){
        float v0 = acc1[mt][nt][2*jp];     v0 = v0 > 0.f ? v0 : 0.f;
        float v1 = acc1[mt][nt][2*jp + 1]; v1 = v1 > 0.f ? v1 : 0.f;
        unsigned pk = cvt_pk_bf16(v0, v1);
        int r0 = g*4 + 2*jp, r1 = r0 + 1;
        int y0 = mt*2 + (r0 >> 3), x0 = r0 & 7;
        int y1 = mt*2 + (r1 >> 3), x1 = r1 & 7;
        cn[((y0+1)*10 + (x0+1))*40 + nt*16 + r16] = (unsigned short)pk;
        cn[((y1+1)*10 + (x1+1))*40 + nt*16 + r16] = (unsigned short)(pk >> 16);
      }
  asm volatile("" ::: "memory");   // keep c1p writes before conv2 reads

  // ---- conv2: tap-loop implicit GEMM, A from LDS, B via L1/L2-resident loads
  float b2v[4];
  #pragma unroll
  for (int nt = 0; nt < 4; nt++) b2v[nt] = b2[nt*16 + r16];
  f32x4 acc2[4][4];
  #pragma unroll
  for (int mt = 0; mt < 4; mt++)
    #pragma unroll
    for (int nt = 0; nt < 4; nt++)
      acc2[mt][nt] = (f32x4){b2v[nt], b2v[nt], b2v[nt], b2v[nt]};

  #pragma unroll
  for (int tap = 0; tap < 9; tap++){
    const int dy = tap/3, dx = tap%3;
    uint4 Bv[4];
    #pragma unroll
    for (int nt = 0; nt < 4; nt++)
      Bv[nt] = *(const uint4*)(W2t + tap*2048 + g*512 + (nt*16 + r16)*8);
    uint4 Av[4];
    #pragma unroll
    for (int mt = 0; mt < 4; mt++){
      int Y = mt*2 + yb + dy, X = xb + dx;
      Av[mt] = *(const uint4*)(cn + (Y*10 + X)*40 + g*8);
    }
    #pragma unroll
    for (int mt = 0; mt < 4; mt++)
      #pragma unroll
      for (int nt = 0; nt < 4; nt++)
        acc2[mt][nt] = __builtin_amdgcn_mfma_f32_16x16x32_bf16(
            __builtin_bit_cast(bf16x8, Av[mt]), __builtin_bit_cast(bf16x8, Bv[nt]), acc2[mt][nt], 0,0,0);
  }

  // relu + mean pool over 64 px -> x128[0:64]
  float* xo = x128 + (size_t)n*128;
  #pragma unroll
  for (int nt = 0; nt < 4; nt++){
    float s = 0.f;
    #pragma unroll
    for (int mt = 0; mt < 4; mt++)
      #pragma unroll
      for (int j = 0; j < 4; j++){
        float v = acc2[mt][nt][j]; s += (v > 0.f ? v : 0.f);
      }
    s += __shfl_xor(s, 16);
    s += __shfl_xor(s, 32);
    if (l < 16) xo[nt*16 + l] = s * (1.f/64.f);
  }
  // sym layer 1 (wave-private)
  {
    const float* xs = x_sym + (size_t)n*3;
    float a = s1b[l] + xs[0]*s1w[l] + xs[1]*s1w[64+l] + xs[2]*s1w[128+l];
    symh[w][l] = a > 0.f ? a : 0.f;
  }
  asm volatile("" ::: "memory");
  // sym layer 2 -> x128[64:128]
  {
    float a = s2b[l];
    #pragma unroll 8
    for (int k = 0; k < 64; k++) a = fmaf(symh[w][k], s2w[k*64 + l], a);
    xo[64 + l] = a > 0.f ? a : 0.f;
  }
}

// ---------------- node GEMM: h = x@W + b via split-bf16 MFMA; fused s,d dots; h stored bf16.
template<int K>
__global__ __launch_bounds__(256) void node_gemm(
    const float* __restrict__ xin,
    const unsigned short* __restrict__ Wh, const unsigned short* __restrict__ Wl,
    const float* __restrict__ b,
    const float* __restrict__ asrc, const float* __restrict__ adst,
    unsigned short* __restrict__ h_out, float* __restrict__ s_out, float* __restrict__ d_out)
{
  const int w = threadIdx.x >> 6, l = threadIdx.x & 63;
  const int g = l >> 4, r16 = l & 15;
  const int wid = blockIdx.x*4 + w;
  if (wid >= NND/16) return;
  const int rowbase = wid*16;

  f32x4 acc[8];
  #pragma unroll
  for (int nt = 0; nt < 8; nt++){
    float bv = b[nt*16 + r16];
    acc[nt] = (f32x4){bv, bv, bv, bv};
  }

  const float* xr = xin + (size_t)(rowbase + r16)*K + g*8;
  #pragma unroll 2
  for (int ks = 0; ks < K/32; ks++){
    float4 xa = *(const float4*)(xr + ks*32);
    float4 xb = *(const float4*)(xr + ks*32 + 4);
    float xs[8] = {xa.x,xa.y,xa.z,xa.w,xb.x,xb.y,xb.z,xb.w};
    uint4 hpk, lpk;
    unsigned* hp = (unsigned*)&hpk;
    unsigned* lp = (unsigned*)&lpk;
    #pragma unroll
    for (int p = 0; p < 4; p++){
      unsigned ph = cvt_pk_bf16(xs[2*p], xs[2*p+1]);
      float r0 = xs[2*p]   - __uint_as_float(ph << 16);
      float r1 = xs[2*p+1] - __uint_as_float(ph & 0xffff0000u);
      hp[p] = ph;
      lp[p] = cvt_pk_bf16(r0, r1);
    }
    bf16x8 Ah = __builtin_bit_cast(bf16x8, hpk);
    bf16x8 Al = __builtin_bit_cast(bf16x8, lpk);
    #pragma unroll
    for (int nt = 0; nt < 8; nt++){
      const int fo = (((ks*8 + nt)*64 + l)*8);
      bf16x8 Bh = ld_frag(Wh + fo);
      bf16x8 Bl = ld_frag(Wl + fo);
      acc[nt] = __builtin_amdgcn_mfma_f32_16x16x32_bf16(Ah, Bh, acc[nt], 0,0,0);
      acc[nt] = __builtin_amdgcn_mfma_f32_16x16x32_bf16(Al, Bh, acc[nt], 0,0,0);
      acc[nt] = __builtin_amdgcn_mfma_f32_16x16x32_bf16(Ah, Bl, acc[nt], 0,0,0);
    }
  }

  #pragma unroll
  for (int nt = 0; nt < 8; nt++)
    #pragma unroll
    for (int jp = 0; jp < 2; jp++){
      unsigned pk = cvt_pk_bf16(acc[nt][2*jp], acc[nt][2*jp+1]);
      h_out[(size_t)(rowbase + g*4 + 2*jp)*128 + nt*16 + r16]     = (unsigned short)pk;
      h_out[(size_t)(rowbase + g*4 + 2*jp + 1)*128 + nt*16 + r16] = (unsigned short)(pk >> 16);
    }

  float as_v[8], ad_v[8];
  #pragma unroll
  for (int nt = 0; nt < 8; nt++){
    as_v[nt] = asrc[nt*16 + r16];
    ad_v[nt] = adst[nt*16 + r16];
  }
  float sp[4][4], dp[4][4];
  #pragma unroll
  for (int hd = 0; hd < 4; hd++)
    #pragma unroll
    for (int j = 0; j < 4; j++){
      sp[hd][j] = acc[2*hd][j]*as_v[2*hd] + acc[2*hd+1][j]*as_v[2*hd+1];
      dp[hd][j] = acc[2*hd][j]*ad_v[2*hd] + acc[2*hd+1][j]*ad_v[2*hd+1];
    }
  #pragma unroll
  for (int o = 1; o < 16; o <<= 1)
    #pragma unroll
    for (int hd = 0; hd < 4; hd++)
      #pragma unroll
      for (int j = 0; j < 4; j++){
        sp[hd][j] += __shfl_xor(sp[hd][j], o);
        dp[hd][j] += __shfl_xor(dp[hd][j], o);
      }
  #pragma unroll
  for (int hd = 0; hd < 4; hd++){
    if (r16 == hd)
      #pragma unroll
      for (int j = 0; j < 4; j++)
        s_out[(rowbase + g*4 + j)*4 + hd] = sp[hd][j];
    if (r16 == 8 + hd)
      #pragma unroll
      for (int j = 0; j < 4; j++)
        d_out[(rowbase + g*4 + j)*4 + hd] = dp[hd][j];
  }
}

// -------------------------------------------- GAT aggregation v3: (edge x head) phase-1,
// 4-edge/uint4 phase-2. wave per dst node.
template<bool FUSE_CLS>
__global__ __launch_bounds__(256) void gat_aggregate(
    const float* __restrict__ sarr, const float* __restrict__ darr,
    const unsigned short* __restrict__ hb,
    const int2* __restrict__ srcattr, const int* __restrict__ offsets,
    const float* __restrict__ We, const float* __restrict__ be,
    const float* __restrict__ aedge, const float* __restrict__ Wg, const float* __restrict__ bgp,
    float* __restrict__ xout,
    const float* __restrict__ cw1, const float* __restrict__ cb1,
    const float* __restrict__ cw2, const float* __restrict__ cb2,
    float* __restrict__ out)
{
  __shared__ int2 ew[4][2][4][64];   // [wave][buf][head][edge] = {w_bits, src}
  __shared__ float xrow[4][128];
  __shared__ float hrow[4][64];
  const int l   = threadIdx.x & 63;
  const int w   = threadIdx.x >> 6;
  const int v   = blockIdx.x*4 + w;
  const int hd  = l >> 4;        // phase-1 head / phase-2 edge offset
  const int e16 = l & 15;        // phase-1 edge slot / phase-2 channel block
  const int c0  = 2*l;
  const int c8  = e16 * 8;       // phase-2 channel base (8 ch/lane)
  const int hd2 = e16 >> 2;      // head of this lane's channel block

  float ae0 = aedge[hd*32 + (c0 & 31)];
  float ae1 = aedge[hd*32 + ((c0+1) & 31)];
  float p0 = We[c0]*ae0 + We[c0+1]*ae1;
  float p1 = We[128+c0]*ae0 + We[128+c0+1]*ae1;
  float pc = be[c0]*ae0 + be[c0+1]*ae1;
  #pragma unroll
  for (int o = 1; o < 16; o <<= 1){ p0 += __shfl_xor(p0,o); p1 += __shfl_xor(p1,o); pc += __shfl_xor(pc,o); }
  const float wg0 = Wg[0], wg1 = Wg[1], bgv = bgp[0];

  const int off = offsets[v];
  const int deg = offsets[v+1] - off;
  const float dh = darr[(size_t)v*4 + hd];

  float dn = 0.f, Sm = 0.f, S0 = 0.f, S1 = 0.f;
  float acc[8] = {0.f,0.f,0.f,0.f,0.f,0.f,0.f,0.f};

  int pb = 0;
  for (int base = 0; base < deg; base += 64, pb ^= 1){
    #pragma unroll
    for (int s = 0; s < 4; s++){
      int ii = base + s*16 + e16;
      float wv = 0.f; int sj = 0;
      if (ii < deg){
        int2 sa = srcattr[off + ii];
        sj = sa.x;
        unsigned pa = (unsigned)sa.y;
        float a0 = __uint_as_float(pa << 16);
        float a1 = __uint_as_float(pa & 0xffff0000u);
        float sv = sarr[(size_t)sj*4 + hd];
        float e  = __expf(leaky02(sv + dh + a0*p0 + a1*p1 + pc));
        float gt = 1.f/(1.f + __expf(-(a0*wg0 + a1*wg1 + bgv)));
        dn += e; wv = gt*e;
        Sm += wv; S0 += wv*a0; S1 += wv*a1;
      }
      ew[w][pb][hd][s*16 + e16] = make_int2(__float_as_int(wv), sj);
    }
    asm volatile("s_waitcnt lgkmcnt(0)" ::: "memory");
    const int2* eb = &ew[w][pb][hd2][0];
    int lim = deg - base; if (lim > 64) lim = 64;
    #pragma unroll 4
    for (int j = 0; j < lim; j += 4){
      int2 ws2 = eb[j + hd];
      float wv = __int_as_float(ws2.x);
      uint4 hv = *(const uint4*)(hb + (((size_t)ws2.y) << 7) + c8);
      acc[0] = fmaf(__uint_as_float(hv.x << 16),         wv, acc[0]);
      acc[1] = fmaf(__uint_as_float(hv.x & 0xffff0000u), wv, acc[1]);
      acc[2] = fmaf(__uint_as_float(hv.y << 16),         wv, acc[2]);
      acc[3] = fmaf(__uint_as_float(hv.y & 0xffff0000u), wv, acc[3]);
      acc[4] = fmaf(__uint_as_float(hv.z << 16),         wv, acc[4]);
      acc[5] = fmaf(__uint_as_float(hv.z & 0xffff0000u), wv, acc[5]);
      acc[6] = fmaf(__uint_as_float(hv.w << 16),         wv, acc[6]);
      acc[7] = fmaf(__uint_as_float(hv.w & 0xffff0000u), wv, acc[7]);
    }
  }

  #pragma unroll
  for (int k = 0; k < 8; k++){
    acc[k] += __shfl_xor(acc[k], 16);
    acc[k] += __shfl_xor(acc[k], 32);
  }
  #pragma unroll
  for (int o = 1; o < 16; o <<= 1){
    dn += __shfl_xor(dn, o); Sm += __shfl_xor(Sm, o);
    S0 += __shfl_xor(S0, o); S1 += __shfl_xor(S1, o);
  }
  int srcl = hd2*16 + e16;
  float den = __shfl(dn, srcl);
  float Smh = __shfl(Sm, srcl);
  float S0h = __shfl(S0, srcl);
  float S1h = __shfl(S1, srcl);
  float rden = 1.f/(den + 1e-16f);

  float o8[8];
  #pragma unroll
  for (int k = 0; k < 8; k++){
    float x = (acc[k] + be[c8+k]*Smh + We[c8+k]*S0h + We[128+c8+k]*S1h) * rden;
    o8[k] = x > 0.f ? x : (__expf(x) - 1.f);
  }

  if constexpr (!FUSE_CLS){
    if (l < 16){
      float4 lo = make_float4(o8[0], o8[1], o8[2], o8[3]);
      float4 hi = make_float4(o8[4], o8[5], o8[6], o8[7]);
      *(float4*)(xout + (size_t)v*128 + c8)     = lo;
      *(float4*)(xout + (size_t)v*128 + c8 + 4) = hi;
    }
  } else {
    if (l < 16){
      *(float4*)&xrow[w][c8]     = make_float4(o8[0], o8[1], o8[2], o8[3]);
      *(float4*)&xrow[w][c8 + 4] = make_float4(o8[4], o8[5], o8[6], o8[7]);
    }
    asm volatile("s_waitcnt lgkmcnt(0)" ::: "memory");
    float a = cb1[l];
    #pragma unroll 8
    for (int k = 0; k < 128; k++) a = fmaf(xrow[w][k], cw1[k*64 + l], a);
    hrow[w][l] = a > 0.f ? a : 0.f;
    asm volatile("s_waitcnt lgkmcnt(0)" ::: "memory");
    if (l < 25){
      float o = cb2[l];
      #pragma unroll 8
      for (int k = 0; k < 64; k++) o = fmaf(hrow[w][k], cw2[k*25 + l], o);
      out[(size_t)v*25 + l] = o;
    }
  }
}

// ---------------------------------------------------------------- launch
extern "C" void kernel_launch(void* const* d_in, const int* in_sizes, int n_in,
                              void* d_out, int out_size, void* d_ws, size_t ws_size,
                              hipStream_t stream)
{
  (void)in_sizes; (void)n_in; (void)out_size; (void)ws_size;
  const float* x_vis   = (const float*)d_in[0];
  const float* x_sym   = (const float*)d_in[1];
  const int*   ei      = (const int*)  d_in[2];
  const float* ea      = (const float*)d_in[3];
  const float* c1w     = (const float*)d_in[4];
  const float* c1b     = (const float*)d_in[5];
  const float* c2w     = (const float*)d_in[6];
  const float* c2b     = (const float*)d_in[7];
  const float* fcw     = (const float*)d_in[8];
  const float* fcb     = (const float*)d_in[9];
  const float* s1w     = (const float*)d_in[10];
  const float* s1b     = (const float*)d_in[11];
  const float* s2w     = (const float*)d_in[12];
  const float* s2b     = (const float*)d_in[13];
  const float* g1W     = (const float*)d_in[14];
  const float* g1b     = (const float*)d_in[15];
  const float* g1We    = (const float*)d_in[16];
  const float* g1be    = (const float*)d_in[17];
  const float* g1asrc  = (const float*)d_in[18];
  const float* g1adst  = (const float*)d_in[19];
  const float* g1aedge = (const float*)d_in[20];
  const float* g1Wg    = (const float*)d_in[21];
  const float* g1bg    = (const float*)d_in[22];
  const float* g2W     = (const float*)d_in[23];
  const float* g2b     = (const float*)d_in[24];
  const float* g2We    = (const float*)d_in[25];
  const float* g2be    = (const float*)d_in[26];
  const float* g2asrc  = (const float*)d_in[27];
  const float* g2adst  = (const float*)d_in[28];
  const float* g2aedge = (const float*)d_in[29];
  const float* g2Wg    = (const float*)d_in[30];
  const float* g2bg    = (const float*)d_in[31];
  const float* cw1     = (const float*)d_in[32];
  const float* cb1     = (const float*)d_in[33];
  const float* cw2     = (const float*)d_in[34];
  const float* cb2     = (const float*)d_in[35];

  size_t off = 0;
  auto take = [&](size_t bytes) -> void* {
    off = (off + 255) & ~(size_t)255;
    void* p = (char*)d_ws + off;
    off += bytes;
    return p;
  };
  int*   cnt     = (int*)  take((size_t)NND*4);
  int*   offs    = (int*)  take((size_t)(NND+1)*4);
  int*   bsum    = (int*)  take((size_t)SCAN_B*4);
  int2*  srcattr = (int2*) take((size_t)NE*8);
  float* x128    = (float*)take((size_t)NND*128*4);
  unsigned short* hb = (unsigned short*)take((size_t)NND*128*2);
  float* sbuf    = (float*)take((size_t)NND*4*4);
  float* dbuf    = (float*)take((size_t)NND*4*4);
  float* x2      = (float*)take((size_t)NND*128*4);
  unsigned short* W1t = (unsigned short*)take(3072*2);
  unsigned short* W2t = (unsigned short*)take(18432*2);
  float* Weff    = (float*)take(16384*4);
  float* beff    = (float*)take(128*4);
  unsigned short* G1h = (unsigned short*)take(16384*2);
  unsigned short* G1l = (unsigned short*)take(16384*2);
  unsigned short* G2h = (unsigned short*)take(16384*2);
  unsigned short* G2l = (unsigned short*)take(16384*2);

  // weight pre-transforms (merged: A = conv weights + fold, B = both gemm packs)
  prep_wf<<<66, 256, 0, stream>>>(c1w, c2w, W1t, W2t, fcw, fcb, g1W, g1b, Weff, beff);
  prep_gemm2<<<128, 256, 0, stream>>>(Weff, g2W, G1h, G1l, G2h, G2l);

  // CSR build (graph identical for both GAT layers)
  hipMemsetAsync(cnt, 0, (size_t)NND*4, stream);
  hist_kernel<<<(NE+255)/256, 256, 0, stream>>>(ei, cnt);
  scan1_kernel<<<SCAN_B, 256, 0, stream>>>(cnt, offs, bsum);
  scan3_kernel<<<SCAN_B, 256, 0, stream>>>(offs, bsum);
  scatter_kernel<<<(NE+255)/256, 256, 0, stream>>>(ei, ea, offs, cnt, srcattr);

  // encoders (MFMA, 4 nodes/block, barrier-free)
  uv_mfma_kernel<<<NND/4, 256, 0, stream>>>(x_vis, x_sym, W1t, W2t, c1b, c2b,
                                            s1w, s1b, s2w, s2b, x128);
  // GAT layer 1 (uvfc folded into Weff)
  node_gemm<128><<<(NND/16 + 3)/4, 256, 0, stream>>>(x128, G1h, G1l, beff, g1asrc, g1adst,
                                                     hb, sbuf, dbuf);
  gat_aggregate<false><<<NND/4, 256, 0, stream>>>(sbuf, dbuf, hb, srcattr, offs,
                                                  g1We, g1be, g1aedge, g1Wg, g1bg, x2,
                                                  nullptr, nullptr, nullptr, nullptr, nullptr);
  // GAT layer 2 + fused classifier
  node_gemm<128><<<(NND/16 + 3)/4, 256, 0, stream>>>(x2, G2h, G2l, g2b, g2asrc, g2adst,
                                                     hb, sbuf, dbuf);
  gat_aggregate<true><<<NND/4, 256, 0, stream>>>(sbuf, dbuf, hb, srcattr, offs,
                                                 g2We, g2be, g2aedge, g2Wg, g2bg, nullptr,
                                                 cw1, cb1, cw2, cb2, (float*)d_out);
}